// Round 2
// baseline (4277.419 us; speedup 1.0000x reference)
//
#include <hip/hip_runtime.h>
#include <hip/hip_bf16.h>
#include <math.h>

typedef __hip_bfloat16 bf16;

__device__ __forceinline__ float b2f(bf16 v) { return __bfloat162float(v); }
__device__ __forceinline__ bf16 f2b(float v) { return __float2bfloat16(v); }
__device__ __forceinline__ float bflo(unsigned u) { return __uint_as_float(u << 16); }
__device__ __forceinline__ float bfhi(unsigned u) { return __uint_as_float(u & 0xffff0000u); }
__device__ __forceinline__ float geluf(float x) { return 0.5f * x * (1.0f + erff(x * 0.70710678118654752f)); }
__device__ __forceinline__ float sigmoidf_(float x) { return 1.0f / (1.0f + __expf(-x)); }

// round-to-nearest-even fp32 -> bf16 bit pack (two values -> one dword)
__device__ __forceinline__ unsigned pack2bf(float a, float b) {
    unsigned ua = __float_as_uint(a); ua = (ua + 0x7FFFu + ((ua >> 16) & 1u)) >> 16;
    unsigned ub = __float_as_uint(b); ub = (ub + 0x7FFFu + ((ub >> 16) & 1u)) >> 16;
    return ua | (ub << 16);
}

// dot of 64 fp32 (LDS) with 64 fp32 (global, 16B-aligned row)
__device__ __forceinline__ float dot64f(const float* a, const float* w) {
    const float4* wp = reinterpret_cast<const float4*>(w);
    float acc = 0.f;
#pragma unroll
    for (int v = 0; v < 16; v++) {
        float4 u = wp[v];
        const float* ar = a + v * 4;
        acc += ar[0] * u.x + ar[1] * u.y + ar[2] * u.z + ar[3] * u.w;
    }
    return acc;
}

__device__ __forceinline__ float dot128f(const float* a, const float* w) {
    const float4* wp = reinterpret_cast<const float4*>(w);
    float acc = 0.f;
#pragma unroll
    for (int v = 0; v < 32; v++) {
        float4 u = wp[v];
        const float* ar = a + v * 4;
        acc += ar[0] * u.x + ar[1] * u.y + ar[2] * u.z + ar[3] * u.w;
    }
    return acc;
}

// ========================== K0a: dtype detector ==============================
// Low 16 bits of each dword: bf16 data -> a sane N(0,1) bf16 value (~100%);
// fp32 data -> random mantissa bits -> sane-looking bf16 only ~16% of the time.
__global__ __launch_bounds__(256) void k_detect(const unsigned* __restrict__ x, int* __restrict__ flag)
{
    __shared__ int cnt;
    if (threadIdx.x == 0) cnt = 0;
    __syncthreads();
    unsigned u = x[threadIdx.x] & 0xFFFFu;
    float f = __uint_as_float(u << 16);
    float a = fabsf(f);
    int sane = (f == 0.0f) || (a > 1e-8f && a < 1e4f);
    atomicAdd(&cnt, sane);
    __syncthreads();
    if (threadIdx.x == 0) *flag = (cnt >= 160) ? 1 : 0;
}

// ========================== K0b: canonicalize to fp32 ========================
struct InPtrs { const void* p[35]; };
struct InOffs { int off[35]; int sz[35]; };

__global__ __launch_bounds__(256) void k_convert(InPtrs P, InOffs O, int total,
                                                 const int* __restrict__ flag,
                                                 float* __restrict__ cvt)
{
    int idx = blockIdx.x * 256 + threadIdx.x;
    if (idx >= total) return;
    int isb = *flag;
    float v = 0.f;
#pragma unroll 1
    for (int s = 0; s < 35; s++) {
        int rel = idx - O.off[s];
        if (rel >= 0 && rel < O.sz[s]) {
            v = isb ? b2f(((const bf16*)P.p[s])[rel]) : ((const float*)P.p[s])[rel];
            break;
        }
    }
    cvt[idx] = v;
}

// =============================== K1: fused CNN ===============================
// x (512,4096) fp32 -> h_main (512,256,64) fp32
__global__ __launch_bounds__(256) void k_cnn(
    const float* __restrict__ x, const float* __restrict__ c1w, const float* __restrict__ c1b,
    const float* __restrict__ bn1g, const float* __restrict__ bn1b, const float* __restrict__ bn1m, const float* __restrict__ bn1v,
    const float* __restrict__ c2w, const float* __restrict__ c2b,
    const float* __restrict__ bn2g, const float* __restrict__ bn2b, const float* __restrict__ bn2m, const float* __restrict__ bn2v,
    float* __restrict__ h_main)
{
    __shared__ float xs[1056];
    __shared__ float h1[32][261];
    __shared__ float w1[32 * 7];
    __shared__ float A1[32], B1[32];
    __shared__ float w2[64 * 160];
    __shared__ float A2[64], B2[64];
    int bc = blockIdx.x, t = threadIdx.x;
    for (int i = t; i < 224; i += 256) w1[i] = c1w[i];
    for (int i = t; i < 10240; i += 256) w2[i] = c2w[i];
    if (t < 32) {
        float s = bn1g[t] * rsqrtf(bn1v[t] + 1e-5f);
        A1[t] = s; B1[t] = (c1b[t] - bn1m[t]) * s + bn1b[t];
    } else if (t < 96) {
        int d = t - 32;
        float s = bn2g[d] * rsqrtf(bn2v[d] + 1e-5f);
        A2[d] = s; B2[d] = (c2b[d] - bn2m[d]) * s + bn2b[d];
    }
    __syncthreads();
    const float* xrow = x + (size_t)bc * 4096;
    for (int tile = 0; tile < 4; tile++) {
        int X0 = 1024 * tile - 11;
        for (int i = t; i < 1056; i += 256) {
            int g = X0 + i;
            xs[i] = (g >= 0 && g < 4096) ? xrow[g] : 0.0f;
        }
        __syncthreads();
        for (int o = t; o < 32 * 260; o += 256) {
            int ic = o / 260, j = o % 260;
            int t1p = 256 * tile - 2 + j;
            float res = 0.0f;
            if (t1p >= 0 && t1p < 1024) {
                const float* wr = &w1[ic * 7];
                float a = A1[ic], bb = B1[ic];
                float mx = -3.4e38f;
#pragma unroll
                for (int q = 0; q < 4; q++) {
                    float acc = 0.f;
#pragma unroll
                    for (int k = 0; k < 7; k++) acc += xs[4 * j + q + k] * wr[k];
                    mx = fmaxf(mx, geluf(acc * a + bb));
                }
                res = mx;
            }
            h1[ic][j] = res;
        }
        __syncthreads();
        int p = t & 63, dg = t >> 6;
        float acc[16][4];
#pragma unroll
        for (int dd = 0; dd < 16; dd++)
#pragma unroll
            for (int q = 0; q < 4; q++) acc[dd][q] = 0.f;
        for (int ic = 0; ic < 32; ic++) {
            float dreg[8];
#pragma unroll
            for (int m = 0; m < 8; m++) dreg[m] = h1[ic][4 * p + m];
#pragma unroll
            for (int dd = 0; dd < 16; dd++) {
                const float* wk = &w2[(dg * 16 + dd) * 160 + ic * 5];
#pragma unroll
                for (int k = 0; k < 5; k++) {
                    float w = wk[k];
                    acc[dd][0] += dreg[k] * w;
                    acc[dd][1] += dreg[k + 1] * w;
                    acc[dd][2] += dreg[k + 2] * w;
                    acc[dd][3] += dreg[k + 3] * w;
                }
            }
        }
        int tp = tile * 64 + p;
        float* dst = h_main + (size_t)bc * 16384 + (size_t)tp * 64 + dg * 16;
#pragma unroll
        for (int dd = 0; dd < 16; dd++) {
            int d = dg * 16 + dd;
            float a = A2[d], bb = B2[d];
            float v = fmaxf(fmaxf(geluf(acc[dd][0] * a + bb), geluf(acc[dd][1] * a + bb)),
                            fmaxf(geluf(acc[dd][2] * a + bb), geluf(acc[dd][3] * a + bb)));
            dst[dd] = v;
        }
        __syncthreads();
    }
}

// =============================== K2: FFT + spec norm =========================
__global__ __launch_bounds__(512) void k_fft(const float* __restrict__ x, float* __restrict__ Xn)
{
    __shared__ float re[4096];
    __shared__ float im[4096];
    __shared__ float red[8];
    int bc = blockIdx.x, t = threadIdx.x;
    const float* xr = x + (size_t)bc * 4096;
    for (int i = t; i < 4096; i += 512) {
        int r = __brev((unsigned)i) >> 20;
        re[r] = xr[i];
        im[r] = 0.f;
    }
    __syncthreads();
    for (int s = 1; s <= 12; s++) {
        int half = 1 << (s - 1);
        float ang = -6.283185307179586f / (float)(1 << s);
        for (int m = t; m < 2048; m += 512) {
            int j = m & (half - 1);
            int pos = ((m >> (s - 1)) << s) | j;
            float sn, cs;
            __sincosf(ang * (float)j, &sn, &cs);
            float ur = re[pos], ui = im[pos];
            float vr = re[pos + half], vi = im[pos + half];
            float tr = vr * cs - vi * sn;
            float ti = vr * sn + vi * cs;
            re[pos] = ur + tr; im[pos] = ui + ti;
            re[pos + half] = ur - tr; im[pos + half] = ui - ti;
        }
        __syncthreads();
    }
    float mag[5];
    float ss = 0.f;
    int cnt = 0;
    for (int f = t; f <= 2048; f += 512) {
        float m2 = re[f] * re[f] + im[f] * im[f];
        mag[cnt++] = sqrtf(m2);
        ss += m2;
    }
    for (int off = 32; off; off >>= 1) ss += __shfl_xor(ss, off, 64);
    if ((t & 63) == 0) red[t >> 6] = ss;
    __syncthreads();
    float tot = 0.f;
#pragma unroll
    for (int i = 0; i < 8; i++) tot += red[i];
    float inv = 1.0f / (sqrtf(tot) + 1e-8f);
    cnt = 0;
    for (int f = t; f <= 2048; f += 512) Xn[(size_t)bc * 2049 + f] = mag[cnt++] * inv;
}

// =============================== K3: h_avg -> hn =============================
__global__ __launch_bounds__(64) void k_havg(const float* __restrict__ hm, float* __restrict__ hnf)
{
    int bc = blockIdx.x, d = threadIdx.x;
    const float* base = hm + (size_t)bc * 16384;
    float s = 0.f;
    for (int tp = 0; tp < 256; tp++) s += base[tp * 64 + d];
    float avg = s * (1.0f / 256.0f);
    float tot = avg;
    for (int off = 32; off; off >>= 1) tot += __shfl_xor(tot, off, 64);
    float hc = avg - tot * (1.0f / 64.0f);
    float sq = hc * hc;
    for (int off = 32; off; off >>= 1) sq += __shfl_xor(sq, off, 64);
    hnf[bc * 64 + d] = hc / (sqrtf(sq) + 1e-8f);
}

// =============================== K4: adjacency ===============================
__global__ __launch_bounds__(256) void k_adj(
    const float* __restrict__ Xn, const float* __restrict__ hnf,
    const float* __restrict__ prior, const float* __restrict__ logw,
    float* __restrict__ adjw, void* __restrict__ out, const int* __restrict__ flag)
{
    __shared__ float xt[16][257];
    __shared__ float hh[16 * 64];
    int b = blockIdx.x, t = threadIdx.x;
    int c = t >> 4, e = t & 15;
    for (int i = t; i < 1024; i += 256) hh[i] = hnf[b * 1024 + i];
    __syncthreads();
    float fc = 0.f;
    for (int d = 0; d < 64; d++) fc += hh[c * 64 + d] * hh[e * 64 + d];
    float sc = 0.f;
    const float* Xb = Xn + (size_t)b * 16 * 2049;
    for (int f0 = 0; f0 < 2048; f0 += 256) {
        __syncthreads();
        for (int i = t; i < 16 * 256; i += 256) {
            int rr = i >> 8, ff = i & 255;
            xt[rr][ff] = Xb[rr * 2049 + f0 + ff];
        }
        __syncthreads();
        for (int ff = 0; ff < 256; ff++) sc += xt[c][ff] * xt[e][ff];
    }
    sc += Xb[c * 2049 + 2048] * Xb[e * 2049 + 2048];
    float l0 = logw[0], l1 = logw[1], l2 = logw[2];
    float mx = fmaxf(l0, fmaxf(l1, l2));
    float e0 = __expf(l0 - mx), e1 = __expf(l1 - mx), e2 = __expf(l2 - mx);
    float isum = 1.0f / (e0 + e1 + e2);
    float pr = prior[c * 16 + e] + prior[e * 16 + c];
    float v = (e0 * fc + e1 * sc + e2 * pr) * isum;
    adjw[b * 256 + t] = v;
    if (*flag) ((bf16*)out)[4096 + b * 256 + t] = f2b(v);
    else       ((float*)out)[4096 + b * 256 + t] = v;
}

// =============================== K5: GAT stack ===============================
__device__ __forceinline__ void ln16x64(float (*src)[65], float (*dst)[65],
                                        const float* g, const float* b, int t)
{
    int c = t >> 4, i = t & 15;
    float p0 = src[c][i], p1 = src[c][i + 16], p2 = src[c][i + 32], p3 = src[c][i + 48];
    float s = p0 + p1 + p2 + p3;
    s += __shfl_xor(s, 1, 16); s += __shfl_xor(s, 2, 16);
    s += __shfl_xor(s, 4, 16); s += __shfl_xor(s, 8, 16);
    float mean = s * (1.0f / 64.0f);
    float q0 = p0 - mean, q1 = p1 - mean, q2 = p2 - mean, q3 = p3 - mean;
    float v = q0 * q0 + q1 * q1 + q2 * q2 + q3 * q3;
    v += __shfl_xor(v, 1, 16); v += __shfl_xor(v, 2, 16);
    v += __shfl_xor(v, 4, 16); v += __shfl_xor(v, 8, 16);
    float rstd = rsqrtf(v * (1.0f / 64.0f) + 1e-5f);
    dst[c][i]      = q0 * rstd * g[i]      + b[i];
    dst[c][i + 16] = q1 * rstd * g[i + 16] + b[i + 16];
    dst[c][i + 32] = q2 * rstd * g[i + 32] + b[i + 32];
    dst[c][i + 48] = q3 * rstd * g[i + 48] + b[i + 48];
}

__global__ __launch_bounds__(256) void k_gat(
    float* __restrict__ hm, const float* __restrict__ adjw,
    const float* __restrict__ n1g_, const float* __restrict__ n1b_,
    const float* __restrict__ qw_, const float* __restrict__ qb_,
    const float* __restrict__ ow_, const float* __restrict__ ob_,
    const float* __restrict__ n2g_, const float* __restrict__ n2b_,
    const float* __restrict__ f1w_, const float* __restrict__ f1b_,
    const float* __restrict__ f2w_, const float* __restrict__ f2b_,
    const float* __restrict__ gng, const float* __restrict__ gnb)
{
    __shared__ float ht_s[16][65];
    __shared__ float hn_s[16][65];
    __shared__ float qkv_s[16][193];
    __shared__ float at_s[4][16][17];
    __shared__ float f_s[16][129];
    __shared__ float adj_s[256];
    int n = blockIdx.x, t = threadIdx.x;
    int b = n >> 8, tp = n & 255;
    float* src = hm + (size_t)b * 16 * 16384 + (size_t)tp * 64;
#pragma unroll
    for (int r = 0; r < 4; r++) {
        int idx = t + 256 * r, c = idx >> 6, d = idx & 63;
        ht_s[c][d] = src[(size_t)c * 16384 + d];
    }
    adj_s[t] = adjw[b * 256 + t];
    __syncthreads();
    for (int l = 0; l < 2; l++) {
        const float* n1g = n1g_ + l * 64;  const float* n1b = n1b_ + l * 64;
        const float* qw = qw_ + l * 192 * 64;  const float* qb = qb_ + l * 192;
        const float* ow = ow_ + l * 64 * 64;   const float* ob = ob_ + l * 64;
        const float* n2g = n2g_ + l * 64;  const float* n2b = n2b_ + l * 64;
        const float* f1w = f1w_ + l * 128 * 64; const float* f1b = f1b_ + l * 128;
        const float* f2w = f2w_ + l * 64 * 128; const float* f2b = f2b_ + l * 64;
        ln16x64(ht_s, hn_s, n1g, n1b, t);
        __syncthreads();
#pragma unroll
        for (int r = 0; r < 12; r++) {
            int idx = t + 256 * r, c = idx / 192, j = idx % 192;
            qkv_s[c][j] = qb[j] + dot64f(hn_s[c], qw + j * 64);
        }
        __syncthreads();
#pragma unroll
        for (int r = 0; r < 4; r++) {
            int idx = t + 256 * r;
            int h = idx >> 8, qc = (idx >> 4) & 15, kc = idx & 15;
            float acc = 0.f;
#pragma unroll
            for (int kk = 0; kk < 16; kk++) acc += qkv_s[qc][h * 16 + kk] * qkv_s[kc][64 + h * 16 + kk];
            at_s[h][qc][kc] = acc * 0.25f + adj_s[qc * 16 + kc];
        }
        __syncthreads();
        if (t < 64) {
            int h = t >> 4, qc = t & 15;
            float mx = -3.4e38f;
#pragma unroll
            for (int kc = 0; kc < 16; kc++) mx = fmaxf(mx, at_s[h][qc][kc]);
            float sum = 0.f; float ex[16];
#pragma unroll
            for (int kc = 0; kc < 16; kc++) { ex[kc] = __expf(at_s[h][qc][kc] - mx); sum += ex[kc]; }
            float inv = 1.0f / sum;
#pragma unroll
            for (int kc = 0; kc < 16; kc++) at_s[h][qc][kc] = ex[kc] * inv;
        }
        __syncthreads();
#pragma unroll
        for (int r = 0; r < 4; r++) {
            int idx = t + 256 * r, c = idx >> 6, e = idx & 63, h = e >> 4;
            float acc = 0.f;
#pragma unroll
            for (int kc = 0; kc < 16; kc++) acc += at_s[h][c][kc] * qkv_s[kc][128 + e];
            f_s[c][e] = acc;
        }
        __syncthreads();
#pragma unroll
        for (int r = 0; r < 4; r++) {
            int idx = t + 256 * r, c = idx >> 6, d = idx & 63;
            ht_s[c][d] += ob[d] + dot64f(f_s[c], ow + d * 64);
        }
        __syncthreads();
        ln16x64(ht_s, hn_s, n2g, n2b, t);
        __syncthreads();
#pragma unroll
        for (int r = 0; r < 8; r++) {
            int idx = t + 256 * r, c = idx >> 7, j = idx & 127;
            f_s[c][j] = geluf(f1b[j] + dot64f(hn_s[c], f1w + j * 64));
        }
        __syncthreads();
#pragma unroll
        for (int r = 0; r < 4; r++) {
            int idx = t + 256 * r, c = idx >> 6, d = idx & 63;
            ht_s[c][d] += f2b[d] + dot128f(f_s[c], f2w + d * 128);
        }
        __syncthreads();
    }
    ln16x64(ht_s, hn_s, gng, gnb, t);
    __syncthreads();
#pragma unroll
    for (int r = 0; r < 4; r++) {
        int idx = t + 256 * r, c = idx >> 6, d = idx & 63;
        src[(size_t)c * 16384 + d] = hn_s[c][d];
    }
}

// =============================== K6: GRU =====================================
__global__ __launch_bounds__(192) void k_gru(
    const float* __restrict__ hs, const float* __restrict__ wih, const float* __restrict__ whh,
    const float* __restrict__ bih, const float* __restrict__ bhh, float* __restrict__ h_out)
{
    __shared__ unsigned wi[192 * 33];
    __shared__ unsigned wh[192 * 33];
    __shared__ float hcur[64];
    __shared__ float xv[64];
    __shared__ float gi[192], gh[192];
    int blk = blockIdx.x;
    int bc = blk >> 1, dir = blk & 1;
    int t = threadIdx.x;
    const float2* wi_g = reinterpret_cast<const float2*>(wih + dir * 192 * 64);
    const float2* wh_g = reinterpret_cast<const float2*>(whh + dir * 192 * 64);
    for (int i = t; i < 192 * 32; i += 192) {
        int j = i >> 5, pcol = i & 31;
        float2 a = wi_g[i];
        float2 c = wh_g[i];
        wi[j * 33 + pcol] = pack2bf(a.x, a.y);
        wh[j * 33 + pcol] = pack2bf(c.x, c.y);
    }
    float bi_r = bih[dir * 192 + t];
    float bh_r = bhh[dir * 192 + t];
    if (t < 64) hcur[t] = 0.f;
    __syncthreads();
    const float* xbase = hs + (size_t)bc * 16384;
    const unsigned* wir = &wi[t * 33];
    const unsigned* whr = &wh[t * 33];
    for (int step = 0; step < 256; step++) {
        int tt = dir ? (255 - step) : step;
        if (t < 64) xv[t] = xbase[tt * 64 + t];
        __syncthreads();
        float a = bi_r, c = bh_r;
#pragma unroll
        for (int p = 0; p < 32; p++) {
            unsigned u = wir[p], v = whr[p];
            a += xv[2 * p] * bflo(u) + xv[2 * p + 1] * bfhi(u);
            c += hcur[2 * p] * bflo(v) + hcur[2 * p + 1] * bfhi(v);
        }
        gi[t] = a; gh[t] = c;
        __syncthreads();
        if (t < 64) {
            float r = sigmoidf_(gi[t] + gh[t]);
            float z = sigmoidf_(gi[64 + t] + gh[64 + t]);
            float nn = tanhf(gi[128 + t] + r * gh[128 + t]);
            hcur[t] = (1.f - z) * nn + z * hcur[t];
        }
        __syncthreads();
    }
    if (t < 64) h_out[bc * 128 + dir * 64 + t] = hcur[t];
}

// =============================== K7: readout =================================
__global__ __launch_bounds__(128) void k_readout(
    const float* __restrict__ h_out, const float* __restrict__ gw, const float* __restrict__ gb,
    void* __restrict__ out, const int* __restrict__ flag)
{
    __shared__ float gate_s[16];
    __shared__ float gws[128];
    int b = blockIdx.x, t = threadIdx.x;
    gws[t] = gw[t];
    __syncthreads();
    int isb = *flag;
    if (t < 16) {
        const float* hr = h_out + (size_t)(b * 16 + t) * 128;
        float acc = gb[0];
        for (int k = 0; k < 128; k++) acc += hr[k] * gws[k];
        float g = sigmoidf_(acc);
        gate_s[t] = g;
        if (isb) ((bf16*)out)[12288 + b * 16 + t] = f2b(g);
        else     ((float*)out)[12288 + b * 16 + t] = g;
    }
    __syncthreads();
    float den = 1e-8f;
#pragma unroll
    for (int c = 0; c < 16; c++) den += gate_s[c];
    float num = 0.f;
#pragma unroll
    for (int c = 0; c < 16; c++) num += h_out[(size_t)(b * 16 + c) * 128 + t] * gate_s[c];
    float v = num / den;
    if (isb) ((bf16*)out)[b * 128 + t] = f2b(v);
    else     ((float*)out)[b * 128 + t] = v;
}

// =============================== launch ======================================
extern "C" void kernel_launch(void* const* d_in, const int* in_sizes, int n_in,
                              void* d_out, int out_size, void* d_ws, size_t ws_size,
                              hipStream_t stream)
{
    // canonical fp32 copies of all inputs in workspace
    int* flag = (int*)d_ws;
    float* cvt = (float*)((char*)d_ws + 256);

    InPtrs P;
    InOffs O;
    int cum = 0;
    for (int i = 0; i < 35; i++) {
        P.p[i] = d_in[i];
        O.off[i] = cum;
        O.sz[i] = in_sizes[i];
        cum += (in_sizes[i] + 7) & ~7;
    }
    int total = cum;

    const float* x     = cvt + O.off[0];
    const float* c1w   = cvt + O.off[1];
    const float* c1b   = cvt + O.off[2];
    const float* bn1g  = cvt + O.off[3];
    const float* bn1b  = cvt + O.off[4];
    const float* bn1m  = cvt + O.off[5];
    const float* bn1v  = cvt + O.off[6];
    const float* c2w   = cvt + O.off[7];
    const float* c2b   = cvt + O.off[8];
    const float* bn2g  = cvt + O.off[9];
    const float* bn2b  = cvt + O.off[10];
    const float* bn2m  = cvt + O.off[11];
    const float* bn2v  = cvt + O.off[12];
    const float* prior = cvt + O.off[13];
    const float* logw  = cvt + O.off[14];
    const float* n1g   = cvt + O.off[15];
    const float* n1b   = cvt + O.off[16];
    const float* qkvw  = cvt + O.off[17];
    const float* qkvb  = cvt + O.off[18];
    const float* outw  = cvt + O.off[19];
    const float* outb  = cvt + O.off[20];
    const float* n2g   = cvt + O.off[21];
    const float* n2b   = cvt + O.off[22];
    const float* f1w   = cvt + O.off[23];
    const float* f1b   = cvt + O.off[24];
    const float* f2w   = cvt + O.off[25];
    const float* f2b_  = cvt + O.off[26];
    const float* gng   = cvt + O.off[27];
    const float* gnb   = cvt + O.off[28];
    const float* gwih  = cvt + O.off[29];
    const float* gwhh  = cvt + O.off[30];
    const float* gbih  = cvt + O.off[31];
    const float* gbhh  = cvt + O.off[32];
    const float* gatew = cvt + O.off[33];
    const float* gateb = cvt + O.off[34];

    float* fbase = cvt + ((total + 63) & ~63);
    float* hm   = fbase;                 // 8388608 floats (also GAT output, in place)
    float* Xn   = hm + 8388608;          // 1049088
    float* hnf  = Xn + 1049088;          // 32768
    float* adjw = hnf + 32768;           // 8192
    float* hout = adjw + 8192;           // 65536

    k_detect<<<1, 256, 0, stream>>>((const unsigned*)d_in[0], flag);
    k_convert<<<(total + 255) / 256, 256, 0, stream>>>(P, O, total, flag, cvt);
    k_cnn<<<512, 256, 0, stream>>>(x, c1w, c1b, bn1g, bn1b, bn1m, bn1v,
                                   c2w, c2b, bn2g, bn2b, bn2m, bn2v, hm);
    k_fft<<<512, 512, 0, stream>>>(x, Xn);
    k_havg<<<512, 64, 0, stream>>>(hm, hnf);
    k_adj<<<32, 256, 0, stream>>>(Xn, hnf, prior, logw, adjw, d_out, flag);
    k_gat<<<8192, 256, 0, stream>>>(hm, adjw, n1g, n1b, qkvw, qkvb, outw, outb,
                                    n2g, n2b, f1w, f1b, f2w, f2b_, gng, gnb);
    k_gru<<<1024, 192, 0, stream>>>(hm, gwih, gwhh, gbih, gbhh, hout);
    k_readout<<<32, 128, 0, stream>>>(hout, gatew, gateb, d_out, flag);
}

// Round 3
// 3510.258 us; speedup vs baseline: 1.2185x; 1.2185x over previous
//
#include <hip/hip_runtime.h>
#include <hip/hip_bf16.h>
#include <math.h>

typedef __hip_bfloat16 bf16;

__device__ __forceinline__ float b2f(bf16 v) { return __bfloat162float(v); }
__device__ __forceinline__ bf16 f2b(float v) { return __float2bfloat16(v); }
__device__ __forceinline__ float bflo(unsigned u) { return __uint_as_float(u << 16); }
__device__ __forceinline__ float bfhi(unsigned u) { return __uint_as_float(u & 0xffff0000u); }
__device__ __forceinline__ float geluf(float x) { return 0.5f * x * (1.0f + erff(x * 0.70710678118654752f)); }
__device__ __forceinline__ float sigmoidf_(float x) { return 1.0f / (1.0f + __expf(-x)); }

// round-to-nearest-even fp32 -> bf16 bit pack (two values -> one dword)
__device__ __forceinline__ unsigned pack2bf(float a, float b) {
    unsigned ua = __float_as_uint(a); ua = (ua + 0x7FFFu + ((ua >> 16) & 1u)) >> 16;
    unsigned ub = __float_as_uint(b); ub = (ub + 0x7FFFu + ((ub >> 16) & 1u)) >> 16;
    return ua | (ub << 16);
}

// dot of 64 fp32 (LDS) with 64 fp32 (global, 16B-aligned row)
__device__ __forceinline__ float dot64f(const float* a, const float* w) {
    const float4* wp = reinterpret_cast<const float4*>(w);
    float acc = 0.f;
#pragma unroll
    for (int v = 0; v < 16; v++) {
        float4 u = wp[v];
        const float* ar = a + v * 4;
        acc += ar[0] * u.x + ar[1] * u.y + ar[2] * u.z + ar[3] * u.w;
    }
    return acc;
}

// dot of 64 fp32 (LDS) with 64 bf16 packed pairs (LDS, stride-padded row)
__device__ __forceinline__ float dot64L(const float* a, const unsigned* w) {
    float acc = 0.f;
#pragma unroll
    for (int k = 0; k < 32; k++) {
        unsigned u = w[k];
        acc += a[2 * k] * bflo(u) + a[2 * k + 1] * bfhi(u);
    }
    return acc;
}

__device__ __forceinline__ float dot128L(const float* a, const unsigned* w) {
    float acc = 0.f;
#pragma unroll
    for (int k = 0; k < 64; k++) {
        unsigned u = w[k];
        acc += a[2 * k] * bflo(u) + a[2 * k + 1] * bfhi(u);
    }
    return acc;
}

// coalesced global fp32 -> LDS packed bf16 (rows x (2*halfcols)), row stride in uints
__device__ __forceinline__ void load_w_bf16(const float* __restrict__ src, unsigned* dst,
                                            int rows, int halfcols, int stride, int t)
{
    int total = rows * halfcols;
    for (int i = t; i < total; i += 256) {
        int j = i / halfcols, k = i - j * halfcols;
        const float* s = src + (size_t)(j * halfcols + k) * 2;
        dst[j * stride + k] = pack2bf(s[0], s[1]);
    }
}

// ========================== K0a: dtype detector ==============================
__global__ __launch_bounds__(256) void k_detect(const unsigned* __restrict__ x, int* __restrict__ flag)
{
    __shared__ int cnt;
    if (threadIdx.x == 0) cnt = 0;
    __syncthreads();
    unsigned u = x[threadIdx.x] & 0xFFFFu;
    float f = __uint_as_float(u << 16);
    float a = fabsf(f);
    int sane = (f == 0.0f) || (a > 1e-8f && a < 1e4f);
    atomicAdd(&cnt, sane);
    __syncthreads();
    if (threadIdx.x == 0) *flag = (cnt >= 160) ? 1 : 0;
}

// ========================== K0b: canonicalize to fp32 ========================
struct InPtrs { const void* p[35]; };
struct InOffs { int off[35]; int sz[35]; };

__global__ __launch_bounds__(256) void k_convert(InPtrs P, InOffs O, int total,
                                                 const int* __restrict__ flag,
                                                 float* __restrict__ cvt)
{
    int idx = blockIdx.x * 256 + threadIdx.x;
    if (idx >= total) return;
    int isb = *flag;
    float v = 0.f;
#pragma unroll 1
    for (int s = 0; s < 35; s++) {
        int rel = idx - O.off[s];
        if (rel >= 0 && rel < O.sz[s]) {
            v = isb ? b2f(((const bf16*)P.p[s])[rel]) : ((const float*)P.p[s])[rel];
            break;
        }
    }
    cvt[idx] = v;
}

// =============================== K1: fused CNN ===============================
__global__ __launch_bounds__(256) void k_cnn(
    const float* __restrict__ x, const float* __restrict__ c1w, const float* __restrict__ c1b,
    const float* __restrict__ bn1g, const float* __restrict__ bn1b, const float* __restrict__ bn1m, const float* __restrict__ bn1v,
    const float* __restrict__ c2w, const float* __restrict__ c2b,
    const float* __restrict__ bn2g, const float* __restrict__ bn2b, const float* __restrict__ bn2m, const float* __restrict__ bn2v,
    float* __restrict__ h_main)
{
    __shared__ float xs[1056];
    __shared__ float h1[32][261];
    __shared__ float w1[32 * 7];
    __shared__ float A1[32], B1[32];
    __shared__ float w2[64 * 160];
    __shared__ float A2[64], B2[64];
    int bc = blockIdx.x, t = threadIdx.x;
    for (int i = t; i < 224; i += 256) w1[i] = c1w[i];
    for (int i = t; i < 10240; i += 256) w2[i] = c2w[i];
    if (t < 32) {
        float s = bn1g[t] * rsqrtf(bn1v[t] + 1e-5f);
        A1[t] = s; B1[t] = (c1b[t] - bn1m[t]) * s + bn1b[t];
    } else if (t < 96) {
        int d = t - 32;
        float s = bn2g[d] * rsqrtf(bn2v[d] + 1e-5f);
        A2[d] = s; B2[d] = (c2b[d] - bn2m[d]) * s + bn2b[d];
    }
    __syncthreads();
    const float* xrow = x + (size_t)bc * 4096;
    for (int tile = 0; tile < 4; tile++) {
        int X0 = 1024 * tile - 11;
        for (int i = t; i < 1056; i += 256) {
            int g = X0 + i;
            xs[i] = (g >= 0 && g < 4096) ? xrow[g] : 0.0f;
        }
        __syncthreads();
        for (int o = t; o < 32 * 260; o += 256) {
            int ic = o / 260, j = o % 260;
            int t1p = 256 * tile - 2 + j;
            float res = 0.0f;
            if (t1p >= 0 && t1p < 1024) {
                const float* wr = &w1[ic * 7];
                float a = A1[ic], bb = B1[ic];
                float mx = -3.4e38f;
#pragma unroll
                for (int q = 0; q < 4; q++) {
                    float acc = 0.f;
#pragma unroll
                    for (int k = 0; k < 7; k++) acc += xs[4 * j + q + k] * wr[k];
                    mx = fmaxf(mx, geluf(acc * a + bb));
                }
                res = mx;
            }
            h1[ic][j] = res;
        }
        __syncthreads();
        int p = t & 63, dg = t >> 6;
        float acc[16][4];
#pragma unroll
        for (int dd = 0; dd < 16; dd++)
#pragma unroll
            for (int q = 0; q < 4; q++) acc[dd][q] = 0.f;
        for (int ic = 0; ic < 32; ic++) {
            float dreg[8];
#pragma unroll
            for (int m = 0; m < 8; m++) dreg[m] = h1[ic][4 * p + m];
#pragma unroll
            for (int dd = 0; dd < 16; dd++) {
                const float* wk = &w2[(dg * 16 + dd) * 160 + ic * 5];
#pragma unroll
                for (int k = 0; k < 5; k++) {
                    float w = wk[k];
                    acc[dd][0] += dreg[k] * w;
                    acc[dd][1] += dreg[k + 1] * w;
                    acc[dd][2] += dreg[k + 2] * w;
                    acc[dd][3] += dreg[k + 3] * w;
                }
            }
        }
        int tp = tile * 64 + p;
        float* dst = h_main + (size_t)bc * 16384 + (size_t)tp * 64 + dg * 16;
#pragma unroll
        for (int dd = 0; dd < 16; dd++) {
            int d = dg * 16 + dd;
            float a = A2[d], bb = B2[d];
            float v = fmaxf(fmaxf(geluf(acc[dd][0] * a + bb), geluf(acc[dd][1] * a + bb)),
                            fmaxf(geluf(acc[dd][2] * a + bb), geluf(acc[dd][3] * a + bb)));
            dst[dd] = v;
        }
        __syncthreads();
    }
}

// =============================== K2: FFT + spec norm =========================
__global__ __launch_bounds__(512) void k_fft(const float* __restrict__ x, float* __restrict__ Xn)
{
    __shared__ float re[4096];
    __shared__ float im[4096];
    __shared__ float red[8];
    int bc = blockIdx.x, t = threadIdx.x;
    const float* xr = x + (size_t)bc * 4096;
    for (int i = t; i < 4096; i += 512) {
        int r = __brev((unsigned)i) >> 20;
        re[r] = xr[i];
        im[r] = 0.f;
    }
    __syncthreads();
    for (int s = 1; s <= 12; s++) {
        int half = 1 << (s - 1);
        float ang = -6.283185307179586f / (float)(1 << s);
        for (int m = t; m < 2048; m += 512) {
            int j = m & (half - 1);
            int pos = ((m >> (s - 1)) << s) | j;
            float sn, cs;
            __sincosf(ang * (float)j, &sn, &cs);
            float ur = re[pos], ui = im[pos];
            float vr = re[pos + half], vi = im[pos + half];
            float tr = vr * cs - vi * sn;
            float ti = vr * sn + vi * cs;
            re[pos] = ur + tr; im[pos] = ui + ti;
            re[pos + half] = ur - tr; im[pos + half] = ui - ti;
        }
        __syncthreads();
    }
    float mag[5];
    float ss = 0.f;
    int cnt = 0;
    for (int f = t; f <= 2048; f += 512) {
        float m2 = re[f] * re[f] + im[f] * im[f];
        mag[cnt++] = sqrtf(m2);
        ss += m2;
    }
    for (int off = 32; off; off >>= 1) ss += __shfl_xor(ss, off, 64);
    if ((t & 63) == 0) red[t >> 6] = ss;
    __syncthreads();
    float tot = 0.f;
#pragma unroll
    for (int i = 0; i < 8; i++) tot += red[i];
    float inv = 1.0f / (sqrtf(tot) + 1e-8f);
    cnt = 0;
    for (int f = t; f <= 2048; f += 512) Xn[(size_t)bc * 2049 + f] = mag[cnt++] * inv;
}

// =============================== K3: h_avg -> hn =============================
__global__ __launch_bounds__(64) void k_havg(const float* __restrict__ hm, float* __restrict__ hnf)
{
    int bc = blockIdx.x, d = threadIdx.x;
    const float* base = hm + (size_t)bc * 16384;
    float s = 0.f;
    for (int tp = 0; tp < 256; tp++) s += base[tp * 64 + d];
    float avg = s * (1.0f / 256.0f);
    float tot = avg;
    for (int off = 32; off; off >>= 1) tot += __shfl_xor(tot, off, 64);
    float hc = avg - tot * (1.0f / 64.0f);
    float sq = hc * hc;
    for (int off = 32; off; off >>= 1) sq += __shfl_xor(sq, off, 64);
    hnf[bc * 64 + d] = hc / (sqrtf(sq) + 1e-8f);
}

// =============================== K4: adjacency ===============================
__global__ __launch_bounds__(256) void k_adj(
    const float* __restrict__ Xn, const float* __restrict__ hnf,
    const float* __restrict__ prior, const float* __restrict__ logw,
    float* __restrict__ adjw, void* __restrict__ out, const int* __restrict__ flag)
{
    __shared__ float xt[16][257];
    __shared__ float hh[16 * 64];
    int b = blockIdx.x, t = threadIdx.x;
    int c = t >> 4, e = t & 15;
    for (int i = t; i < 1024; i += 256) hh[i] = hnf[b * 1024 + i];
    __syncthreads();
    float fc = 0.f;
    for (int d = 0; d < 64; d++) fc += hh[c * 64 + d] * hh[e * 64 + d];
    float sc = 0.f;
    const float* Xb = Xn + (size_t)b * 16 * 2049;
    for (int f0 = 0; f0 < 2048; f0 += 256) {
        __syncthreads();
        for (int i = t; i < 16 * 256; i += 256) {
            int rr = i >> 8, ff = i & 255;
            xt[rr][ff] = Xb[rr * 2049 + f0 + ff];
        }
        __syncthreads();
        for (int ff = 0; ff < 256; ff++) sc += xt[c][ff] * xt[e][ff];
    }
    sc += Xb[c * 2049 + 2048] * Xb[e * 2049 + 2048];
    float l0 = logw[0], l1 = logw[1], l2 = logw[2];
    float mx = fmaxf(l0, fmaxf(l1, l2));
    float e0 = __expf(l0 - mx), e1 = __expf(l1 - mx), e2 = __expf(l2 - mx);
    float isum = 1.0f / (e0 + e1 + e2);
    float pr = prior[c * 16 + e] + prior[e * 16 + c];
    float v = (e0 * fc + e1 * sc + e2 * pr) * isum;
    adjw[b * 256 + t] = v;
    if (*flag) ((bf16*)out)[4096 + b * 256 + t] = f2b(v);
    else       ((float*)out)[4096 + b * 256 + t] = v;
}

// =============================== K5: GAT stack ===============================
__device__ __forceinline__ void ln16x64(float (*src)[65], float (*dst)[65],
                                        const float* g, const float* b, int t)
{
    int c = t >> 4, i = t & 15;
    float p0 = src[c][i], p1 = src[c][i + 16], p2 = src[c][i + 32], p3 = src[c][i + 48];
    float s = p0 + p1 + p2 + p3;
    s += __shfl_xor(s, 1, 16); s += __shfl_xor(s, 2, 16);
    s += __shfl_xor(s, 4, 16); s += __shfl_xor(s, 8, 16);
    float mean = s * (1.0f / 64.0f);
    float q0 = p0 - mean, q1 = p1 - mean, q2 = p2 - mean, q3 = p3 - mean;
    float v = q0 * q0 + q1 * q1 + q2 * q2 + q3 * q3;
    v += __shfl_xor(v, 1, 16); v += __shfl_xor(v, 2, 16);
    v += __shfl_xor(v, 4, 16); v += __shfl_xor(v, 8, 16);
    float rstd = rsqrtf(v * (1.0f / 64.0f) + 1e-5f);
    dst[c][i]      = q0 * rstd * g[i]      + b[i];
    dst[c][i + 16] = q1 * rstd * g[i + 16] + b[i + 16];
    dst[c][i + 32] = q2 * rstd * g[i + 32] + b[i + 32];
    dst[c][i + 48] = q3 * rstd * g[i + 48] + b[i + 48];
}

// weights staged per-phase into LDS as packed bf16; odd uint strides (33/65)
// make the lane-divergent row reads 2-way bank aliased (free on CDNA4).
__global__ __launch_bounds__(256) void k_gat(
    float* __restrict__ hm, const float* __restrict__ adjw,
    const float* __restrict__ n1g_, const float* __restrict__ n1b_,
    const float* __restrict__ qw_, const float* __restrict__ qb_,
    const float* __restrict__ ow_, const float* __restrict__ ob_,
    const float* __restrict__ n2g_, const float* __restrict__ n2b_,
    const float* __restrict__ f1w_, const float* __restrict__ f1b_,
    const float* __restrict__ f2w_, const float* __restrict__ f2b_,
    const float* __restrict__ gng, const float* __restrict__ gnb)
{
    __shared__ float ht_s[16][65];
    __shared__ float hn_s[16][65];
    __shared__ float qkv_s[16][193];
    __shared__ float at_s[4][16][17];
    __shared__ float f_s[16][129];
    __shared__ float adj_s[256];
    __shared__ unsigned wbuf[192 * 33];   // max phase region (qw)
    __shared__ float bias_s[192];
    int n = blockIdx.x, t = threadIdx.x;
    int b = n >> 8, tp = n & 255;
    float* src = hm + (size_t)b * 16 * 16384 + (size_t)tp * 64;
#pragma unroll
    for (int r = 0; r < 4; r++) {
        int idx = t + 256 * r, c = idx >> 6, d = idx & 63;
        ht_s[c][d] = src[(size_t)c * 16384 + d];
    }
    adj_s[t] = adjw[b * 256 + t];
    __syncthreads();
    for (int l = 0; l < 2; l++) {
        const float* n1g = n1g_ + l * 64;  const float* n1b = n1b_ + l * 64;
        const float* qw = qw_ + l * 192 * 64;  const float* qb = qb_ + l * 192;
        const float* ow = ow_ + l * 64 * 64;   const float* ob = ob_ + l * 64;
        const float* n2g = n2g_ + l * 64;  const float* n2b = n2b_ + l * 64;
        const float* f1w = f1w_ + l * 128 * 64; const float* f1b = f1b_ + l * 128;
        const float* f2w = f2w_ + l * 64 * 128; const float* f2b = f2b_ + l * 64;
        // LN1 + stage qw (bf16) + qb
        ln16x64(ht_s, hn_s, n1g, n1b, t);
        load_w_bf16(qw, wbuf, 192, 32, 33, t);
        for (int i = t; i < 192; i += 256) bias_s[i] = qb[i];
        __syncthreads();
        // qkv (16,192) from LDS weights
#pragma unroll
        for (int r = 0; r < 12; r++) {
            int idx = t + 256 * r, c = idx / 192, j = idx % 192;
            qkv_s[c][j] = bias_s[j] + dot64L(hn_s[c], wbuf + j * 33);
        }
        __syncthreads();
        // scores
#pragma unroll
        for (int r = 0; r < 4; r++) {
            int idx = t + 256 * r;
            int h = idx >> 8, qc = (idx >> 4) & 15, kc = idx & 15;
            float acc = 0.f;
#pragma unroll
            for (int kk = 0; kk < 16; kk++) acc += qkv_s[qc][h * 16 + kk] * qkv_s[kc][64 + h * 16 + kk];
            at_s[h][qc][kc] = acc * 0.25f + adj_s[qc * 16 + kc];
        }
        __syncthreads();
        if (t < 64) {
            int h = t >> 4, qc = t & 15;
            float mx = -3.4e38f;
#pragma unroll
            for (int kc = 0; kc < 16; kc++) mx = fmaxf(mx, at_s[h][qc][kc]);
            float sum = 0.f; float ex[16];
#pragma unroll
            for (int kc = 0; kc < 16; kc++) { ex[kc] = __expf(at_s[h][qc][kc] - mx); sum += ex[kc]; }
            float inv = 1.0f / sum;
#pragma unroll
            for (int kc = 0; kc < 16; kc++) at_s[h][qc][kc] = ex[kc] * inv;
        }
        __syncthreads();
        // out = attn @ v -> f_s
#pragma unroll
        for (int r = 0; r < 4; r++) {
            int idx = t + 256 * r, c = idx >> 6, e = idx & 63, h = e >> 4;
            float acc = 0.f;
#pragma unroll
            for (int kc = 0; kc < 16; kc++) acc += at_s[h][c][kc] * qkv_s[kc][128 + e];
            f_s[c][e] = acc;
        }
        __syncthreads();
        // stage ow + ob (qw dead)
        load_w_bf16(ow, wbuf, 64, 32, 33, t);
        if (t < 64) bias_s[t] = ob[t];
        __syncthreads();
        // residual proj
#pragma unroll
        for (int r = 0; r < 4; r++) {
            int idx = t + 256 * r, c = idx >> 6, d = idx & 63;
            ht_s[c][d] += bias_s[d] + dot64L(f_s[c], wbuf + d * 33);
        }
        __syncthreads();
        // LN2 + stage f1w + f1b (ow dead)
        ln16x64(ht_s, hn_s, n2g, n2b, t);
        load_w_bf16(f1w, wbuf, 128, 32, 33, t);
        for (int i = t; i < 128; i += 256) bias_s[i] = f1b[i];
        __syncthreads();
        // ffn1 (16,128)
#pragma unroll
        for (int r = 0; r < 8; r++) {
            int idx = t + 256 * r, c = idx >> 7, j = idx & 127;
            f_s[c][j] = geluf(bias_s[j] + dot64L(hn_s[c], wbuf + j * 33));
        }
        __syncthreads();
        // stage f2w + f2b (f1w dead)
        load_w_bf16(f2w, wbuf, 64, 64, 65, t);
        if (t < 64) bias_s[t] = f2b[t];
        __syncthreads();
        // ffn2 + residual
#pragma unroll
        for (int r = 0; r < 4; r++) {
            int idx = t + 256 * r, c = idx >> 6, d = idx & 63;
            ht_s[c][d] += bias_s[d] + dot128L(f_s[c], wbuf + d * 65);
        }
        __syncthreads();
    }
    ln16x64(ht_s, hn_s, gng, gnb, t);
    __syncthreads();
#pragma unroll
    for (int r = 0; r < 4; r++) {
        int idx = t + 256 * r, c = idx >> 6, d = idx & 63;
        src[(size_t)c * 16384 + d] = hn_s[c][d];
    }
}

// =============================== K6: GRU =====================================
__global__ __launch_bounds__(192) void k_gru(
    const float* __restrict__ hs, const float* __restrict__ wih, const float* __restrict__ whh,
    const float* __restrict__ bih, const float* __restrict__ bhh, float* __restrict__ h_out)
{
    __shared__ unsigned wi[192 * 33];
    __shared__ unsigned wh[192 * 33];
    __shared__ float hcur[64];
    __shared__ float xv[64];
    __shared__ float gi[192], gh[192];
    int blk = blockIdx.x;
    int bc = blk >> 1, dir = blk & 1;
    int t = threadIdx.x;
    const float2* wi_g = reinterpret_cast<const float2*>(wih + dir * 192 * 64);
    const float2* wh_g = reinterpret_cast<const float2*>(whh + dir * 192 * 64);
    for (int i = t; i < 192 * 32; i += 192) {
        int j = i >> 5, pcol = i & 31;
        float2 a = wi_g[i];
        float2 c = wh_g[i];
        wi[j * 33 + pcol] = pack2bf(a.x, a.y);
        wh[j * 33 + pcol] = pack2bf(c.x, c.y);
    }
    float bi_r = bih[dir * 192 + t];
    float bh_r = bhh[dir * 192 + t];
    if (t < 64) hcur[t] = 0.f;
    __syncthreads();
    const float* xbase = hs + (size_t)bc * 16384;
    const unsigned* wir = &wi[t * 33];
    const unsigned* whr = &wh[t * 33];
    for (int step = 0; step < 256; step++) {
        int tt = dir ? (255 - step) : step;
        if (t < 64) xv[t] = xbase[tt * 64 + t];
        __syncthreads();
        float a = bi_r, c = bh_r;
#pragma unroll
        for (int p = 0; p < 32; p++) {
            unsigned u = wir[p], v = whr[p];
            a += xv[2 * p] * bflo(u) + xv[2 * p + 1] * bfhi(u);
            c += hcur[2 * p] * bflo(v) + hcur[2 * p + 1] * bfhi(v);
        }
        gi[t] = a; gh[t] = c;
        __syncthreads();
        if (t < 64) {
            float r = sigmoidf_(gi[t] + gh[t]);
            float z = sigmoidf_(gi[64 + t] + gh[64 + t]);
            float nn = tanhf(gi[128 + t] + r * gh[128 + t]);
            hcur[t] = (1.f - z) * nn + z * hcur[t];
        }
        __syncthreads();
    }
    if (t < 64) h_out[bc * 128 + dir * 64 + t] = hcur[t];
}

// =============================== K7: readout =================================
__global__ __launch_bounds__(128) void k_readout(
    const float* __restrict__ h_out, const float* __restrict__ gw, const float* __restrict__ gb,
    void* __restrict__ out, const int* __restrict__ flag)
{
    __shared__ float gate_s[16];
    __shared__ float gws[128];
    int b = blockIdx.x, t = threadIdx.x;
    gws[t] = gw[t];
    __syncthreads();
    int isb = *flag;
    if (t < 16) {
        const float* hr = h_out + (size_t)(b * 16 + t) * 128;
        float acc = gb[0];
        for (int k = 0; k < 128; k++) acc += hr[k] * gws[k];
        float g = sigmoidf_(acc);
        gate_s[t] = g;
        if (isb) ((bf16*)out)[12288 + b * 16 + t] = f2b(g);
        else     ((float*)out)[12288 + b * 16 + t] = g;
    }
    __syncthreads();
    float den = 1e-8f;
#pragma unroll
    for (int c = 0; c < 16; c++) den += gate_s[c];
    float num = 0.f;
#pragma unroll
    for (int c = 0; c < 16; c++) num += h_out[(size_t)(b * 16 + c) * 128 + t] * gate_s[c];
    float v = num / den;
    if (isb) ((bf16*)out)[b * 128 + t] = f2b(v);
    else     ((float*)out)[b * 128 + t] = v;
}

// =============================== launch ======================================
extern "C" void kernel_launch(void* const* d_in, const int* in_sizes, int n_in,
                              void* d_out, int out_size, void* d_ws, size_t ws_size,
                              hipStream_t stream)
{
    int* flag = (int*)d_ws;
    float* cvt = (float*)((char*)d_ws + 256);

    InPtrs P;
    InOffs O;
    int cum = 0;
    for (int i = 0; i < 35; i++) {
        P.p[i] = d_in[i];
        O.off[i] = cum;
        O.sz[i] = in_sizes[i];
        cum += (in_sizes[i] + 7) & ~7;
    }
    int total = cum;

    const float* x     = cvt + O.off[0];
    const float* c1w   = cvt + O.off[1];
    const float* c1b   = cvt + O.off[2];
    const float* bn1g  = cvt + O.off[3];
    const float* bn1b  = cvt + O.off[4];
    const float* bn1m  = cvt + O.off[5];
    const float* bn1v  = cvt + O.off[6];
    const float* c2w   = cvt + O.off[7];
    const float* c2b   = cvt + O.off[8];
    const float* bn2g  = cvt + O.off[9];
    const float* bn2b  = cvt + O.off[10];
    const float* bn2m  = cvt + O.off[11];
    const float* bn2v  = cvt + O.off[12];
    const float* prior = cvt + O.off[13];
    const float* logw  = cvt + O.off[14];
    const float* n1g   = cvt + O.off[15];
    const float* n1b   = cvt + O.off[16];
    const float* qkvw  = cvt + O.off[17];
    const float* qkvb  = cvt + O.off[18];
    const float* outw  = cvt + O.off[19];
    const float* outb  = cvt + O.off[20];
    const float* n2g   = cvt + O.off[21];
    const float* n2b   = cvt + O.off[22];
    const float* f1w   = cvt + O.off[23];
    const float* f1b   = cvt + O.off[24];
    const float* f2w   = cvt + O.off[25];
    const float* f2b_  = cvt + O.off[26];
    const float* gng   = cvt + O.off[27];
    const float* gnb   = cvt + O.off[28];
    const float* gwih  = cvt + O.off[29];
    const float* gwhh  = cvt + O.off[30];
    const float* gbih  = cvt + O.off[31];
    const float* gbhh  = cvt + O.off[32];
    const float* gatew = cvt + O.off[33];
    const float* gateb = cvt + O.off[34];

    float* fbase = cvt + ((total + 63) & ~63);
    float* hm   = fbase;                 // 8388608 floats (GAT in place)
    float* Xn   = hm + 8388608;          // 1049088
    float* hnf  = Xn + 1049088;          // 32768
    float* adjw = hnf + 32768;           // 8192
    float* hout = adjw + 8192;           // 65536

    k_detect<<<1, 256, 0, stream>>>((const unsigned*)d_in[0], flag);
    k_convert<<<(total + 255) / 256, 256, 0, stream>>>(P, O, total, flag, cvt);
    k_cnn<<<512, 256, 0, stream>>>(x, c1w, c1b, bn1g, bn1b, bn1m, bn1v,
                                   c2w, c2b, bn2g, bn2b, bn2m, bn2v, hm);
    k_fft<<<512, 512, 0, stream>>>(x, Xn);
    k_havg<<<512, 64, 0, stream>>>(hm, hnf);
    k_adj<<<32, 256, 0, stream>>>(Xn, hnf, prior, logw, adjw, d_out, flag);
    k_gat<<<8192, 256, 0, stream>>>(hm, adjw, n1g, n1b, qkvw, qkvb, outw, outb,
                                    n2g, n2b, f1w, f1b, f2w, f2b_, gng, gnb);
    k_gru<<<1024, 192, 0, stream>>>(hm, gwih, gwhh, gbih, gbhh, hout);
    k_readout<<<32, 128, 0, stream>>>(hout, gatew, gateb, d_out, flag);
}

// Round 4
// 1616.543 us; speedup vs baseline: 2.6460x; 2.1715x over previous
//
#include <hip/hip_runtime.h>
#include <hip/hip_bf16.h>
#include <math.h>

typedef __hip_bfloat16 bf16;
typedef unsigned short ushort_t;
typedef __attribute__((ext_vector_type(8))) short short8;
typedef __attribute__((ext_vector_type(4))) float f32x4;

__device__ __forceinline__ float b2f(bf16 v) { return __bfloat162float(v); }
__device__ __forceinline__ bf16 f2b(float v) { return __float2bfloat16(v); }
__device__ __forceinline__ float bflo(unsigned u) { return __uint_as_float(u << 16); }
__device__ __forceinline__ float bfhi(unsigned u) { return __uint_as_float(u & 0xffff0000u); }
__device__ __forceinline__ float geluf(float x) { return 0.5f * x * (1.0f + erff(x * 0.70710678118654752f)); }
__device__ __forceinline__ float sigmoidf_(float x) { return 1.0f / (1.0f + __expf(-x)); }

// round-to-nearest-even fp32 -> bf16 bit pack
__device__ __forceinline__ unsigned pack2bf(float a, float b) {
    unsigned ua = __float_as_uint(a); ua = (ua + 0x7FFFu + ((ua >> 16) & 1u)) >> 16;
    unsigned ub = __float_as_uint(b); ub = (ub + 0x7FFFu + ((ub >> 16) & 1u)) >> 16;
    return ua | (ub << 16);
}
__device__ __forceinline__ ushort_t f2bu(float v) {
    unsigned u = __float_as_uint(v);
    u = (u + 0x7FFFu + ((u >> 16) & 1u)) >> 16;
    return (ushort_t)u;
}

// ========================== K0a: dtype detector ==============================
__global__ __launch_bounds__(256) void k_detect(const unsigned* __restrict__ x, int* __restrict__ flag)
{
    __shared__ int cnt;
    if (threadIdx.x == 0) cnt = 0;
    __syncthreads();
    unsigned u = x[threadIdx.x] & 0xFFFFu;
    float f = __uint_as_float(u << 16);
    float a = fabsf(f);
    int sane = (f == 0.0f) || (a > 1e-8f && a < 1e4f);
    atomicAdd(&cnt, sane);
    __syncthreads();
    if (threadIdx.x == 0) *flag = (cnt >= 160) ? 1 : 0;
}

// ========================== K0b: canonicalize to fp32 ========================
struct InPtrs { const void* p[35]; };
struct InOffs { int off[35]; int sz[35]; };

__global__ __launch_bounds__(256) void k_convert(InPtrs P, InOffs O, int total,
                                                 const int* __restrict__ flag,
                                                 float* __restrict__ cvt)
{
    int idx = blockIdx.x * 256 + threadIdx.x;
    if (idx >= total) return;
    int isb = *flag;
    float v = 0.f;
#pragma unroll 1
    for (int s = 0; s < 35; s++) {
        int rel = idx - O.off[s];
        if (rel >= 0 && rel < O.sz[s]) {
            v = isb ? b2f(((const bf16*)P.p[s])[rel]) : ((const float*)P.p[s])[rel];
            break;
        }
    }
    cvt[idx] = v;
}

// ========================== K0c: pack GAT weights to bf16 ====================
// regions (uints): qw 12288 | ow 4096 | f1w 8192 | f2w 8192  (both layers each)
__global__ __launch_bounds__(256) void k_pack(const float* __restrict__ qw, const float* __restrict__ ow,
                                              const float* __restrict__ f1w, const float* __restrict__ f2w,
                                              unsigned* __restrict__ dst)
{
    int i = blockIdx.x * 256 + threadIdx.x;
    if (i >= 32768) return;
    const float* s; int rel;
    if (i < 12288)      { s = qw;  rel = i; }
    else if (i < 16384) { s = ow;  rel = i - 12288; }
    else if (i < 24576) { s = f1w; rel = i - 16384; }
    else                { s = f2w; rel = i - 24576; }
    dst[i] = pack2bf(s[2 * rel], s[2 * rel + 1]);
}

// =============================== K1: fused CNN ===============================
__global__ __launch_bounds__(256) void k_cnn(
    const float* __restrict__ x, const float* __restrict__ c1w, const float* __restrict__ c1b,
    const float* __restrict__ bn1g, const float* __restrict__ bn1b, const float* __restrict__ bn1m, const float* __restrict__ bn1v,
    const float* __restrict__ c2w, const float* __restrict__ c2b,
    const float* __restrict__ bn2g, const float* __restrict__ bn2b, const float* __restrict__ bn2m, const float* __restrict__ bn2v,
    float* __restrict__ h_main)
{
    __shared__ float xs[1056];
    __shared__ float h1[32][261];
    __shared__ float w1[32 * 7];
    __shared__ float A1[32], B1[32];
    __shared__ float w2[64 * 160];
    __shared__ float A2[64], B2[64];
    int bc = blockIdx.x, t = threadIdx.x;
    for (int i = t; i < 224; i += 256) w1[i] = c1w[i];
    for (int i = t; i < 10240; i += 256) w2[i] = c2w[i];
    if (t < 32) {
        float s = bn1g[t] * rsqrtf(bn1v[t] + 1e-5f);
        A1[t] = s; B1[t] = (c1b[t] - bn1m[t]) * s + bn1b[t];
    } else if (t < 96) {
        int d = t - 32;
        float s = bn2g[d] * rsqrtf(bn2v[d] + 1e-5f);
        A2[d] = s; B2[d] = (c2b[d] - bn2m[d]) * s + bn2b[d];
    }
    __syncthreads();
    const float* xrow = x + (size_t)bc * 4096;
    for (int tile = 0; tile < 4; tile++) {
        int X0 = 1024 * tile - 11;
        for (int i = t; i < 1056; i += 256) {
            int g = X0 + i;
            xs[i] = (g >= 0 && g < 4096) ? xrow[g] : 0.0f;
        }
        __syncthreads();
        for (int o = t; o < 32 * 260; o += 256) {
            int ic = o / 260, j = o % 260;
            int t1p = 256 * tile - 2 + j;
            float res = 0.0f;
            if (t1p >= 0 && t1p < 1024) {
                const float* wr = &w1[ic * 7];
                float a = A1[ic], bb = B1[ic];
                float mx = -3.4e38f;
#pragma unroll
                for (int q = 0; q < 4; q++) {
                    float acc = 0.f;
#pragma unroll
                    for (int k = 0; k < 7; k++) acc += xs[4 * j + q + k] * wr[k];
                    mx = fmaxf(mx, geluf(acc * a + bb));
                }
                res = mx;
            }
            h1[ic][j] = res;
        }
        __syncthreads();
        int p = t & 63, dg = t >> 6;
        float acc[16][4];
#pragma unroll
        for (int dd = 0; dd < 16; dd++)
#pragma unroll
            for (int q = 0; q < 4; q++) acc[dd][q] = 0.f;
        for (int ic = 0; ic < 32; ic++) {
            float dreg[8];
#pragma unroll
            for (int m = 0; m < 8; m++) dreg[m] = h1[ic][4 * p + m];
#pragma unroll
            for (int dd = 0; dd < 16; dd++) {
                const float* wk = &w2[(dg * 16 + dd) * 160 + ic * 5];
#pragma unroll
                for (int k = 0; k < 5; k++) {
                    float w = wk[k];
                    acc[dd][0] += dreg[k] * w;
                    acc[dd][1] += dreg[k + 1] * w;
                    acc[dd][2] += dreg[k + 2] * w;
                    acc[dd][3] += dreg[k + 3] * w;
                }
            }
        }
        int tp = tile * 64 + p;
        float* dst = h_main + (size_t)bc * 16384 + (size_t)tp * 64 + dg * 16;
#pragma unroll
        for (int dd = 0; dd < 16; dd++) {
            int d = dg * 16 + dd;
            float a = A2[d], bb = B2[d];
            float v = fmaxf(fmaxf(geluf(acc[dd][0] * a + bb), geluf(acc[dd][1] * a + bb)),
                            fmaxf(geluf(acc[dd][2] * a + bb), geluf(acc[dd][3] * a + bb)));
            dst[dd] = v;
        }
        __syncthreads();
    }
}

// =============================== K2: FFT + spec norm =========================
__global__ __launch_bounds__(512) void k_fft(const float* __restrict__ x, float* __restrict__ Xn)
{
    __shared__ float re[4096];
    __shared__ float im[4096];
    __shared__ float red[8];
    int bc = blockIdx.x, t = threadIdx.x;
    const float* xr = x + (size_t)bc * 4096;
    for (int i = t; i < 4096; i += 512) {
        int r = __brev((unsigned)i) >> 20;
        re[r] = xr[i];
        im[r] = 0.f;
    }
    __syncthreads();
    for (int s = 1; s <= 12; s++) {
        int half = 1 << (s - 1);
        float ang = -6.283185307179586f / (float)(1 << s);
        for (int m = t; m < 2048; m += 512) {
            int j = m & (half - 1);
            int pos = ((m >> (s - 1)) << s) | j;
            float sn, cs;
            __sincosf(ang * (float)j, &sn, &cs);
            float ur = re[pos], ui = im[pos];
            float vr = re[pos + half], vi = im[pos + half];
            float tr = vr * cs - vi * sn;
            float ti = vr * sn + vi * cs;
            re[pos] = ur + tr; im[pos] = ui + ti;
            re[pos + half] = ur - tr; im[pos + half] = ui - ti;
        }
        __syncthreads();
    }
    float mag[5];
    float ss = 0.f;
    int cnt = 0;
    for (int f = t; f <= 2048; f += 512) {
        float m2 = re[f] * re[f] + im[f] * im[f];
        mag[cnt++] = sqrtf(m2);
        ss += m2;
    }
    for (int off = 32; off; off >>= 1) ss += __shfl_xor(ss, off, 64);
    if ((t & 63) == 0) red[t >> 6] = ss;
    __syncthreads();
    float tot = 0.f;
#pragma unroll
    for (int i = 0; i < 8; i++) tot += red[i];
    float inv = 1.0f / (sqrtf(tot) + 1e-8f);
    cnt = 0;
    for (int f = t; f <= 2048; f += 512) Xn[(size_t)bc * 2049 + f] = mag[cnt++] * inv;
}

// =============================== K3: h_avg -> hn =============================
__global__ __launch_bounds__(64) void k_havg(const float* __restrict__ hm, float* __restrict__ hnf)
{
    int bc = blockIdx.x, d = threadIdx.x;
    const float* base = hm + (size_t)bc * 16384;
    float s = 0.f;
    for (int tp = 0; tp < 256; tp++) s += base[tp * 64 + d];
    float avg = s * (1.0f / 256.0f);
    float tot = avg;
    for (int off = 32; off; off >>= 1) tot += __shfl_xor(tot, off, 64);
    float hc = avg - tot * (1.0f / 64.0f);
    float sq = hc * hc;
    for (int off = 32; off; off >>= 1) sq += __shfl_xor(sq, off, 64);
    hnf[bc * 64 + d] = hc / (sqrtf(sq) + 1e-8f);
}

// =============================== K4: adjacency ===============================
__global__ __launch_bounds__(256) void k_adj(
    const float* __restrict__ Xn, const float* __restrict__ hnf,
    const float* __restrict__ prior, const float* __restrict__ logw,
    float* __restrict__ adjw, void* __restrict__ out, const int* __restrict__ flag)
{
    __shared__ float xt[16][257];
    __shared__ float hh[16 * 64];
    int b = blockIdx.x, t = threadIdx.x;
    int c = t >> 4, e = t & 15;
    for (int i = t; i < 1024; i += 256) hh[i] = hnf[b * 1024 + i];
    __syncthreads();
    float fc = 0.f;
    for (int d = 0; d < 64; d++) fc += hh[c * 64 + d] * hh[e * 64 + d];
    float sc = 0.f;
    const float* Xb = Xn + (size_t)b * 16 * 2049;
    for (int f0 = 0; f0 < 2048; f0 += 256) {
        __syncthreads();
        for (int i = t; i < 16 * 256; i += 256) {
            int rr = i >> 8, ff = i & 255;
            xt[rr][ff] = Xb[rr * 2049 + f0 + ff];
        }
        __syncthreads();
        for (int ff = 0; ff < 256; ff++) sc += xt[c][ff] * xt[e][ff];
    }
    sc += Xb[c * 2049 + 2048] * Xb[e * 2049 + 2048];
    float l0 = logw[0], l1 = logw[1], l2 = logw[2];
    float mx = fmaxf(l0, fmaxf(l1, l2));
    float e0 = __expf(l0 - mx), e1 = __expf(l1 - mx), e2 = __expf(l2 - mx);
    float isum = 1.0f / (e0 + e1 + e2);
    float pr = prior[c * 16 + e] + prior[e * 16 + c];
    float v = (e0 * fc + e1 * sc + e2 * pr) * isum;
    adjw[b * 256 + t] = v;
    if (*flag) ((bf16*)out)[4096 + b * 256 + t] = f2b(v);
    else       ((float*)out)[4096 + b * 256 + t] = v;
}

// =============================== K5: GAT stack (MFMA) ========================
// One wave per (b,tp); 4 waves/block; no __syncthreads (all LDS is per-wave).
// MFMA layouts (verified m89/m91/m120): A[m=lane&15][k=quad*8+j],
// B[k=quad*8+j][n=lane&15], C/D col=lane&15 row=quad*4+reg.
__device__ __forceinline__ void ln_wave(const float (*ht)[68], ushort_t (*out)[72],
                                        const float* __restrict__ g, const float* __restrict__ bp,
                                        int quad, int lo)
{
    float v[16];
    const float4* row = (const float4*)(&ht[lo][quad * 16]);
#pragma unroll
    for (int i = 0; i < 4; i++) {
        float4 a = row[i];
        v[4 * i] = a.x; v[4 * i + 1] = a.y; v[4 * i + 2] = a.z; v[4 * i + 3] = a.w;
    }
    float s = 0.f;
#pragma unroll
    for (int i = 0; i < 16; i++) s += v[i];
    s += __shfl_xor(s, 16); s += __shfl_xor(s, 32);
    float mean = s * (1.0f / 64.0f);
    float q = 0.f;
#pragma unroll
    for (int i = 0; i < 16; i++) { float d = v[i] - mean; q += d * d; }
    q += __shfl_xor(q, 16); q += __shfl_xor(q, 32);
    float rstd = rsqrtf(q * (1.0f / 64.0f) + 1e-5f);
    const float4* gp = (const float4*)(g + quad * 16);
    const float4* bb4 = (const float4*)(bp + quad * 16);
    unsigned* orow = (unsigned*)(&out[lo][quad * 16]);
#pragma unroll
    for (int i = 0; i < 4; i++) {
        float4 gg = gp[i], bb = bb4[i];
        float o0 = (v[4 * i] - mean) * rstd * gg.x + bb.x;
        float o1 = (v[4 * i + 1] - mean) * rstd * gg.y + bb.y;
        float o2 = (v[4 * i + 2] - mean) * rstd * gg.z + bb.z;
        float o3 = (v[4 * i + 3] - mean) * rstd * gg.w + bb.w;
        orow[2 * i] = pack2bf(o0, o1);
        orow[2 * i + 1] = pack2bf(o2, o3);
    }
}

__global__ __launch_bounds__(256) void k_gat(
    float* __restrict__ hm, const float* __restrict__ adjw,
    const ushort_t* __restrict__ wpk,
    const float* __restrict__ qb_, const float* __restrict__ ob_,
    const float* __restrict__ f1b_, const float* __restrict__ f2b_,
    const float* __restrict__ n1g_, const float* __restrict__ n1b_,
    const float* __restrict__ n2g_, const float* __restrict__ n2b_,
    const float* __restrict__ gng, const float* __restrict__ gnb)
{
    __shared__ float htw_all[4][16][68];
    __shared__ ushort_t hnw_all[4][16][72];
    __shared__ ushort_t qkb_all[4][16][200];
    __shared__ ushort_t pb_all[4][16][72];
    __shared__ ushort_t vt_all[4][64][24];
    int t = threadIdx.x;
    int w = t >> 6, l = t & 63;
    int quad = l >> 4, lo = l & 15;
    int n = blockIdx.x * 4 + w;
    int b = n >> 8, tp = n & 255;
    float (*htw)[68] = htw_all[w];
    ushort_t (*hnw)[72] = hnw_all[w];
    ushort_t (*qkb)[200] = qkb_all[w];
    ushort_t (*pb)[72] = pb_all[w];
    ushort_t (*vt)[24] = vt_all[w];
    float* src = hm + (size_t)b * 16 * 16384 + (size_t)tp * 64;
#pragma unroll
    for (int c = 0; c < 16; c++) htw[c][l] = src[(size_t)c * 16384 + l];
    float adjr[4];
#pragma unroll
    for (int r = 0; r < 4; r++) adjr[r] = adjw[b * 256 + (quad * 4 + r) * 16 + lo];

    for (int layer = 0; layer < 2; layer++) {
        const ushort_t* wq  = wpk + layer * 12288;
        const ushort_t* wo  = wpk + 24576 + layer * 4096;
        const ushort_t* wf1 = wpk + 32768 + layer * 8192;
        const ushort_t* wf2 = wpk + 49152 + layer * 8192;
        const float* qb = qb_ + layer * 192;
        const float* ob = ob_ + layer * 64;
        const float* f1b = f1b_ + layer * 128;
        const float* f2b = f2b_ + layer * 64;

        // ---- LN1 -> hnw (bf16) ----
        ln_wave(htw, hnw, n1g_ + layer * 64, n1b_ + layer * 64, quad, lo);

        // ---- qkv GEMM: (16x64)@(64x192) ----
        short8 a0 = *(const short8*)&hnw[lo][quad * 8];
        short8 a1 = *(const short8*)&hnw[lo][32 + quad * 8];
#pragma unroll
        for (int nt = 0; nt < 12; nt++) {
            const ushort_t* wr = wq + (nt * 16 + lo) * 64 + quad * 8;
            short8 b0 = *(const short8*)wr;
            short8 b1 = *(const short8*)(wr + 32);
            f32x4 acc = {0.f, 0.f, 0.f, 0.f};
            acc = __builtin_amdgcn_mfma_f32_16x16x32_bf16(a0, b0, acc, 0, 0, 0);
            acc = __builtin_amdgcn_mfma_f32_16x16x32_bf16(a1, b1, acc, 0, 0, 0);
            float bias = qb[nt * 16 + lo];
            if (nt < 8) {
#pragma unroll
                for (int r = 0; r < 4; r++) qkb[quad * 4 + r][nt * 16 + lo] = f2bu(acc[r] + bias);
            } else {
#pragma unroll
                for (int r = 0; r < 4; r++) vt[(nt - 8) * 16 + lo][quad * 4 + r] = f2bu(acc[r] + bias);
            }
        }

        // ---- attention scores + softmax (per head, K=16 zero-padded to 32) ----
        short8 zf = {0, 0, 0, 0, 0, 0, 0, 0};
#pragma unroll
        for (int h = 0; h < 4; h++) {
            short8 qf = zf, kf = zf;
            if (quad < 2) {
                qf = *(const short8*)&qkb[lo][h * 16 + quad * 8];
                kf = *(const short8*)&qkb[lo][64 + h * 16 + quad * 8];
            }
            f32x4 s4 = {0.f, 0.f, 0.f, 0.f};
            s4 = __builtin_amdgcn_mfma_f32_16x16x32_bf16(qf, kf, s4, 0, 0, 0);
#pragma unroll
            for (int r = 0; r < 4; r++) {
                float sv = s4[r] * 0.25f + adjr[r];
                float mx = sv;
                mx = fmaxf(mx, __shfl_xor(mx, 1));
                mx = fmaxf(mx, __shfl_xor(mx, 2));
                mx = fmaxf(mx, __shfl_xor(mx, 4));
                mx = fmaxf(mx, __shfl_xor(mx, 8));
                float e = __expf(sv - mx);
                float sm = e;
                sm += __shfl_xor(sm, 1);
                sm += __shfl_xor(sm, 2);
                sm += __shfl_xor(sm, 4);
                sm += __shfl_xor(sm, 8);
                pb[quad * 4 + r][h * 16 + lo] = f2bu(e / sm);
            }
        }
        // ---- PV: per head (16x16)@(16x16), K padded; O -> qkb (A-layout src) ----
#pragma unroll
        for (int h = 0; h < 4; h++) {
            short8 pf = zf, vf = zf;
            if (quad < 2) {
                pf = *(const short8*)&pb[lo][h * 16 + quad * 8];
                vf = *(const short8*)&vt[h * 16 + lo][quad * 8];
            }
            f32x4 oc = {0.f, 0.f, 0.f, 0.f};
            oc = __builtin_amdgcn_mfma_f32_16x16x32_bf16(pf, vf, oc, 0, 0, 0);
#pragma unroll
            for (int r = 0; r < 4; r++) qkb[quad * 4 + r][h * 16 + lo] = f2bu(oc[r]);
        }
        // ---- proj GEMM + residual ----
        short8 pa0 = *(const short8*)&qkb[lo][quad * 8];
        short8 pa1 = *(const short8*)&qkb[lo][32 + quad * 8];
#pragma unroll
        for (int nt = 0; nt < 4; nt++) {
            const ushort_t* wr = wo + (nt * 16 + lo) * 64 + quad * 8;
            short8 b0 = *(const short8*)wr;
            short8 b1 = *(const short8*)(wr + 32);
            f32x4 acc = {0.f, 0.f, 0.f, 0.f};
            acc = __builtin_amdgcn_mfma_f32_16x16x32_bf16(pa0, b0, acc, 0, 0, 0);
            acc = __builtin_amdgcn_mfma_f32_16x16x32_bf16(pa1, b1, acc, 0, 0, 0);
            float bias = ob[nt * 16 + lo];
#pragma unroll
            for (int r = 0; r < 4; r++) htw[quad * 4 + r][nt * 16 + lo] += acc[r] + bias;
        }
        // ---- LN2 -> hnw ----
        ln_wave(htw, hnw, n2g_ + layer * 64, n2b_ + layer * 64, quad, lo);
        // ---- ffn1: (16x64)@(64x128) + GELU -> qkb ----
        short8 fa0 = *(const short8*)&hnw[lo][quad * 8];
        short8 fa1 = *(const short8*)&hnw[lo][32 + quad * 8];
#pragma unroll
        for (int nt = 0; nt < 8; nt++) {
            const ushort_t* wr = wf1 + (nt * 16 + lo) * 64 + quad * 8;
            short8 b0 = *(const short8*)wr;
            short8 b1 = *(const short8*)(wr + 32);
            f32x4 acc = {0.f, 0.f, 0.f, 0.f};
            acc = __builtin_amdgcn_mfma_f32_16x16x32_bf16(fa0, b0, acc, 0, 0, 0);
            acc = __builtin_amdgcn_mfma_f32_16x16x32_bf16(fa1, b1, acc, 0, 0, 0);
            float bias = f1b[nt * 16 + lo];
#pragma unroll
            for (int r = 0; r < 4; r++) qkb[quad * 4 + r][nt * 16 + lo] = f2bu(geluf(acc[r] + bias));
        }
        // ---- ffn2: (16x128)@(128x64) + residual ----
        short8 ga[4];
#pragma unroll
        for (int kb = 0; kb < 4; kb++) ga[kb] = *(const short8*)&qkb[lo][kb * 32 + quad * 8];
#pragma unroll
        for (int nt = 0; nt < 4; nt++) {
            const ushort_t* wr = wf2 + (nt * 16 + lo) * 128 + quad * 8;
            f32x4 acc = {0.f, 0.f, 0.f, 0.f};
#pragma unroll
            for (int kb = 0; kb < 4; kb++) {
                short8 bb = *(const short8*)(wr + kb * 32);
                acc = __builtin_amdgcn_mfma_f32_16x16x32_bf16(ga[kb], bb, acc, 0, 0, 0);
            }
            float bias = f2b[nt * 16 + lo];
#pragma unroll
            for (int r = 0; r < 4; r++) htw[quad * 4 + r][nt * 16 + lo] += acc[r] + bias;
        }
    }
    // ---- final LN -> fp32 global (in place) ----
    {
        float v[16];
        const float4* row = (const float4*)(&htw[lo][quad * 16]);
#pragma unroll
        for (int i = 0; i < 4; i++) {
            float4 a = row[i];
            v[4 * i] = a.x; v[4 * i + 1] = a.y; v[4 * i + 2] = a.z; v[4 * i + 3] = a.w;
        }
        float s = 0.f;
#pragma unroll
        for (int i = 0; i < 16; i++) s += v[i];
        s += __shfl_xor(s, 16); s += __shfl_xor(s, 32);
        float mean = s * (1.0f / 64.0f);
        float q = 0.f;
#pragma unroll
        for (int i = 0; i < 16; i++) { float d = v[i] - mean; q += d * d; }
        q += __shfl_xor(q, 16); q += __shfl_xor(q, 32);
        float rstd = rsqrtf(q * (1.0f / 64.0f) + 1e-5f);
        const float4* gp = (const float4*)(gng + quad * 16);
        const float4* bb4 = (const float4*)(gnb + quad * 16);
        float4* orow = (float4*)(src + (size_t)lo * 16384 + quad * 16);
#pragma unroll
        for (int i = 0; i < 4; i++) {
            float4 gg = gp[i], bb = bb4[i];
            float4 o;
            o.x = (v[4 * i] - mean) * rstd * gg.x + bb.x;
            o.y = (v[4 * i + 1] - mean) * rstd * gg.y + bb.y;
            o.z = (v[4 * i + 2] - mean) * rstd * gg.z + bb.z;
            o.w = (v[4 * i + 3] - mean) * rstd * gg.w + bb.w;
            orow[i] = o;
        }
    }
}

// =============================== K6: GRU =====================================
__global__ __launch_bounds__(192) void k_gru(
    const float* __restrict__ hs, const float* __restrict__ wih, const float* __restrict__ whh,
    const float* __restrict__ bih, const float* __restrict__ bhh, float* __restrict__ h_out)
{
    __shared__ unsigned wi[192 * 33];
    __shared__ unsigned wh[192 * 33];
    __shared__ float hcur[64];
    __shared__ float xv[64];
    __shared__ float gi[192], gh[192];
    int blk = blockIdx.x;
    int bc = blk >> 1, dir = blk & 1;
    int t = threadIdx.x;
    const float2* wi_g = reinterpret_cast<const float2*>(wih + dir * 192 * 64);
    const float2* wh_g = reinterpret_cast<const float2*>(whh + dir * 192 * 64);
    for (int i = t; i < 192 * 32; i += 192) {
        int j = i >> 5, pcol = i & 31;
        float2 a = wi_g[i];
        float2 c = wh_g[i];
        wi[j * 33 + pcol] = pack2bf(a.x, a.y);
        wh[j * 33 + pcol] = pack2bf(c.x, c.y);
    }
    float bi_r = bih[dir * 192 + t];
    float bh_r = bhh[dir * 192 + t];
    if (t < 64) hcur[t] = 0.f;
    __syncthreads();
    const float* xbase = hs + (size_t)bc * 16384;
    const unsigned* wir = &wi[t * 33];
    const unsigned* whr = &wh[t * 33];
    for (int step = 0; step < 256; step++) {
        int tt = dir ? (255 - step) : step;
        if (t < 64) xv[t] = xbase[tt * 64 + t];
        __syncthreads();
        float a = bi_r, c = bh_r;
#pragma unroll
        for (int p = 0; p < 32; p++) {
            unsigned u = wir[p], v = whr[p];
            a += xv[2 * p] * bflo(u) + xv[2 * p + 1] * bfhi(u);
            c += hcur[2 * p] * bflo(v) + hcur[2 * p + 1] * bfhi(v);
        }
        gi[t] = a; gh[t] = c;
        __syncthreads();
        if (t < 64) {
            float r = sigmoidf_(gi[t] + gh[t]);
            float z = sigmoidf_(gi[64 + t] + gh[64 + t]);
            float nn = tanhf(gi[128 + t] + r * gh[128 + t]);
            hcur[t] = (1.f - z) * nn + z * hcur[t];
        }
        __syncthreads();
    }
    if (t < 64) h_out[bc * 128 + dir * 64 + t] = hcur[t];
}

// =============================== K7: readout =================================
__global__ __launch_bounds__(128) void k_readout(
    const float* __restrict__ h_out, const float* __restrict__ gw, const float* __restrict__ gb,
    void* __restrict__ out, const int* __restrict__ flag)
{
    __shared__ float gate_s[16];
    __shared__ float gws[128];
    int b = blockIdx.x, t = threadIdx.x;
    gws[t] = gw[t];
    __syncthreads();
    int isb = *flag;
    if (t < 16) {
        const float* hr = h_out + (size_t)(b * 16 + t) * 128;
        float acc = gb[0];
        for (int k = 0; k < 128; k++) acc += hr[k] * gws[k];
        float g = sigmoidf_(acc);
        gate_s[t] = g;
        if (isb) ((bf16*)out)[12288 + b * 16 + t] = f2b(g);
        else     ((float*)out)[12288 + b * 16 + t] = g;
    }
    __syncthreads();
    float den = 1e-8f;
#pragma unroll
    for (int c = 0; c < 16; c++) den += gate_s[c];
    float num = 0.f;
#pragma unroll
    for (int c = 0; c < 16; c++) num += h_out[(size_t)(b * 16 + c) * 128 + t] * gate_s[c];
    float v = num / den;
    if (isb) ((bf16*)out)[b * 128 + t] = f2b(v);
    else     ((float*)out)[b * 128 + t] = v;
}

// =============================== launch ======================================
extern "C" void kernel_launch(void* const* d_in, const int* in_sizes, int n_in,
                              void* d_out, int out_size, void* d_ws, size_t ws_size,
                              hipStream_t stream)
{
    int* flag = (int*)d_ws;
    float* cvt = (float*)((char*)d_ws + 256);

    InPtrs P;
    InOffs O;
    int cum = 0;
    for (int i = 0; i < 35; i++) {
        P.p[i] = d_in[i];
        O.off[i] = cum;
        O.sz[i] = in_sizes[i];
        cum += (in_sizes[i] + 7) & ~7;
    }
    int total = cum;

    const float* x     = cvt + O.off[0];
    const float* c1w   = cvt + O.off[1];
    const float* c1b   = cvt + O.off[2];
    const float* bn1g  = cvt + O.off[3];
    const float* bn1b  = cvt + O.off[4];
    const float* bn1m  = cvt + O.off[5];
    const float* bn1v  = cvt + O.off[6];
    const float* c2w   = cvt + O.off[7];
    const float* c2b   = cvt + O.off[8];
    const float* bn2g  = cvt + O.off[9];
    const float* bn2b  = cvt + O.off[10];
    const float* bn2m  = cvt + O.off[11];
    const float* bn2v  = cvt + O.off[12];
    const float* prior = cvt + O.off[13];
    const float* logw  = cvt + O.off[14];
    const float* n1g   = cvt + O.off[15];
    const float* n1b   = cvt + O.off[16];
    const float* qkvw  = cvt + O.off[17];
    const float* qkvb  = cvt + O.off[18];
    const float* outw  = cvt + O.off[19];
    const float* outb  = cvt + O.off[20];
    const float* n2g   = cvt + O.off[21];
    const float* n2b   = cvt + O.off[22];
    const float* f1w   = cvt + O.off[23];
    const float* f1b   = cvt + O.off[24];
    const float* f2w   = cvt + O.off[25];
    const float* f2b_  = cvt + O.off[26];
    const float* gng   = cvt + O.off[27];
    const float* gnb   = cvt + O.off[28];
    const float* gwih  = cvt + O.off[29];
    const float* gwhh  = cvt + O.off[30];
    const float* gbih  = cvt + O.off[31];
    const float* gbhh  = cvt + O.off[32];
    const float* gatew = cvt + O.off[33];
    const float* gateb = cvt + O.off[34];

    float* fbase = cvt + ((total + 63) & ~63);
    float* hm   = fbase;                 // 8388608 floats (GAT in place)
    float* Xn   = hm + 8388608;          // 1049088
    float* hnf  = Xn + 1049088;          // 32768
    float* adjw = hnf + 32768;           // 8192
    float* hout = adjw + 8192;           // 65536
    unsigned* wpk = (unsigned*)(hout + 65536);   // 32768 uints (bf16-packed GAT weights)

    k_detect<<<1, 256, 0, stream>>>((const unsigned*)d_in[0], flag);
    k_convert<<<(total + 255) / 256, 256, 0, stream>>>(P, O, total, flag, cvt);
    k_pack<<<128, 256, 0, stream>>>(qkvw, outw, f1w, f2w, wpk);
    k_cnn<<<512, 256, 0, stream>>>(x, c1w, c1b, bn1g, bn1b, bn1m, bn1v,
                                   c2w, c2b, bn2g, bn2b, bn2m, bn2v, hm);
    k_fft<<<512, 512, 0, stream>>>(x, Xn);
    k_havg<<<512, 64, 0, stream>>>(hm, hnf);
    k_adj<<<32, 256, 0, stream>>>(Xn, hnf, prior, logw, adjw, d_out, flag);
    k_gat<<<2048, 256, 0, stream>>>(hm, adjw, (const ushort_t*)wpk,
                                    qkvb, outb, f1b, f2b_, n1g, n1b, n2g, n2b, gng, gnb);
    k_gru<<<1024, 192, 0, stream>>>(hm, gwih, gwhh, gbih, gbhh, hout);
    k_readout<<<32, 128, 0, stream>>>(hout, gatew, gateb, d_out, flag);
}

// Round 5
// 845.932 us; speedup vs baseline: 5.0565x; 1.9110x over previous
//
#include <hip/hip_runtime.h>
#include <hip/hip_bf16.h>
#include <math.h>

typedef __hip_bfloat16 bf16;
typedef unsigned short ushort_t;
typedef __attribute__((ext_vector_type(8))) short short8;
typedef __attribute__((ext_vector_type(4))) float f32x4;

__device__ __forceinline__ float b2f(bf16 v) { return __bfloat162float(v); }
__device__ __forceinline__ bf16 f2b(float v) { return __float2bfloat16(v); }
__device__ __forceinline__ float bflo(unsigned u) { return __uint_as_float(u << 16); }
__device__ __forceinline__ float bfhi(unsigned u) { return __uint_as_float(u & 0xffff0000u); }
__device__ __forceinline__ float geluf(float x) { return 0.5f * x * (1.0f + erff(x * 0.70710678118654752f)); }
__device__ __forceinline__ float sigmoidf_(float x) { return 1.0f / (1.0f + __expf(-x)); }

// round-to-nearest-even fp32 -> bf16 bit pack
__device__ __forceinline__ unsigned pack2bf(float a, float b) {
    unsigned ua = __float_as_uint(a); ua = (ua + 0x7FFFu + ((ua >> 16) & 1u)) >> 16;
    unsigned ub = __float_as_uint(b); ub = (ub + 0x7FFFu + ((ub >> 16) & 1u)) >> 16;
    return ua | (ub << 16);
}
__device__ __forceinline__ ushort_t f2bu(float v) {
    unsigned u = __float_as_uint(v);
    u = (u + 0x7FFFu + ((u >> 16) & 1u)) >> 16;
    return (ushort_t)u;
}

// ========================== K0a: dtype detector ==============================
__global__ __launch_bounds__(256) void k_detect(const unsigned* __restrict__ x, int* __restrict__ flag)
{
    __shared__ int cnt;
    if (threadIdx.x == 0) cnt = 0;
    __syncthreads();
    unsigned u = x[threadIdx.x] & 0xFFFFu;
    float f = __uint_as_float(u << 16);
    float a = fabsf(f);
    int sane = (f == 0.0f) || (a > 1e-8f && a < 1e4f);
    atomicAdd(&cnt, sane);
    __syncthreads();
    if (threadIdx.x == 0) *flag = (cnt >= 160) ? 1 : 0;
}

// ========================== K0b: canonicalize to fp32 ========================
struct InPtrs { const void* p[35]; };
struct InOffs { int off[35]; int sz[35]; };

__global__ __launch_bounds__(256) void k_convert(InPtrs P, InOffs O, int total,
                                                 const int* __restrict__ flag,
                                                 float* __restrict__ cvt)
{
    int idx = blockIdx.x * 256 + threadIdx.x;
    if (idx >= total) return;
    int isb = *flag;
    float v = 0.f;
#pragma unroll 1
    for (int s = 0; s < 35; s++) {
        int rel = idx - O.off[s];
        if (rel >= 0 && rel < O.sz[s]) {
            v = isb ? b2f(((const bf16*)P.p[s])[rel]) : ((const float*)P.p[s])[rel];
            break;
        }
    }
    cvt[idx] = v;
}

// ========================== K0c: pack weights to bf16 ========================
// uint regions: qw 12288 | ow 4096 | f1w 8192 | f2w 8192 | gwih 12288 | gwhh 12288
__global__ __launch_bounds__(256) void k_pack(const float* __restrict__ qw, const float* __restrict__ ow,
                                              const float* __restrict__ f1w, const float* __restrict__ f2w,
                                              const float* __restrict__ gwih, const float* __restrict__ gwhh,
                                              unsigned* __restrict__ dst)
{
    int i = blockIdx.x * 256 + threadIdx.x;
    if (i >= 57344) return;
    const float* s; int rel;
    if (i < 12288)      { s = qw;   rel = i; }
    else if (i < 16384) { s = ow;   rel = i - 12288; }
    else if (i < 24576) { s = f1w;  rel = i - 16384; }
    else if (i < 32768) { s = f2w;  rel = i - 24576; }
    else if (i < 45056) { s = gwih; rel = i - 32768; }
    else                { s = gwhh; rel = i - 45056; }
    dst[i] = pack2bf(s[2 * rel], s[2 * rel + 1]);
}

// =============================== K1: fused CNN ===============================
__global__ __launch_bounds__(256) void k_cnn(
    const float* __restrict__ x, const float* __restrict__ c1w, const float* __restrict__ c1b,
    const float* __restrict__ bn1g, const float* __restrict__ bn1b, const float* __restrict__ bn1m, const float* __restrict__ bn1v,
    const float* __restrict__ c2w, const float* __restrict__ c2b,
    const float* __restrict__ bn2g, const float* __restrict__ bn2b, const float* __restrict__ bn2m, const float* __restrict__ bn2v,
    float* __restrict__ h_main)
{
    __shared__ float xs[1056];
    __shared__ float h1[32][261];
    __shared__ float w1[32 * 7];
    __shared__ float A1[32], B1[32];
    __shared__ float w2[64 * 160];
    __shared__ float A2[64], B2[64];
    int bc = blockIdx.x, t = threadIdx.x;
    for (int i = t; i < 224; i += 256) w1[i] = c1w[i];
    for (int i = t; i < 10240; i += 256) w2[i] = c2w[i];
    if (t < 32) {
        float s = bn1g[t] * rsqrtf(bn1v[t] + 1e-5f);
        A1[t] = s; B1[t] = (c1b[t] - bn1m[t]) * s + bn1b[t];
    } else if (t < 96) {
        int d = t - 32;
        float s = bn2g[d] * rsqrtf(bn2v[d] + 1e-5f);
        A2[d] = s; B2[d] = (c2b[d] - bn2m[d]) * s + bn2b[d];
    }
    __syncthreads();
    const float* xrow = x + (size_t)bc * 4096;
    for (int tile = 0; tile < 4; tile++) {
        int X0 = 1024 * tile - 11;
        for (int i = t; i < 1056; i += 256) {
            int g = X0 + i;
            xs[i] = (g >= 0 && g < 4096) ? xrow[g] : 0.0f;
        }
        __syncthreads();
        for (int o = t; o < 32 * 260; o += 256) {
            int ic = o / 260, j = o % 260;
            int t1p = 256 * tile - 2 + j;
            float res = 0.0f;
            if (t1p >= 0 && t1p < 1024) {
                const float* wr = &w1[ic * 7];
                float a = A1[ic], bb = B1[ic];
                float mx = -3.4e38f;
#pragma unroll
                for (int q = 0; q < 4; q++) {
                    float acc = 0.f;
#pragma unroll
                    for (int k = 0; k < 7; k++) acc += xs[4 * j + q + k] * wr[k];
                    mx = fmaxf(mx, geluf(acc * a + bb));
                }
                res = mx;
            }
            h1[ic][j] = res;
        }
        __syncthreads();
        int p = t & 63, dg = t >> 6;
        float acc[16][4];
#pragma unroll
        for (int dd = 0; dd < 16; dd++)
#pragma unroll
            for (int q = 0; q < 4; q++) acc[dd][q] = 0.f;
        for (int ic = 0; ic < 32; ic++) {
            float dreg[8];
#pragma unroll
            for (int m = 0; m < 8; m++) dreg[m] = h1[ic][4 * p + m];
#pragma unroll
            for (int dd = 0; dd < 16; dd++) {
                const float* wk = &w2[(dg * 16 + dd) * 160 + ic * 5];
#pragma unroll
                for (int k = 0; k < 5; k++) {
                    float w = wk[k];
                    acc[dd][0] += dreg[k] * w;
                    acc[dd][1] += dreg[k + 1] * w;
                    acc[dd][2] += dreg[k + 2] * w;
                    acc[dd][3] += dreg[k + 3] * w;
                }
            }
        }
        int tp = tile * 64 + p;
        float* dst = h_main + (size_t)bc * 16384 + (size_t)tp * 64 + dg * 16;
#pragma unroll
        for (int dd = 0; dd < 16; dd++) {
            int d = dg * 16 + dd;
            float a = A2[d], bb = B2[d];
            float v = fmaxf(fmaxf(geluf(acc[dd][0] * a + bb), geluf(acc[dd][1] * a + bb)),
                            fmaxf(geluf(acc[dd][2] * a + bb), geluf(acc[dd][3] * a + bb)));
            dst[dd] = v;
        }
        __syncthreads();
    }
}

// =============================== K2: FFT + spec norm =========================
__global__ __launch_bounds__(512) void k_fft(const float* __restrict__ x, float* __restrict__ Xn)
{
    __shared__ float re[4096];
    __shared__ float im[4096];
    __shared__ float red[8];
    int bc = blockIdx.x, t = threadIdx.x;
    const float* xr = x + (size_t)bc * 4096;
    for (int i = t; i < 4096; i += 512) {
        int r = __brev((unsigned)i) >> 20;
        re[r] = xr[i];
        im[r] = 0.f;
    }
    __syncthreads();
    for (int s = 1; s <= 12; s++) {
        int half = 1 << (s - 1);
        float ang = -6.283185307179586f / (float)(1 << s);
        for (int m = t; m < 2048; m += 512) {
            int j = m & (half - 1);
            int pos = ((m >> (s - 1)) << s) | j;
            float sn, cs;
            __sincosf(ang * (float)j, &sn, &cs);
            float ur = re[pos], ui = im[pos];
            float vr = re[pos + half], vi = im[pos + half];
            float tr = vr * cs - vi * sn;
            float ti = vr * sn + vi * cs;
            re[pos] = ur + tr; im[pos] = ui + ti;
            re[pos + half] = ur - tr; im[pos + half] = ui - ti;
        }
        __syncthreads();
    }
    float mag[5];
    float ss = 0.f;
    int cnt = 0;
    for (int f = t; f <= 2048; f += 512) {
        float m2 = re[f] * re[f] + im[f] * im[f];
        mag[cnt++] = sqrtf(m2);
        ss += m2;
    }
    for (int off = 32; off; off >>= 1) ss += __shfl_xor(ss, off, 64);
    if ((t & 63) == 0) red[t >> 6] = ss;
    __syncthreads();
    float tot = 0.f;
#pragma unroll
    for (int i = 0; i < 8; i++) tot += red[i];
    float inv = 1.0f / (sqrtf(tot) + 1e-8f);
    cnt = 0;
    for (int f = t; f <= 2048; f += 512) Xn[(size_t)bc * 2049 + f] = mag[cnt++] * inv;
}

// =============================== K3: h_avg -> hn =============================
__global__ __launch_bounds__(64) void k_havg(const float* __restrict__ hm, float* __restrict__ hnf)
{
    int bc = blockIdx.x, d = threadIdx.x;
    const float* base = hm + (size_t)bc * 16384;
    float s = 0.f;
    for (int tp = 0; tp < 256; tp++) s += base[tp * 64 + d];
    float avg = s * (1.0f / 256.0f);
    float tot = avg;
    for (int off = 32; off; off >>= 1) tot += __shfl_xor(tot, off, 64);
    float hc = avg - tot * (1.0f / 64.0f);
    float sq = hc * hc;
    for (int off = 32; off; off >>= 1) sq += __shfl_xor(sq, off, 64);
    hnf[bc * 64 + d] = hc / (sqrtf(sq) + 1e-8f);
}

// =============================== K4: adjacency ===============================
__global__ __launch_bounds__(256) void k_adj(
    const float* __restrict__ Xn, const float* __restrict__ hnf,
    const float* __restrict__ prior, const float* __restrict__ logw,
    float* __restrict__ adjw, void* __restrict__ out, const int* __restrict__ flag)
{
    __shared__ float xt[16][257];
    __shared__ float hh[16 * 64];
    int b = blockIdx.x, t = threadIdx.x;
    int c = t >> 4, e = t & 15;
    for (int i = t; i < 1024; i += 256) hh[i] = hnf[b * 1024 + i];
    __syncthreads();
    float fc = 0.f;
    for (int d = 0; d < 64; d++) fc += hh[c * 64 + d] * hh[e * 64 + d];
    float sc = 0.f;
    const float* Xb = Xn + (size_t)b * 16 * 2049;
    for (int f0 = 0; f0 < 2048; f0 += 256) {
        __syncthreads();
        for (int i = t; i < 16 * 256; i += 256) {
            int rr = i >> 8, ff = i & 255;
            xt[rr][ff] = Xb[rr * 2049 + f0 + ff];
        }
        __syncthreads();
        for (int ff = 0; ff < 256; ff++) sc += xt[c][ff] * xt[e][ff];
    }
    sc += Xb[c * 2049 + 2048] * Xb[e * 2049 + 2048];
    float l0 = logw[0], l1 = logw[1], l2 = logw[2];
    float mx = fmaxf(l0, fmaxf(l1, l2));
    float e0 = __expf(l0 - mx), e1 = __expf(l1 - mx), e2 = __expf(l2 - mx);
    float isum = 1.0f / (e0 + e1 + e2);
    float pr = prior[c * 16 + e] + prior[e * 16 + c];
    float v = (e0 * fc + e1 * sc + e2 * pr) * isum;
    adjw[b * 256 + t] = v;
    if (*flag) ((bf16*)out)[4096 + b * 256 + t] = f2b(v);
    else       ((float*)out)[4096 + b * 256 + t] = v;
}

// =============================== K5: GAT stack (MFMA) ========================
// One wave per (b,tp); 4 waves/block; no __syncthreads (all LDS is per-wave).
__device__ __forceinline__ void ln_wave(const float (*ht)[68], ushort_t (*out)[72],
                                        const float* __restrict__ g, const float* __restrict__ bp,
                                        int quad, int lo)
{
    float v[16];
    const float4* row = (const float4*)(&ht[lo][quad * 16]);
#pragma unroll
    for (int i = 0; i < 4; i++) {
        float4 a = row[i];
        v[4 * i] = a.x; v[4 * i + 1] = a.y; v[4 * i + 2] = a.z; v[4 * i + 3] = a.w;
    }
    float s = 0.f;
#pragma unroll
    for (int i = 0; i < 16; i++) s += v[i];
    s += __shfl_xor(s, 16); s += __shfl_xor(s, 32);
    float mean = s * (1.0f / 64.0f);
    float q = 0.f;
#pragma unroll
    for (int i = 0; i < 16; i++) { float d = v[i] - mean; q += d * d; }
    q += __shfl_xor(q, 16); q += __shfl_xor(q, 32);
    float rstd = rsqrtf(q * (1.0f / 64.0f) + 1e-5f);
    const float4* gp = (const float4*)(g + quad * 16);
    const float4* bb4 = (const float4*)(bp + quad * 16);
    unsigned* orow = (unsigned*)(&out[lo][quad * 16]);
#pragma unroll
    for (int i = 0; i < 4; i++) {
        float4 gg = gp[i], bb = bb4[i];
        float o0 = (v[4 * i] - mean) * rstd * gg.x + bb.x;
        float o1 = (v[4 * i + 1] - mean) * rstd * gg.y + bb.y;
        float o2 = (v[4 * i + 2] - mean) * rstd * gg.z + bb.z;
        float o3 = (v[4 * i + 3] - mean) * rstd * gg.w + bb.w;
        orow[2 * i] = pack2bf(o0, o1);
        orow[2 * i + 1] = pack2bf(o2, o3);
    }
}

__global__ __launch_bounds__(256) void k_gat(
    const float* __restrict__ hm, const float* __restrict__ adjw,
    const ushort_t* __restrict__ wpk,
    const float* __restrict__ qb_, const float* __restrict__ ob_,
    const float* __restrict__ f1b_, const float* __restrict__ f2b_,
    const float* __restrict__ n1g_, const float* __restrict__ n1b_,
    const float* __restrict__ n2g_, const float* __restrict__ n2b_,
    const float* __restrict__ gng, const float* __restrict__ gnb,
    ushort_t* __restrict__ hmb)
{
    __shared__ float htw_all[4][16][68];
    __shared__ ushort_t hnw_all[4][16][72];
    __shared__ ushort_t qkb_all[4][16][200];
    __shared__ ushort_t pb_all[4][16][72];
    __shared__ ushort_t vt_all[4][64][24];
    int t = threadIdx.x;
    int w = t >> 6, l = t & 63;
    int quad = l >> 4, lo = l & 15;
    int n = blockIdx.x * 4 + w;
    int b = n >> 8, tp = n & 255;
    float (*htw)[68] = htw_all[w];
    ushort_t (*hnw)[72] = hnw_all[w];
    ushort_t (*qkb)[200] = qkb_all[w];
    ushort_t (*pb)[72] = pb_all[w];
    ushort_t (*vt)[24] = vt_all[w];
    const float* src = hm + (size_t)b * 16 * 16384 + (size_t)tp * 64;
#pragma unroll
    for (int c = 0; c < 16; c++) htw[c][l] = src[(size_t)c * 16384 + l];
    float adjr[4];
#pragma unroll
    for (int r = 0; r < 4; r++) adjr[r] = adjw[b * 256 + (quad * 4 + r) * 16 + lo];

    for (int layer = 0; layer < 2; layer++) {
        const ushort_t* wq  = wpk + layer * 12288;
        const ushort_t* wo  = wpk + 24576 + layer * 4096;
        const ushort_t* wf1 = wpk + 32768 + layer * 8192;
        const ushort_t* wf2 = wpk + 49152 + layer * 8192;
        const float* qb = qb_ + layer * 192;
        const float* ob = ob_ + layer * 64;
        const float* f1b = f1b_ + layer * 128;
        const float* f2b = f2b_ + layer * 64;

        ln_wave(htw, hnw, n1g_ + layer * 64, n1b_ + layer * 64, quad, lo);

        short8 a0 = *(const short8*)&hnw[lo][quad * 8];
        short8 a1 = *(const short8*)&hnw[lo][32 + quad * 8];
#pragma unroll
        for (int nt = 0; nt < 12; nt++) {
            const ushort_t* wr = wq + (nt * 16 + lo) * 64 + quad * 8;
            short8 b0 = *(const short8*)wr;
            short8 b1 = *(const short8*)(wr + 32);
            f32x4 acc = {0.f, 0.f, 0.f, 0.f};
            acc = __builtin_amdgcn_mfma_f32_16x16x32_bf16(a0, b0, acc, 0, 0, 0);
            acc = __builtin_amdgcn_mfma_f32_16x16x32_bf16(a1, b1, acc, 0, 0, 0);
            float bias = qb[nt * 16 + lo];
            if (nt < 8) {
#pragma unroll
                for (int r = 0; r < 4; r++) qkb[quad * 4 + r][nt * 16 + lo] = f2bu(acc[r] + bias);
            } else {
#pragma unroll
                for (int r = 0; r < 4; r++) vt[(nt - 8) * 16 + lo][quad * 4 + r] = f2bu(acc[r] + bias);
            }
        }

        short8 zf = {0, 0, 0, 0, 0, 0, 0, 0};
#pragma unroll
        for (int h = 0; h < 4; h++) {
            short8 qf = zf, kf = zf;
            if (quad < 2) {
                qf = *(const short8*)&qkb[lo][h * 16 + quad * 8];
                kf = *(const short8*)&qkb[lo][64 + h * 16 + quad * 8];
            }
            f32x4 s4 = {0.f, 0.f, 0.f, 0.f};
            s4 = __builtin_amdgcn_mfma_f32_16x16x32_bf16(qf, kf, s4, 0, 0, 0);
#pragma unroll
            for (int r = 0; r < 4; r++) {
                float sv = s4[r] * 0.25f + adjr[r];
                float mx = sv;
                mx = fmaxf(mx, __shfl_xor(mx, 1));
                mx = fmaxf(mx, __shfl_xor(mx, 2));
                mx = fmaxf(mx, __shfl_xor(mx, 4));
                mx = fmaxf(mx, __shfl_xor(mx, 8));
                float e = __expf(sv - mx);
                float sm = e;
                sm += __shfl_xor(sm, 1);
                sm += __shfl_xor(sm, 2);
                sm += __shfl_xor(sm, 4);
                sm += __shfl_xor(sm, 8);
                pb[quad * 4 + r][h * 16 + lo] = f2bu(e / sm);
            }
        }
#pragma unroll
        for (int h = 0; h < 4; h++) {
            short8 pf = zf, vf = zf;
            if (quad < 2) {
                pf = *(const short8*)&pb[lo][h * 16 + quad * 8];
                vf = *(const short8*)&vt[h * 16 + lo][quad * 8];
            }
            f32x4 oc = {0.f, 0.f, 0.f, 0.f};
            oc = __builtin_amdgcn_mfma_f32_16x16x32_bf16(pf, vf, oc, 0, 0, 0);
#pragma unroll
            for (int r = 0; r < 4; r++) qkb[quad * 4 + r][h * 16 + lo] = f2bu(oc[r]);
        }
        short8 pa0 = *(const short8*)&qkb[lo][quad * 8];
        short8 pa1 = *(const short8*)&qkb[lo][32 + quad * 8];
#pragma unroll
        for (int nt = 0; nt < 4; nt++) {
            const ushort_t* wr = wo + (nt * 16 + lo) * 64 + quad * 8;
            short8 b0 = *(const short8*)wr;
            short8 b1 = *(const short8*)(wr + 32);
            f32x4 acc = {0.f, 0.f, 0.f, 0.f};
            acc = __builtin_amdgcn_mfma_f32_16x16x32_bf16(pa0, b0, acc, 0, 0, 0);
            acc = __builtin_amdgcn_mfma_f32_16x16x32_bf16(pa1, b1, acc, 0, 0, 0);
            float bias = ob[nt * 16 + lo];
#pragma unroll
            for (int r = 0; r < 4; r++) htw[quad * 4 + r][nt * 16 + lo] += acc[r] + bias;
        }
        ln_wave(htw, hnw, n2g_ + layer * 64, n2b_ + layer * 64, quad, lo);
        short8 fa0 = *(const short8*)&hnw[lo][quad * 8];
        short8 fa1 = *(const short8*)&hnw[lo][32 + quad * 8];
#pragma unroll
        for (int nt = 0; nt < 8; nt++) {
            const ushort_t* wr = wf1 + (nt * 16 + lo) * 64 + quad * 8;
            short8 b0 = *(const short8*)wr;
            short8 b1 = *(const short8*)(wr + 32);
            f32x4 acc = {0.f, 0.f, 0.f, 0.f};
            acc = __builtin_amdgcn_mfma_f32_16x16x32_bf16(fa0, b0, acc, 0, 0, 0);
            acc = __builtin_amdgcn_mfma_f32_16x16x32_bf16(fa1, b1, acc, 0, 0, 0);
            float bias = f1b[nt * 16 + lo];
#pragma unroll
            for (int r = 0; r < 4; r++) qkb[quad * 4 + r][nt * 16 + lo] = f2bu(geluf(acc[r] + bias));
        }
        short8 ga[4];
#pragma unroll
        for (int kb = 0; kb < 4; kb++) ga[kb] = *(const short8*)&qkb[lo][kb * 32 + quad * 8];
#pragma unroll
        for (int nt = 0; nt < 4; nt++) {
            const ushort_t* wr = wf2 + (nt * 16 + lo) * 128 + quad * 8;
            f32x4 acc = {0.f, 0.f, 0.f, 0.f};
#pragma unroll
            for (int kb = 0; kb < 4; kb++) {
                short8 bb = *(const short8*)(wr + kb * 32);
                acc = __builtin_amdgcn_mfma_f32_16x16x32_bf16(ga[kb], bb, acc, 0, 0, 0);
            }
            float bias = f2b[nt * 16 + lo];
#pragma unroll
            for (int r = 0; r < 4; r++) htw[quad * 4 + r][nt * 16 + lo] += acc[r] + bias;
        }
    }
    // ---- final LN -> bf16 hmb ----
    {
        float v[16];
        const float4* row = (const float4*)(&htw[lo][quad * 16]);
#pragma unroll
        for (int i = 0; i < 4; i++) {
            float4 a = row[i];
            v[4 * i] = a.x; v[4 * i + 1] = a.y; v[4 * i + 2] = a.z; v[4 * i + 3] = a.w;
        }
        float s = 0.f;
#pragma unroll
        for (int i = 0; i < 16; i++) s += v[i];
        s += __shfl_xor(s, 16); s += __shfl_xor(s, 32);
        float mean = s * (1.0f / 64.0f);
        float q = 0.f;
#pragma unroll
        for (int i = 0; i < 16; i++) { float d = v[i] - mean; q += d * d; }
        q += __shfl_xor(q, 16); q += __shfl_xor(q, 32);
        float rstd = rsqrtf(q * (1.0f / 64.0f) + 1e-5f);
        const float4* gp = (const float4*)(gng + quad * 16);
        const float4* bb4 = (const float4*)(gnb + quad * 16);
        unsigned u[8];
#pragma unroll
        for (int i = 0; i < 4; i++) {
            float4 gg = gp[i], bb = bb4[i];
            float o0 = (v[4 * i] - mean) * rstd * gg.x + bb.x;
            float o1 = (v[4 * i + 1] - mean) * rstd * gg.y + bb.y;
            float o2 = (v[4 * i + 2] - mean) * rstd * gg.z + bb.z;
            float o3 = (v[4 * i + 3] - mean) * rstd * gg.w + bb.w;
            u[2 * i] = pack2bf(o0, o1);
            u[2 * i + 1] = pack2bf(o2, o3);
        }
        ushort_t* dst = hmb + (size_t)(b * 16 + lo) * 16384 + (size_t)tp * 64 + quad * 16;
        ((uint4*)dst)[0] = make_uint4(u[0], u[1], u[2], u[3]);
        ((uint4*)dst)[1] = make_uint4(u[4], u[5], u[6], u[7]);
    }
}

// =============================== K6: GRU (MFMA) ==============================
// 64 blocks: block = (dir, 16-sequence group). 4 waves split d (16 each).
// Weight B-frags live in VGPRs for all 256 steps; h round-trips via a
// double-buffered LDS tile (1 barrier/step).
__global__ __launch_bounds__(256) void k_gru(
    const ushort_t* __restrict__ hmb, const ushort_t* __restrict__ wgru,
    const float* __restrict__ bih_, const float* __restrict__ bhh_,
    float* __restrict__ h_out)
{
    __shared__ ushort_t hbuf[2][16][72];
    int t = threadIdx.x;
    int w = t >> 6, l = t & 63;
    int ln = l & 15, qd = l >> 4;
    int dir = blockIdx.x >> 5;
    int cseq0 = (blockIdx.x & 31) * 16;
    const ushort_t* wih = wgru + dir * 12288;
    const ushort_t* whh = wgru + 24576 + dir * 12288;
    // B-frags: B[k=qd*8+j][n=ln] = W[tile*16+ln][half*32+qd*8+j]
    const ushort_t* pr0 = wih + ((w)*16 + ln) * 64 + qd * 8;
    const ushort_t* pz0 = wih + ((4 + w)*16 + ln) * 64 + qd * 8;
    const ushort_t* pn0 = wih + ((8 + w)*16 + ln) * 64 + qd * 8;
    const ushort_t* hr0 = whh + ((w)*16 + ln) * 64 + qd * 8;
    const ushort_t* hz0 = whh + ((4 + w)*16 + ln) * 64 + qd * 8;
    const ushort_t* hn0 = whh + ((8 + w)*16 + ln) * 64 + qd * 8;
    short8 wi_r0 = *(const short8*)pr0, wi_r1 = *(const short8*)(pr0 + 32);
    short8 wi_z0 = *(const short8*)pz0, wi_z1 = *(const short8*)(pz0 + 32);
    short8 wi_n0 = *(const short8*)pn0, wi_n1 = *(const short8*)(pn0 + 32);
    short8 wh_r0 = *(const short8*)hr0, wh_r1 = *(const short8*)(hr0 + 32);
    short8 wh_z0 = *(const short8*)hz0, wh_z1 = *(const short8*)(hz0 + 32);
    short8 wh_n0 = *(const short8*)hn0, wh_n1 = *(const short8*)(hn0 + 32);
    int d = w * 16 + ln;
    float bs_r = bih_[dir * 192 + d] + bhh_[dir * 192 + d];
    float bs_z = bih_[dir * 192 + 64 + d] + bhh_[dir * 192 + 64 + d];
    float bi_n = bih_[dir * 192 + 128 + d];
    float bh_n = bhh_[dir * 192 + 128 + d];
    const ushort_t* xrow = hmb + (size_t)(cseq0 + ln) * 16384 + qd * 8;
    for (int i = t; i < 2 * 16 * 72; i += 256) ((ushort_t*)hbuf)[i] = 0;
    float h_old[4] = {0.f, 0.f, 0.f, 0.f};
    int tt0 = dir ? 255 : 0;
    short8 xc0 = *(const short8*)(xrow + tt0 * 64);
    short8 xc1 = *(const short8*)(xrow + tt0 * 64 + 32);
    __syncthreads();
#pragma unroll 2
    for (int step = 0; step < 256; step++) {
        int cur = step & 1, nxt = cur ^ 1;
        short8 ah0 = *(const short8*)&hbuf[cur][ln][qd * 8];
        short8 ah1 = *(const short8*)&hbuf[cur][ln][32 + qd * 8];
        f32x4 ar = {0.f, 0.f, 0.f, 0.f}, az = {0.f, 0.f, 0.f, 0.f};
        f32x4 ani = {0.f, 0.f, 0.f, 0.f}, anh = {0.f, 0.f, 0.f, 0.f};
        ar = __builtin_amdgcn_mfma_f32_16x16x32_bf16(xc0, wi_r0, ar, 0, 0, 0);
        ar = __builtin_amdgcn_mfma_f32_16x16x32_bf16(xc1, wi_r1, ar, 0, 0, 0);
        ar = __builtin_amdgcn_mfma_f32_16x16x32_bf16(ah0, wh_r0, ar, 0, 0, 0);
        ar = __builtin_amdgcn_mfma_f32_16x16x32_bf16(ah1, wh_r1, ar, 0, 0, 0);
        az = __builtin_amdgcn_mfma_f32_16x16x32_bf16(xc0, wi_z0, az, 0, 0, 0);
        az = __builtin_amdgcn_mfma_f32_16x16x32_bf16(xc1, wi_z1, az, 0, 0, 0);
        az = __builtin_amdgcn_mfma_f32_16x16x32_bf16(ah0, wh_z0, az, 0, 0, 0);
        az = __builtin_amdgcn_mfma_f32_16x16x32_bf16(ah1, wh_z1, az, 0, 0, 0);
        ani = __builtin_amdgcn_mfma_f32_16x16x32_bf16(xc0, wi_n0, ani, 0, 0, 0);
        ani = __builtin_amdgcn_mfma_f32_16x16x32_bf16(xc1, wi_n1, ani, 0, 0, 0);
        anh = __builtin_amdgcn_mfma_f32_16x16x32_bf16(ah0, wh_n0, anh, 0, 0, 0);
        anh = __builtin_amdgcn_mfma_f32_16x16x32_bf16(ah1, wh_n1, anh, 0, 0, 0);
        if (step < 255) {
            int tn = dir ? (254 - step) : (step + 1);
            xc0 = *(const short8*)(xrow + tn * 64);
            xc1 = *(const short8*)(xrow + tn * 64 + 32);
        }
#pragma unroll
        for (int r = 0; r < 4; r++) {
            float gr = sigmoidf_(ar[r] + bs_r);
            float gz = sigmoidf_(az[r] + bs_z);
            float nin = (ani[r] + bi_n) + gr * (anh[r] + bh_n);
            nin = fminf(fmaxf(nin, -15.f), 15.f);
            float e = __expf(-2.f * nin);
            float gn = (1.f - e) / (1.f + e);
            float hn = gn + gz * (h_old[r] - gn);
            h_old[r] = hn;
            hbuf[nxt][qd * 4 + r][d] = f2bu(hn);
        }
        __syncthreads();
    }
#pragma unroll
    for (int r = 0; r < 4; r++)
        h_out[(size_t)(cseq0 + qd * 4 + r) * 128 + dir * 64 + d] = h_old[r];
}

// =============================== K7: readout =================================
__global__ __launch_bounds__(128) void k_readout(
    const float* __restrict__ h_out, const float* __restrict__ gw, const float* __restrict__ gb,
    void* __restrict__ out, const int* __restrict__ flag)
{
    __shared__ float gate_s[16];
    __shared__ float gws[128];
    int b = blockIdx.x, t = threadIdx.x;
    gws[t] = gw[t];
    __syncthreads();
    int isb = *flag;
    if (t < 16) {
        const float* hr = h_out + (size_t)(b * 16 + t) * 128;
        float acc = gb[0];
        for (int k = 0; k < 128; k++) acc += hr[k] * gws[k];
        float g = sigmoidf_(acc);
        gate_s[t] = g;
        if (isb) ((bf16*)out)[12288 + b * 16 + t] = f2b(g);
        else     ((float*)out)[12288 + b * 16 + t] = g;
    }
    __syncthreads();
    float den = 1e-8f;
#pragma unroll
    for (int c = 0; c < 16; c++) den += gate_s[c];
    float num = 0.f;
#pragma unroll
    for (int c = 0; c < 16; c++) num += h_out[(size_t)(b * 16 + c) * 128 + t] * gate_s[c];
    float v = num / den;
    if (isb) ((bf16*)out)[b * 128 + t] = f2b(v);
    else     ((float*)out)[b * 128 + t] = v;
}

// =============================== launch ======================================
extern "C" void kernel_launch(void* const* d_in, const int* in_sizes, int n_in,
                              void* d_out, int out_size, void* d_ws, size_t ws_size,
                              hipStream_t stream)
{
    int* flag = (int*)d_ws;
    float* cvt = (float*)((char*)d_ws + 256);

    InPtrs P;
    InOffs O;
    int cum = 0;
    for (int i = 0; i < 35; i++) {
        P.p[i] = d_in[i];
        O.off[i] = cum;
        O.sz[i] = in_sizes[i];
        cum += (in_sizes[i] + 7) & ~7;
    }
    int total = cum;

    const float* x     = cvt + O.off[0];
    const float* c1w   = cvt + O.off[1];
    const float* c1b   = cvt + O.off[2];
    const float* bn1g  = cvt + O.off[3];
    const float* bn1b  = cvt + O.off[4];
    const float* bn1m  = cvt + O.off[5];
    const float* bn1v  = cvt + O.off[6];
    const float* c2w   = cvt + O.off[7];
    const float* c2b   = cvt + O.off[8];
    const float* bn2g  = cvt + O.off[9];
    const float* bn2b  = cvt + O.off[10];
    const float* bn2m  = cvt + O.off[11];
    const float* bn2v  = cvt + O.off[12];
    const float* prior = cvt + O.off[13];
    const float* logw  = cvt + O.off[14];
    const float* n1g   = cvt + O.off[15];
    const float* n1b   = cvt + O.off[16];
    const float* qkvw  = cvt + O.off[17];
    const float* qkvb  = cvt + O.off[18];
    const float* outw  = cvt + O.off[19];
    const float* outb  = cvt + O.off[20];
    const float* n2g   = cvt + O.off[21];
    const float* n2b   = cvt + O.off[22];
    const float* f1w   = cvt + O.off[23];
    const float* f1b   = cvt + O.off[24];
    const float* f2w   = cvt + O.off[25];
    const float* f2b_  = cvt + O.off[26];
    const float* gng   = cvt + O.off[27];
    const float* gnb   = cvt + O.off[28];
    const float* gwih  = cvt + O.off[29];
    const float* gwhh  = cvt + O.off[30];
    const float* gbih  = cvt + O.off[31];
    const float* gbhh  = cvt + O.off[32];
    const float* gatew = cvt + O.off[33];
    const float* gateb = cvt + O.off[34];

    float* fbase = cvt + ((total + 63) & ~63);
    float* hm   = fbase;                 // 8388608 floats (CNN out)
    float* Xn   = hm + 8388608;          // 1049088
    float* hnf  = Xn + 1049088;          // 32768
    float* adjw = hnf + 32768;           // 8192
    float* hout = adjw + 8192;           // 65536
    unsigned* wpk = (unsigned*)(hout + 65536);     // 57344 uints (bf16 weights)
    ushort_t* hmb = (ushort_t*)(wpk + 57344);      // 8388608 bf16 (GAT out)

    k_detect<<<1, 256, 0, stream>>>((const unsigned*)d_in[0], flag);
    k_convert<<<(total + 255) / 256, 256, 0, stream>>>(P, O, total, flag, cvt);
    k_pack<<<224, 256, 0, stream>>>(qkvw, outw, f1w, f2w, gwih, gwhh, wpk);
    k_cnn<<<512, 256, 0, stream>>>(x, c1w, c1b, bn1g, bn1b, bn1m, bn1v,
                                   c2w, c2b, bn2g, bn2b, bn2m, bn2v, hm);
    k_fft<<<512, 512, 0, stream>>>(x, Xn);
    k_havg<<<512, 64, 0, stream>>>(hm, hnf);
    k_adj<<<32, 256, 0, stream>>>(Xn, hnf, prior, logw, adjw, d_out, flag);
    k_gat<<<2048, 256, 0, stream>>>(hm, adjw, (const ushort_t*)wpk,
                                    qkvb, outb, f1b, f2b_, n1g, n1b, n2g, n2b, gng, gnb, hmb);
    k_gru<<<64, 256, 0, stream>>>(hmb, (const ushort_t*)(wpk + 32768), gbih, gbhh, hout);
    k_readout<<<32, 128, 0, stream>>>(hout, gatew, gateb, d_out, flag);
}

// Round 6
// 678.769 us; speedup vs baseline: 6.3017x; 1.2463x over previous
//
#include <hip/hip_runtime.h>
#include <hip/hip_bf16.h>
#include <math.h>

typedef __hip_bfloat16 bf16;
typedef unsigned short ushort_t;
typedef __attribute__((ext_vector_type(8))) short short8;
typedef __attribute__((ext_vector_type(4))) float f32x4;

__device__ __forceinline__ float b2f(bf16 v) { return __bfloat162float(v); }
__device__ __forceinline__ bf16 f2b(float v) { return __float2bfloat16(v); }
__device__ __forceinline__ float bflo(unsigned u) { return __uint_as_float(u << 16); }
__device__ __forceinline__ float bfhi(unsigned u) { return __uint_as_float(u & 0xffff0000u); }
__device__ __forceinline__ float sigmoidf_(float x) { return 1.0f / (1.0f + __expf(-x)); }

// fast exact-gelu: erf via Abramowitz-Stegun 7.1.26 (|err| <= 1.5e-7)
__device__ __forceinline__ float geluf(float x) {
    float z = x * 0.70710678118654752f;
    float az = fabsf(z);
    float t = 1.0f / (1.0f + 0.3275911f * az);
    float poly = ((((1.061405429f * t - 1.453152027f) * t + 1.421413741f) * t
                   - 0.284496736f) * t + 0.254829592f) * t;
    float erfa = 1.0f - poly * __expf(-z * z);
    float er = (z < 0.f) ? -erfa : erfa;
    return 0.5f * x * (1.0f + er);
}

// round-to-nearest-even fp32 -> bf16 bit pack
__device__ __forceinline__ unsigned pack2bf(float a, float b) {
    unsigned ua = __float_as_uint(a); ua = (ua + 0x7FFFu + ((ua >> 16) & 1u)) >> 16;
    unsigned ub = __float_as_uint(b); ub = (ub + 0x7FFFu + ((ub >> 16) & 1u)) >> 16;
    return ua | (ub << 16);
}
__device__ __forceinline__ ushort_t f2bu(float v) {
    unsigned u = __float_as_uint(v);
    u = (u + 0x7FFFu + ((u >> 16) & 1u)) >> 16;
    return (ushort_t)u;
}

// ========================== K0a: dtype detector ==============================
__global__ __launch_bounds__(256) void k_detect(const unsigned* __restrict__ x, int* __restrict__ flag)
{
    __shared__ int cnt;
    if (threadIdx.x == 0) cnt = 0;
    __syncthreads();
    unsigned u = x[threadIdx.x] & 0xFFFFu;
    float f = __uint_as_float(u << 16);
    float a = fabsf(f);
    int sane = (f == 0.0f) || (a > 1e-8f && a < 1e4f);
    atomicAdd(&cnt, sane);
    __syncthreads();
    if (threadIdx.x == 0) *flag = (cnt >= 160) ? 1 : 0;
}

// ========================== K0b: canonicalize to fp32 ========================
struct InPtrs { const void* p[35]; };
struct InOffs { int off[35]; int sz[35]; };

__global__ __launch_bounds__(256) void k_convert(InPtrs P, InOffs O, int total,
                                                 const int* __restrict__ flag,
                                                 float* __restrict__ cvt)
{
    int idx = blockIdx.x * 256 + threadIdx.x;
    if (idx >= total) return;
    int isb = *flag;
    float v = 0.f;
#pragma unroll 1
    for (int s = 0; s < 35; s++) {
        int rel = idx - O.off[s];
        if (rel >= 0 && rel < O.sz[s]) {
            v = isb ? b2f(((const bf16*)P.p[s])[rel]) : ((const float*)P.p[s])[rel];
            break;
        }
    }
    cvt[idx] = v;
}

// ========================== K0c: pack weights to bf16 ========================
// uint regions: qw 12288 | ow 4096 | f1w 8192 | f2w 8192 | gwih 12288 | gwhh 12288
//             | conv2 wt [tap][d][ic] 5120
__global__ __launch_bounds__(256) void k_pack(const float* __restrict__ qw, const float* __restrict__ ow,
                                              const float* __restrict__ f1w, const float* __restrict__ f2w,
                                              const float* __restrict__ gwih, const float* __restrict__ gwhh,
                                              const float* __restrict__ c2w,
                                              unsigned* __restrict__ dst)
{
    int i = blockIdx.x * 256 + threadIdx.x;
    if (i >= 62464) return;
    if (i >= 57344) {
        int j0 = (i - 57344) * 2;
        int tap = j0 >> 11, rem = j0 & 2047;
        int d = rem >> 5, ic = rem & 31;
        dst[i] = pack2bf(c2w[d * 160 + ic * 5 + tap], c2w[d * 160 + (ic + 1) * 5 + tap]);
        return;
    }
    const float* s; int rel;
    if (i < 12288)      { s = qw;   rel = i; }
    else if (i < 16384) { s = ow;   rel = i - 12288; }
    else if (i < 24576) { s = f1w;  rel = i - 16384; }
    else if (i < 32768) { s = f2w;  rel = i - 24576; }
    else if (i < 45056) { s = gwih; rel = i - 32768; }
    else                { s = gwhh; rel = i - 45056; }
    dst[i] = pack2bf(s[2 * rel], s[2 * rel + 1]);
}

// =============================== K1: fused CNN (MFMA conv2) ==================
// conv1+bn+gelu+pool4 (VALU, bf16 out to LDS) -> conv2 as 5 tap-GEMMs
// (mfma 16x16x32 bf16, K=32=ic) + bn + gelu + pool4 -> h_main fp32.
// maxpool(gelu(v)) = max(gelu(min v), gelu(max v))  [gelu unimodal].
__global__ __launch_bounds__(256) void k_cnn(
    const float* __restrict__ x, const float* __restrict__ c1w, const float* __restrict__ c1b,
    const float* __restrict__ bn1g, const float* __restrict__ bn1b, const float* __restrict__ bn1m, const float* __restrict__ bn1v,
    const float* __restrict__ c2b,
    const float* __restrict__ bn2g, const float* __restrict__ bn2b, const float* __restrict__ bn2m, const float* __restrict__ bn2v,
    const ushort_t* __restrict__ w2pk,
    float* __restrict__ h_main)
{
    __shared__ float ubuf[4352];          // union: xs[1056] | houtile[64][68]
    __shared__ ushort_t h1t[260 * 40];    // conv1 out bf16: row=pos (stride 40), col=ic
    __shared__ float A2s[64], B2s[64];
    int bc = blockIdx.x, t = threadIdx.x;
    int l = t & 63, w = t >> 6;
    int lo = l & 15, quad = l >> 4;

    if (t < 64) {
        float s = bn2g[t] * rsqrtf(bn2v[t] + 1e-5f);
        A2s[t] = s; B2s[t] = (c2b[t] - bn2m[t]) * s + bn2b[t];
    }
    // conv1 weights: per-thread registers (thread owns ic pair = 2*(t&15)+{0,1})
    int icp = t & 15;
    float w1r[2][7], A1r[2], B1r[2];
#pragma unroll
    for (int s = 0; s < 2; s++) {
        int ic = icp * 2 + s;
#pragma unroll
        for (int k = 0; k < 7; k++) w1r[s][k] = c1w[ic * 7 + k];
        float sc = bn1g[ic] * rsqrtf(bn1v[ic] + 1e-5f);
        A1r[s] = sc; B1r[s] = (c1b[ic] - bn1m[ic]) * sc + bn1b[ic];
    }
    // conv2 A-frags (weights [tap][d][ic] bf16), resident in VGPRs all kernel
    short8 Afr[4][5];
#pragma unroll
    for (int dt = 0; dt < 4; dt++)
#pragma unroll
        for (int tap = 0; tap < 5; tap++)
            Afr[dt][tap] = *(const short8*)(w2pk + ((tap * 64 + dt * 16 + lo) * 32 + quad * 8));

    const float* xrow = x + (size_t)bc * 4096;
    for (int tile = 0; tile < 4; tile++) {
        int X0 = 1024 * tile - 11;
        for (int i = t; i < 1056; i += 256) {
            int g = X0 + i;
            ubuf[i] = (g >= 0 && g < 4096) ? xrow[g] : 0.0f;
        }
        __syncthreads();
        // ---- stage A: conv1 ----
        for (int pos = (t >> 4); pos < 260; pos += 16) {
            const float4* xw = (const float4*)&ubuf[4 * pos];
            float4 fa = xw[0], fb = xw[1], fc = xw[2];
            float xv[12] = {fa.x, fa.y, fa.z, fa.w, fb.x, fb.y, fb.z, fb.w,
                            fc.x, fc.y, fc.z, fc.w};
            int t1pg = tile * 256 + pos - 2;
            bool ok = (t1pg >= 0 && t1pg < 1024);
            float res[2];
#pragma unroll
            for (int s = 0; s < 2; s++) {
                float a0 = 0.f, a1 = 0.f, a2 = 0.f, a3 = 0.f;
#pragma unroll
                for (int k = 0; k < 7; k++) {
                    float wv = w1r[s][k];
                    a0 += xv[k] * wv;     a1 += xv[k + 1] * wv;
                    a2 += xv[k + 2] * wv; a3 += xv[k + 3] * wv;
                }
                float A = A1r[s], B = B1r[s];
                a0 = a0 * A + B; a1 = a1 * A + B; a2 = a2 * A + B; a3 = a3 * A + B;
                float mx = fmaxf(fmaxf(a0, a1), fmaxf(a2, a3));
                float mn = fminf(fminf(a0, a1), fminf(a2, a3));
                res[s] = ok ? fmaxf(geluf(mx), geluf(mn)) : 0.0f;
            }
            ((unsigned*)h1t)[pos * 20 + icp] = pack2bf(res[0], res[1]);
        }
        __syncthreads();
        // ---- stage B: conv2 via MFMA; wave w owns nt = w*4..w*4+3 ----
        float* houtile = ubuf;
#pragma unroll
        for (int ni = 0; ni < 4; ni++) {
            int nt = w * 4 + ni;
            short8 bf[5];
#pragma unroll
            for (int tap = 0; tap < 5; tap++)
                bf[tap] = *(const short8*)&h1t[(nt * 16 + lo + tap) * 40 + quad * 8];
#pragma unroll
            for (int dt = 0; dt < 4; dt++) {
                f32x4 acc = {0.f, 0.f, 0.f, 0.f};
#pragma unroll
                for (int tap = 0; tap < 5; tap++)
                    acc = __builtin_amdgcn_mfma_f32_16x16x32_bf16(Afr[dt][tap], bf[tap], acc, 0, 0, 0);
                const float4 a2 = *(const float4*)&A2s[dt * 16 + quad * 4];
                const float4 b2 = *(const float4*)&B2s[dt * 16 + quad * 4];
                float a2a[4] = {a2.x, a2.y, a2.z, a2.w};
                float b2a[4] = {b2.x, b2.y, b2.z, b2.w};
#pragma unroll
                for (int r = 0; r < 4; r++) {
                    float v = acc[r] * a2a[r] + b2a[r];
                    float o1 = __shfl_xor(v, 1);
                    float mx = fmaxf(v, o1), mn = fminf(v, o1);
                    float mx2 = __shfl_xor(mx, 2), mn2 = __shfl_xor(mn, 2);
                    mx = fmaxf(mx, mx2); mn = fminf(mn, mn2);
                    float res = fmaxf(geluf(mx), geluf(mn));
                    if ((lo & 3) == 0)
                        houtile[(nt * 4 + (lo >> 2)) * 68 + dt * 16 + quad * 4 + r] = res;
                }
            }
        }
        __syncthreads();
        // ---- flush pooled tile (coalesced float4) ----
        float* dst = h_main + (size_t)bc * 16384 + tile * 4096;
        for (int i = t * 4; i < 4096; i += 1024) {
            float4 v = *(const float4*)&ubuf[(i >> 6) * 68 + (i & 63)];
            *(float4*)&dst[i] = v;
        }
        __syncthreads();
    }
}

// =============================== K2: FFT + spec norm =========================
__global__ __launch_bounds__(512) void k_fft(const float* __restrict__ x, float* __restrict__ Xn)
{
    __shared__ float re[4096];
    __shared__ float im[4096];
    __shared__ float red[8];
    int bc = blockIdx.x, t = threadIdx.x;
    const float* xr = x + (size_t)bc * 4096;
    for (int i = t; i < 4096; i += 512) {
        int r = __brev((unsigned)i) >> 20;
        re[r] = xr[i];
        im[r] = 0.f;
    }
    __syncthreads();
    for (int s = 1; s <= 12; s++) {
        int half = 1 << (s - 1);
        float ang = -6.283185307179586f / (float)(1 << s);
        for (int m = t; m < 2048; m += 512) {
            int j = m & (half - 1);
            int pos = ((m >> (s - 1)) << s) | j;
            float sn, cs;
            __sincosf(ang * (float)j, &sn, &cs);
            float ur = re[pos], ui = im[pos];
            float vr = re[pos + half], vi = im[pos + half];
            float tr = vr * cs - vi * sn;
            float ti = vr * sn + vi * cs;
            re[pos] = ur + tr; im[pos] = ui + ti;
            re[pos + half] = ur - tr; im[pos + half] = ui - ti;
        }
        __syncthreads();
    }
    float mag[5];
    float ss = 0.f;
    int cnt = 0;
    for (int f = t; f <= 2048; f += 512) {
        float m2 = re[f] * re[f] + im[f] * im[f];
        mag[cnt++] = sqrtf(m2);
        ss += m2;
    }
    for (int off = 32; off; off >>= 1) ss += __shfl_xor(ss, off, 64);
    if ((t & 63) == 0) red[t >> 6] = ss;
    __syncthreads();
    float tot = 0.f;
#pragma unroll
    for (int i = 0; i < 8; i++) tot += red[i];
    float inv = 1.0f / (sqrtf(tot) + 1e-8f);
    cnt = 0;
    for (int f = t; f <= 2048; f += 512) Xn[(size_t)bc * 2049 + f] = mag[cnt++] * inv;
}

// =============================== K3: h_avg -> hn =============================
__global__ __launch_bounds__(64) void k_havg(const float* __restrict__ hm, float* __restrict__ hnf)
{
    int bc = blockIdx.x, d = threadIdx.x;
    const float* base = hm + (size_t)bc * 16384;
    float s = 0.f;
    for (int tp = 0; tp < 256; tp++) s += base[tp * 64 + d];
    float avg = s * (1.0f / 256.0f);
    float tot = avg;
    for (int off = 32; off; off >>= 1) tot += __shfl_xor(tot, off, 64);
    float hc = avg - tot * (1.0f / 64.0f);
    float sq = hc * hc;
    for (int off = 32; off; off >>= 1) sq += __shfl_xor(sq, off, 64);
    hnf[bc * 64 + d] = hc / (sqrtf(sq) + 1e-8f);
}

// =============================== K4: adjacency ===============================
__global__ __launch_bounds__(256) void k_adj(
    const float* __restrict__ Xn, const float* __restrict__ hnf,
    const float* __restrict__ prior, const float* __restrict__ logw,
    float* __restrict__ adjw, void* __restrict__ out, const int* __restrict__ flag)
{
    __shared__ float xt[16][257];
    __shared__ float hh[16 * 64];
    int b = blockIdx.x, t = threadIdx.x;
    int c = t >> 4, e = t & 15;
    for (int i = t; i < 1024; i += 256) hh[i] = hnf[b * 1024 + i];
    __syncthreads();
    float fc = 0.f;
    for (int d = 0; d < 64; d++) fc += hh[c * 64 + d] * hh[e * 64 + d];
    float sc = 0.f;
    const float* Xb = Xn + (size_t)b * 16 * 2049;
    for (int f0 = 0; f0 < 2048; f0 += 256) {
        __syncthreads();
        for (int i = t; i < 16 * 256; i += 256) {
            int rr = i >> 8, ff = i & 255;
            xt[rr][ff] = Xb[rr * 2049 + f0 + ff];
        }
        __syncthreads();
        for (int ff = 0; ff < 256; ff++) sc += xt[c][ff] * xt[e][ff];
    }
    sc += Xb[c * 2049 + 2048] * Xb[e * 2049 + 2048];
    float l0 = logw[0], l1 = logw[1], l2 = logw[2];
    float mx = fmaxf(l0, fmaxf(l1, l2));
    float e0 = __expf(l0 - mx), e1 = __expf(l1 - mx), e2 = __expf(l2 - mx);
    float isum = 1.0f / (e0 + e1 + e2);
    float pr = prior[c * 16 + e] + prior[e * 16 + c];
    float v = (e0 * fc + e1 * sc + e2 * pr) * isum;
    adjw[b * 256 + t] = v;
    if (*flag) ((bf16*)out)[4096 + b * 256 + t] = f2b(v);
    else       ((float*)out)[4096 + b * 256 + t] = v;
}

// =============================== K5: GAT stack (MFMA) ========================
__device__ __forceinline__ void ln_wave(const float (*ht)[68], ushort_t (*out)[72],
                                        const float* __restrict__ g, const float* __restrict__ bp,
                                        int quad, int lo)
{
    float v[16];
    const float4* row = (const float4*)(&ht[lo][quad * 16]);
#pragma unroll
    for (int i = 0; i < 4; i++) {
        float4 a = row[i];
        v[4 * i] = a.x; v[4 * i + 1] = a.y; v[4 * i + 2] = a.z; v[4 * i + 3] = a.w;
    }
    float s = 0.f;
#pragma unroll
    for (int i = 0; i < 16; i++) s += v[i];
    s += __shfl_xor(s, 16); s += __shfl_xor(s, 32);
    float mean = s * (1.0f / 64.0f);
    float q = 0.f;
#pragma unroll
    for (int i = 0; i < 16; i++) { float d = v[i] - mean; q += d * d; }
    q += __shfl_xor(q, 16); q += __shfl_xor(q, 32);
    float rstd = rsqrtf(q * (1.0f / 64.0f) + 1e-5f);
    const float4* gp = (const float4*)(g + quad * 16);
    const float4* bb4 = (const float4*)(bp + quad * 16);
    unsigned* orow = (unsigned*)(&out[lo][quad * 16]);
#pragma unroll
    for (int i = 0; i < 4; i++) {
        float4 gg = gp[i], bb = bb4[i];
        float o0 = (v[4 * i] - mean) * rstd * gg.x + bb.x;
        float o1 = (v[4 * i + 1] - mean) * rstd * gg.y + bb.y;
        float o2 = (v[4 * i + 2] - mean) * rstd * gg.z + bb.z;
        float o3 = (v[4 * i + 3] - mean) * rstd * gg.w + bb.w;
        orow[2 * i] = pack2bf(o0, o1);
        orow[2 * i + 1] = pack2bf(o2, o3);
    }
}

__global__ __launch_bounds__(256) void k_gat(
    const float* __restrict__ hm, const float* __restrict__ adjw,
    const ushort_t* __restrict__ wpk,
    const float* __restrict__ qb_, const float* __restrict__ ob_,
    const float* __restrict__ f1b_, const float* __restrict__ f2b_,
    const float* __restrict__ n1g_, const float* __restrict__ n1b_,
    const float* __restrict__ n2g_, const float* __restrict__ n2b_,
    const float* __restrict__ gng, const float* __restrict__ gnb,
    ushort_t* __restrict__ hmb)
{
    __shared__ float htw_all[4][16][68];
    __shared__ ushort_t hnw_all[4][16][72];
    __shared__ ushort_t qkb_all[4][16][200];
    __shared__ ushort_t pb_all[4][16][72];
    __shared__ ushort_t vt_all[4][64][24];
    int t = threadIdx.x;
    int w = t >> 6, l = t & 63;
    int quad = l >> 4, lo = l & 15;
    int n = blockIdx.x * 4 + w;
    int b = n >> 8, tp = n & 255;
    float (*htw)[68] = htw_all[w];
    ushort_t (*hnw)[72] = hnw_all[w];
    ushort_t (*qkb)[200] = qkb_all[w];
    ushort_t (*pb)[72] = pb_all[w];
    ushort_t (*vt)[24] = vt_all[w];
    const float* src = hm + (size_t)b * 16 * 16384 + (size_t)tp * 64;
#pragma unroll
    for (int c = 0; c < 16; c++) htw[c][l] = src[(size_t)c * 16384 + l];
    float adjr[4];
#pragma unroll
    for (int r = 0; r < 4; r++) adjr[r] = adjw[b * 256 + (quad * 4 + r) * 16 + lo];

    for (int layer = 0; layer < 2; layer++) {
        const ushort_t* wq  = wpk + layer * 12288;
        const ushort_t* wo  = wpk + 24576 + layer * 4096;
        const ushort_t* wf1 = wpk + 32768 + layer * 8192;
        const ushort_t* wf2 = wpk + 49152 + layer * 8192;
        const float* qb = qb_ + layer * 192;
        const float* ob = ob_ + layer * 64;
        const float* f1b = f1b_ + layer * 128;
        const float* f2b = f2b_ + layer * 64;

        ln_wave(htw, hnw, n1g_ + layer * 64, n1b_ + layer * 64, quad, lo);

        short8 a0 = *(const short8*)&hnw[lo][quad * 8];
        short8 a1 = *(const short8*)&hnw[lo][32 + quad * 8];
#pragma unroll
        for (int nt = 0; nt < 12; nt++) {
            const ushort_t* wr = wq + (nt * 16 + lo) * 64 + quad * 8;
            short8 b0 = *(const short8*)wr;
            short8 b1 = *(const short8*)(wr + 32);
            f32x4 acc = {0.f, 0.f, 0.f, 0.f};
            acc = __builtin_amdgcn_mfma_f32_16x16x32_bf16(a0, b0, acc, 0, 0, 0);
            acc = __builtin_amdgcn_mfma_f32_16x16x32_bf16(a1, b1, acc, 0, 0, 0);
            float bias = qb[nt * 16 + lo];
            if (nt < 8) {
#pragma unroll
                for (int r = 0; r < 4; r++) qkb[quad * 4 + r][nt * 16 + lo] = f2bu(acc[r] + bias);
            } else {
#pragma unroll
                for (int r = 0; r < 4; r++) vt[(nt - 8) * 16 + lo][quad * 4 + r] = f2bu(acc[r] + bias);
            }
        }

        short8 zf = {0, 0, 0, 0, 0, 0, 0, 0};
#pragma unroll
        for (int h = 0; h < 4; h++) {
            short8 qf = zf, kf = zf;
            if (quad < 2) {
                qf = *(const short8*)&qkb[lo][h * 16 + quad * 8];
                kf = *(const short8*)&qkb[lo][64 + h * 16 + quad * 8];
            }
            f32x4 s4 = {0.f, 0.f, 0.f, 0.f};
            s4 = __builtin_amdgcn_mfma_f32_16x16x32_bf16(qf, kf, s4, 0, 0, 0);
#pragma unroll
            for (int r = 0; r < 4; r++) {
                float sv = s4[r] * 0.25f + adjr[r];
                float mx = sv;
                mx = fmaxf(mx, __shfl_xor(mx, 1));
                mx = fmaxf(mx, __shfl_xor(mx, 2));
                mx = fmaxf(mx, __shfl_xor(mx, 4));
                mx = fmaxf(mx, __shfl_xor(mx, 8));
                float e = __expf(sv - mx);
                float sm = e;
                sm += __shfl_xor(sm, 1);
                sm += __shfl_xor(sm, 2);
                sm += __shfl_xor(sm, 4);
                sm += __shfl_xor(sm, 8);
                pb[quad * 4 + r][h * 16 + lo] = f2bu(e / sm);
            }
        }
#pragma unroll
        for (int h = 0; h < 4; h++) {
            short8 pf = zf, vf = zf;
            if (quad < 2) {
                pf = *(const short8*)&pb[lo][h * 16 + quad * 8];
                vf = *(const short8*)&vt[h * 16 + lo][quad * 8];
            }
            f32x4 oc = {0.f, 0.f, 0.f, 0.f};
            oc = __builtin_amdgcn_mfma_f32_16x16x32_bf16(pf, vf, oc, 0, 0, 0);
#pragma unroll
            for (int r = 0; r < 4; r++) qkb[quad * 4 + r][h * 16 + lo] = f2bu(oc[r]);
        }
        short8 pa0 = *(const short8*)&qkb[lo][quad * 8];
        short8 pa1 = *(const short8*)&qkb[lo][32 + quad * 8];
#pragma unroll
        for (int nt = 0; nt < 4; nt++) {
            const ushort_t* wr = wo + (nt * 16 + lo) * 64 + quad * 8;
            short8 b0 = *(const short8*)wr;
            short8 b1 = *(const short8*)(wr + 32);
            f32x4 acc = {0.f, 0.f, 0.f, 0.f};
            acc = __builtin_amdgcn_mfma_f32_16x16x32_bf16(pa0, b0, acc, 0, 0, 0);
            acc = __builtin_amdgcn_mfma_f32_16x16x32_bf16(pa1, b1, acc, 0, 0, 0);
            float bias = ob[nt * 16 + lo];
#pragma unroll
            for (int r = 0; r < 4; r++) htw[quad * 4 + r][nt * 16 + lo] += acc[r] + bias;
        }
        ln_wave(htw, hnw, n2g_ + layer * 64, n2b_ + layer * 64, quad, lo);
        short8 fa0 = *(const short8*)&hnw[lo][quad * 8];
        short8 fa1 = *(const short8*)&hnw[lo][32 + quad * 8];
#pragma unroll
        for (int nt = 0; nt < 8; nt++) {
            const ushort_t* wr = wf1 + (nt * 16 + lo) * 64 + quad * 8;
            short8 b0 = *(const short8*)wr;
            short8 b1 = *(const short8*)(wr + 32);
            f32x4 acc = {0.f, 0.f, 0.f, 0.f};
            acc = __builtin_amdgcn_mfma_f32_16x16x32_bf16(fa0, b0, acc, 0, 0, 0);
            acc = __builtin_amdgcn_mfma_f32_16x16x32_bf16(fa1, b1, acc, 0, 0, 0);
            float bias = f1b[nt * 16 + lo];
#pragma unroll
            for (int r = 0; r < 4; r++) qkb[quad * 4 + r][nt * 16 + lo] = f2bu(geluf(acc[r] + bias));
        }
        short8 ga[4];
#pragma unroll
        for (int kb = 0; kb < 4; kb++) ga[kb] = *(const short8*)&qkb[lo][kb * 32 + quad * 8];
#pragma unroll
        for (int nt = 0; nt < 4; nt++) {
            const ushort_t* wr = wf2 + (nt * 16 + lo) * 128 + quad * 8;
            f32x4 acc = {0.f, 0.f, 0.f, 0.f};
#pragma unroll
            for (int kb = 0; kb < 4; kb++) {
                short8 bb = *(const short8*)(wr + kb * 32);
                acc = __builtin_amdgcn_mfma_f32_16x16x32_bf16(ga[kb], bb, acc, 0, 0, 0);
            }
            float bias = f2b[nt * 16 + lo];
#pragma unroll
            for (int r = 0; r < 4; r++) htw[quad * 4 + r][nt * 16 + lo] += acc[r] + bias;
        }
    }
    // ---- final LN -> bf16 hmb ----
    {
        float v[16];
        const float4* row = (const float4*)(&htw[lo][quad * 16]);
#pragma unroll
        for (int i = 0; i < 4; i++) {
            float4 a = row[i];
            v[4 * i] = a.x; v[4 * i + 1] = a.y; v[4 * i + 2] = a.z; v[4 * i + 3] = a.w;
        }
        float s = 0.f;
#pragma unroll
        for (int i = 0; i < 16; i++) s += v[i];
        s += __shfl_xor(s, 16); s += __shfl_xor(s, 32);
        float mean = s * (1.0f / 64.0f);
        float q = 0.f;
#pragma unroll
        for (int i = 0; i < 16; i++) { float d = v[i] - mean; q += d * d; }
        q += __shfl_xor(q, 16); q += __shfl_xor(q, 32);
        float rstd = rsqrtf(q * (1.0f / 64.0f) + 1e-5f);
        const float4* gp = (const float4*)(gng + quad * 16);
        const float4* bb4 = (const float4*)(gnb + quad * 16);
        unsigned u[8];
#pragma unroll
        for (int i = 0; i < 4; i++) {
            float4 gg = gp[i], bb = bb4[i];
            float o0 = (v[4 * i] - mean) * rstd * gg.x + bb.x;
            float o1 = (v[4 * i + 1] - mean) * rstd * gg.y + bb.y;
            float o2 = (v[4 * i + 2] - mean) * rstd * gg.z + bb.z;
            float o3 = (v[4 * i + 3] - mean) * rstd * gg.w + bb.w;
            u[2 * i] = pack2bf(o0, o1);
            u[2 * i + 1] = pack2bf(o2, o3);
        }
        ushort_t* dst = hmb + (size_t)(b * 16 + lo) * 16384 + (size_t)tp * 64 + quad * 16;
        ((uint4*)dst)[0] = make_uint4(u[0], u[1], u[2], u[3]);
        ((uint4*)dst)[1] = make_uint4(u[4], u[5], u[6], u[7]);
    }
}

// =============================== K6: GRU (MFMA) ==============================
__global__ __launch_bounds__(256) void k_gru(
    const ushort_t* __restrict__ hmb, const ushort_t* __restrict__ wgru,
    const float* __restrict__ bih_, const float* __restrict__ bhh_,
    float* __restrict__ h_out)
{
    __shared__ ushort_t hbuf[2][16][72];
    int t = threadIdx.x;
    int w = t >> 6, l = t & 63;
    int ln = l & 15, qd = l >> 4;
    int dir = blockIdx.x >> 5;
    int cseq0 = (blockIdx.x & 31) * 16;
    const ushort_t* wih = wgru + dir * 12288;
    const ushort_t* whh = wgru + 24576 + dir * 12288;
    const ushort_t* pr0 = wih + ((w)*16 + ln) * 64 + qd * 8;
    const ushort_t* pz0 = wih + ((4 + w)*16 + ln) * 64 + qd * 8;
    const ushort_t* pn0 = wih + ((8 + w)*16 + ln) * 64 + qd * 8;
    const ushort_t* hr0 = whh + ((w)*16 + ln) * 64 + qd * 8;
    const ushort_t* hz0 = whh + ((4 + w)*16 + ln) * 64 + qd * 8;
    const ushort_t* hn0 = whh + ((8 + w)*16 + ln) * 64 + qd * 8;
    short8 wi_r0 = *(const short8*)pr0, wi_r1 = *(const short8*)(pr0 + 32);
    short8 wi_z0 = *(const short8*)pz0, wi_z1 = *(const short8*)(pz0 + 32);
    short8 wi_n0 = *(const short8*)pn0, wi_n1 = *(const short8*)(pn0 + 32);
    short8 wh_r0 = *(const short8*)hr0, wh_r1 = *(const short8*)(hr0 + 32);
    short8 wh_z0 = *(const short8*)hz0, wh_z1 = *(const short8*)(hz0 + 32);
    short8 wh_n0 = *(const short8*)hn0, wh_n1 = *(const short8*)(hn0 + 32);
    int d = w * 16 + ln;
    float bs_r = bih_[dir * 192 + d] + bhh_[dir * 192 + d];
    float bs_z = bih_[dir * 192 + 64 + d] + bhh_[dir * 192 + 64 + d];
    float bi_n = bih_[dir * 192 + 128 + d];
    float bh_n = bhh_[dir * 192 + 128 + d];
    const ushort_t* xrow = hmb + (size_t)(cseq0 + ln) * 16384 + qd * 8;
    for (int i = t; i < 2 * 16 * 72; i += 256) ((ushort_t*)hbuf)[i] = 0;
    float h_old[4] = {0.f, 0.f, 0.f, 0.f};
    int tt0 = dir ? 255 : 0;
    short8 xc0 = *(const short8*)(xrow + tt0 * 64);
    short8 xc1 = *(const short8*)(xrow + tt0 * 64 + 32);
    __syncthreads();
#pragma unroll 2
    for (int step = 0; step < 256; step++) {
        int cur = step & 1, nxt = cur ^ 1;
        short8 ah0 = *(const short8*)&hbuf[cur][ln][qd * 8];
        short8 ah1 = *(const short8*)&hbuf[cur][ln][32 + qd * 8];
        f32x4 ar = {0.f, 0.f, 0.f, 0.f}, az = {0.f, 0.f, 0.f, 0.f};
        f32x4 ani = {0.f, 0.f, 0.f, 0.f}, anh = {0.f, 0.f, 0.f, 0.f};
        ar = __builtin_amdgcn_mfma_f32_16x16x32_bf16(xc0, wi_r0, ar, 0, 0, 0);
        ar = __builtin_amdgcn_mfma_f32_16x16x32_bf16(xc1, wi_r1, ar, 0, 0, 0);
        ar = __builtin_amdgcn_mfma_f32_16x16x32_bf16(ah0, wh_r0, ar, 0, 0, 0);
        ar = __builtin_amdgcn_mfma_f32_16x16x32_bf16(ah1, wh_r1, ar, 0, 0, 0);
        az = __builtin_amdgcn_mfma_f32_16x16x32_bf16(xc0, wi_z0, az, 0, 0, 0);
        az = __builtin_amdgcn_mfma_f32_16x16x32_bf16(xc1, wi_z1, az, 0, 0, 0);
        az = __builtin_amdgcn_mfma_f32_16x16x32_bf16(ah0, wh_z0, az, 0, 0, 0);
        az = __builtin_amdgcn_mfma_f32_16x16x32_bf16(ah1, wh_z1, az, 0, 0, 0);
        ani = __builtin_amdgcn_mfma_f32_16x16x32_bf16(xc0, wi_n0, ani, 0, 0, 0);
        ani = __builtin_amdgcn_mfma_f32_16x16x32_bf16(xc1, wi_n1, ani, 0, 0, 0);
        anh = __builtin_amdgcn_mfma_f32_16x16x32_bf16(ah0, wh_n0, anh, 0, 0, 0);
        anh = __builtin_amdgcn_mfma_f32_16x16x32_bf16(ah1, wh_n1, anh, 0, 0, 0);
        if (step < 255) {
            int tn = dir ? (254 - step) : (step + 1);
            xc0 = *(const short8*)(xrow + tn * 64);
            xc1 = *(const short8*)(xrow + tn * 64 + 32);
        }
#pragma unroll
        for (int r = 0; r < 4; r++) {
            float gr = sigmoidf_(ar[r] + bs_r);
            float gz = sigmoidf_(az[r] + bs_z);
            float nin = (ani[r] + bi_n) + gr * (anh[r] + bh_n);
            nin = fminf(fmaxf(nin, -15.f), 15.f);
            float e = __expf(-2.f * nin);
            float gn = (1.f - e) / (1.f + e);
            float hn = gn + gz * (h_old[r] - gn);
            h_old[r] = hn;
            hbuf[nxt][qd * 4 + r][d] = f2bu(hn);
        }
        __syncthreads();
    }
#pragma unroll
    for (int r = 0; r < 4; r++)
        h_out[(size_t)(cseq0 + qd * 4 + r) * 128 + dir * 64 + d] = h_old[r];
}

// =============================== K7: readout =================================
__global__ __launch_bounds__(128) void k_readout(
    const float* __restrict__ h_out, const float* __restrict__ gw, const float* __restrict__ gb,
    void* __restrict__ out, const int* __restrict__ flag)
{
    __shared__ float gate_s[16];
    __shared__ float gws[128];
    int b = blockIdx.x, t = threadIdx.x;
    gws[t] = gw[t];
    __syncthreads();
    int isb = *flag;
    if (t < 16) {
        const float* hr = h_out + (size_t)(b * 16 + t) * 128;
        float acc = gb[0];
        for (int k = 0; k < 128; k++) acc += hr[k] * gws[k];
        float g = sigmoidf_(acc);
        gate_s[t] = g;
        if (isb) ((bf16*)out)[12288 + b * 16 + t] = f2b(g);
        else     ((float*)out)[12288 + b * 16 + t] = g;
    }
    __syncthreads();
    float den = 1e-8f;
#pragma unroll
    for (int c = 0; c < 16; c++) den += gate_s[c];
    float num = 0.f;
#pragma unroll
    for (int c = 0; c < 16; c++) num += h_out[(size_t)(b * 16 + c) * 128 + t] * gate_s[c];
    float v = num / den;
    if (isb) ((bf16*)out)[b * 128 + t] = f2b(v);
    else     ((float*)out)[b * 128 + t] = v;
}

// =============================== launch ======================================
extern "C" void kernel_launch(void* const* d_in, const int* in_sizes, int n_in,
                              void* d_out, int out_size, void* d_ws, size_t ws_size,
                              hipStream_t stream)
{
    int* flag = (int*)d_ws;
    float* cvt = (float*)((char*)d_ws + 256);

    InPtrs P;
    InOffs O;
    int cum = 0;
    for (int i = 0; i < 35; i++) {
        P.p[i] = d_in[i];
        O.off[i] = cum;
        O.sz[i] = in_sizes[i];
        cum += (in_sizes[i] + 7) & ~7;
    }
    int total = cum;

    const float* x     = cvt + O.off[0];
    const float* c1w   = cvt + O.off[1];
    const float* c1b   = cvt + O.off[2];
    const float* bn1g  = cvt + O.off[3];
    const float* bn1b  = cvt + O.off[4];
    const float* bn1m  = cvt + O.off[5];
    const float* bn1v  = cvt + O.off[6];
    const float* c2w   = cvt + O.off[7];
    const float* c2b   = cvt + O.off[8];
    const float* bn2g  = cvt + O.off[9];
    const float* bn2b  = cvt + O.off[10];
    const float* bn2m  = cvt + O.off[11];
    const float* bn2v  = cvt + O.off[12];
    const float* prior = cvt + O.off[13];
    const float* logw  = cvt + O.off[14];
    const float* n1g   = cvt + O.off[15];
    const float* n1b   = cvt + O.off[16];
    const float* qkvw  = cvt + O.off[17];
    const float* qkvb  = cvt + O.off[18];
    const float* outw  = cvt + O.off[19];
    const float* outb  = cvt + O.off[20];
    const float* n2g   = cvt + O.off[21];
    const float* n2b   = cvt + O.off[22];
    const float* f1w   = cvt + O.off[23];
    const float* f1b   = cvt + O.off[24];
    const float* f2w   = cvt + O.off[25];
    const float* f2b_  = cvt + O.off[26];
    const float* gng   = cvt + O.off[27];
    const float* gnb   = cvt + O.off[28];
    const float* gwih  = cvt + O.off[29];
    const float* gwhh  = cvt + O.off[30];
    const float* gbih  = cvt + O.off[31];
    const float* gbhh  = cvt + O.off[32];
    const float* gatew = cvt + O.off[33];
    const float* gateb = cvt + O.off[34];

    float* fbase = cvt + ((total + 63) & ~63);
    float* hm   = fbase;                 // 8388608 floats (CNN out)
    float* Xn   = hm + 8388608;          // 1049088
    float* hnf  = Xn + 1049088;          // 32768
    float* adjw = hnf + 32768;           // 8192
    float* hout = adjw + 8192;           // 65536
    unsigned* wpk = (unsigned*)(hout + 65536);     // 62464 uints (bf16 weights)
    ushort_t* hmb = (ushort_t*)(wpk + 62464);      // 8388608 bf16 (GAT out)

    k_detect<<<1, 256, 0, stream>>>((const unsigned*)d_in[0], flag);
    k_convert<<<(total + 255) / 256, 256, 0, stream>>>(P, O, total, flag, cvt);
    k_pack<<<244, 256, 0, stream>>>(qkvw, outw, f1w, f2w, gwih, gwhh, c2w, wpk);
    k_cnn<<<512, 256, 0, stream>>>(x, c1w, c1b, bn1g, bn1b, bn1m, bn1v,
                                   c2b, bn2g, bn2b, bn2m, bn2v,
                                   (const ushort_t*)(wpk + 57344), hm);
    k_fft<<<512, 512, 0, stream>>>(x, Xn);
    k_havg<<<512, 64, 0, stream>>>(hm, hnf);
    k_adj<<<32, 256, 0, stream>>>(Xn, hnf, prior, logw, adjw, d_out, flag);
    k_gat<<<2048, 256, 0, stream>>>(hm, adjw, (const ushort_t*)wpk,
                                    qkvb, outb, f1b, f2b_, n1g, n1b, n2g, n2b, gng, gnb, hmb);
    k_gru<<<64, 256, 0, stream>>>(hmb, (const ushort_t*)(wpk + 32768), gbih, gbhh, hout);
    k_readout<<<32, 128, 0, stream>>>(hout, gatew, gateb, d_out, flag);
}

// Round 7
// 669.840 us; speedup vs baseline: 6.3857x; 1.0133x over previous
//
#include <hip/hip_runtime.h>
#include <hip/hip_bf16.h>
#include <math.h>

typedef __hip_bfloat16 bf16;
typedef unsigned short ushort_t;
typedef __attribute__((ext_vector_type(8))) short short8;
typedef __attribute__((ext_vector_type(4))) float f32x4;

__device__ __forceinline__ float b2f(bf16 v) { return __bfloat162float(v); }
__device__ __forceinline__ bf16 f2b(float v) { return __float2bfloat16(v); }
__device__ __forceinline__ float bflo(unsigned u) { return __uint_as_float(u << 16); }
__device__ __forceinline__ float bfhi(unsigned u) { return __uint_as_float(u & 0xffff0000u); }
__device__ __forceinline__ float sigmoidf_(float x) { return 1.0f / (1.0f + __expf(-x)); }

// fast exact-gelu: erf via Abramowitz-Stegun 7.1.26 (|err| <= 1.5e-7)
__device__ __forceinline__ float geluf(float x) {
    float z = x * 0.70710678118654752f;
    float az = fabsf(z);
    float t = 1.0f / (1.0f + 0.3275911f * az);
    float poly = ((((1.061405429f * t - 1.453152027f) * t + 1.421413741f) * t
                   - 0.284496736f) * t + 0.254829592f) * t;
    float erfa = 1.0f - poly * __expf(-z * z);
    float er = (z < 0.f) ? -erfa : erfa;
    return 0.5f * x * (1.0f + er);
}

// round-to-nearest-even fp32 -> bf16 bit pack
__device__ __forceinline__ unsigned pack2bf(float a, float b) {
    unsigned ua = __float_as_uint(a); ua = (ua + 0x7FFFu + ((ua >> 16) & 1u)) >> 16;
    unsigned ub = __float_as_uint(b); ub = (ub + 0x7FFFu + ((ub >> 16) & 1u)) >> 16;
    return ua | (ub << 16);
}
__device__ __forceinline__ ushort_t f2bu(float v) {
    unsigned u = __float_as_uint(v);
    u = (u + 0x7FFFu + ((u >> 16) & 1u)) >> 16;
    return (ushort_t)u;
}

// ========================== K0a: dtype detector ==============================
__global__ __launch_bounds__(256) void k_detect(const unsigned* __restrict__ x, int* __restrict__ flag)
{
    __shared__ int cnt;
    if (threadIdx.x == 0) cnt = 0;
    __syncthreads();
    unsigned u = x[threadIdx.x] & 0xFFFFu;
    float f = __uint_as_float(u << 16);
    float a = fabsf(f);
    int sane = (f == 0.0f) || (a > 1e-8f && a < 1e4f);
    atomicAdd(&cnt, sane);
    __syncthreads();
    if (threadIdx.x == 0) *flag = (cnt >= 160) ? 1 : 0;
}

// ========================== K0b: canonicalize to fp32 ========================
struct InPtrs { const void* p[35]; };
struct InOffs { int off[35]; int sz[35]; };

__global__ __launch_bounds__(256) void k_convert(InPtrs P, InOffs O, int total,
                                                 const int* __restrict__ flag,
                                                 float* __restrict__ cvt)
{
    int idx = blockIdx.x * 256 + threadIdx.x;
    if (idx >= total) return;
    int isb = *flag;
    float v = 0.f;
#pragma unroll 1
    for (int s = 0; s < 35; s++) {
        int rel = idx - O.off[s];
        if (rel >= 0 && rel < O.sz[s]) {
            v = isb ? b2f(((const bf16*)P.p[s])[rel]) : ((const float*)P.p[s])[rel];
            break;
        }
    }
    cvt[idx] = v;
}

// ========================== K0c: pack weights to bf16 ========================
// uint regions: qw 12288 | ow 4096 | f1w 8192 | f2w 8192 | gwih 12288 | gwhh 12288
//             | conv2 wt [tap][d][ic] 5120
__global__ __launch_bounds__(256) void k_pack(const float* __restrict__ qw, const float* __restrict__ ow,
                                              const float* __restrict__ f1w, const float* __restrict__ f2w,
                                              const float* __restrict__ gwih, const float* __restrict__ gwhh,
                                              const float* __restrict__ c2w,
                                              unsigned* __restrict__ dst)
{
    int i = blockIdx.x * 256 + threadIdx.x;
    if (i >= 62464) return;
    if (i >= 57344) {
        int j0 = (i - 57344) * 2;
        int tap = j0 >> 11, rem = j0 & 2047;
        int d = rem >> 5, ic = rem & 31;
        dst[i] = pack2bf(c2w[d * 160 + ic * 5 + tap], c2w[d * 160 + (ic + 1) * 5 + tap]);
        return;
    }
    const float* s; int rel;
    if (i < 12288)      { s = qw;   rel = i; }
    else if (i < 16384) { s = ow;   rel = i - 12288; }
    else if (i < 24576) { s = f1w;  rel = i - 16384; }
    else if (i < 32768) { s = f2w;  rel = i - 24576; }
    else if (i < 45056) { s = gwih; rel = i - 32768; }
    else                { s = gwhh; rel = i - 45056; }
    dst[i] = pack2bf(s[2 * rel], s[2 * rel + 1]);
}

// =============================== K1: fused CNN (MFMA conv2) ==================
__global__ __launch_bounds__(256) void k_cnn(
    const float* __restrict__ x, const float* __restrict__ c1w, const float* __restrict__ c1b,
    const float* __restrict__ bn1g, const float* __restrict__ bn1b, const float* __restrict__ bn1m, const float* __restrict__ bn1v,
    const float* __restrict__ c2b,
    const float* __restrict__ bn2g, const float* __restrict__ bn2b, const float* __restrict__ bn2m, const float* __restrict__ bn2v,
    const ushort_t* __restrict__ w2pk,
    float* __restrict__ h_main)
{
    __shared__ float ubuf[4352];          // union: xs[1056] | houtile[64][68]
    __shared__ ushort_t h1t[260 * 40];    // conv1 out bf16: row=pos (stride 40), col=ic
    __shared__ float A2s[64], B2s[64];
    int bc = blockIdx.x, t = threadIdx.x;
    int l = t & 63, w = t >> 6;
    int lo = l & 15, quad = l >> 4;

    if (t < 64) {
        float s = bn2g[t] * rsqrtf(bn2v[t] + 1e-5f);
        A2s[t] = s; B2s[t] = (c2b[t] - bn2m[t]) * s + bn2b[t];
    }
    int icp = t & 15;
    float w1r[2][7], A1r[2], B1r[2];
#pragma unroll
    for (int s = 0; s < 2; s++) {
        int ic = icp * 2 + s;
#pragma unroll
        for (int k = 0; k < 7; k++) w1r[s][k] = c1w[ic * 7 + k];
        float sc = bn1g[ic] * rsqrtf(bn1v[ic] + 1e-5f);
        A1r[s] = sc; B1r[s] = (c1b[ic] - bn1m[ic]) * sc + bn1b[ic];
    }
    short8 Afr[4][5];
#pragma unroll
    for (int dt = 0; dt < 4; dt++)
#pragma unroll
        for (int tap = 0; tap < 5; tap++)
            Afr[dt][tap] = *(const short8*)(w2pk + ((tap * 64 + dt * 16 + lo) * 32 + quad * 8));

    const float* xrow = x + (size_t)bc * 4096;
    for (int tile = 0; tile < 4; tile++) {
        int X0 = 1024 * tile - 11;
        for (int i = t; i < 1056; i += 256) {
            int g = X0 + i;
            ubuf[i] = (g >= 0 && g < 4096) ? xrow[g] : 0.0f;
        }
        __syncthreads();
        for (int pos = (t >> 4); pos < 260; pos += 16) {
            const float4* xw = (const float4*)&ubuf[4 * pos];
            float4 fa = xw[0], fb = xw[1], fc = xw[2];
            float xv[12] = {fa.x, fa.y, fa.z, fa.w, fb.x, fb.y, fb.z, fb.w,
                            fc.x, fc.y, fc.z, fc.w};
            int t1pg = tile * 256 + pos - 2;
            bool ok = (t1pg >= 0 && t1pg < 1024);
            float res[2];
#pragma unroll
            for (int s = 0; s < 2; s++) {
                float a0 = 0.f, a1 = 0.f, a2 = 0.f, a3 = 0.f;
#pragma unroll
                for (int k = 0; k < 7; k++) {
                    float wv = w1r[s][k];
                    a0 += xv[k] * wv;     a1 += xv[k + 1] * wv;
                    a2 += xv[k + 2] * wv; a3 += xv[k + 3] * wv;
                }
                float A = A1r[s], B = B1r[s];
                a0 = a0 * A + B; a1 = a1 * A + B; a2 = a2 * A + B; a3 = a3 * A + B;
                float mx = fmaxf(fmaxf(a0, a1), fmaxf(a2, a3));
                float mn = fminf(fminf(a0, a1), fminf(a2, a3));
                res[s] = ok ? fmaxf(geluf(mx), geluf(mn)) : 0.0f;
            }
            ((unsigned*)h1t)[pos * 20 + icp] = pack2bf(res[0], res[1]);
        }
        __syncthreads();
        float* houtile = ubuf;
#pragma unroll
        for (int ni = 0; ni < 4; ni++) {
            int nt = w * 4 + ni;
            short8 bf[5];
#pragma unroll
            for (int tap = 0; tap < 5; tap++)
                bf[tap] = *(const short8*)&h1t[(nt * 16 + lo + tap) * 40 + quad * 8];
#pragma unroll
            for (int dt = 0; dt < 4; dt++) {
                f32x4 acc = {0.f, 0.f, 0.f, 0.f};
#pragma unroll
                for (int tap = 0; tap < 5; tap++)
                    acc = __builtin_amdgcn_mfma_f32_16x16x32_bf16(Afr[dt][tap], bf[tap], acc, 0, 0, 0);
                const float4 a2 = *(const float4*)&A2s[dt * 16 + quad * 4];
                const float4 b2 = *(const float4*)&B2s[dt * 16 + quad * 4];
                float a2a[4] = {a2.x, a2.y, a2.z, a2.w};
                float b2a[4] = {b2.x, b2.y, b2.z, b2.w};
#pragma unroll
                for (int r = 0; r < 4; r++) {
                    float v = acc[r] * a2a[r] + b2a[r];
                    float o1 = __shfl_xor(v, 1);
                    float mx = fmaxf(v, o1), mn = fminf(v, o1);
                    float mx2 = __shfl_xor(mx, 2), mn2 = __shfl_xor(mn, 2);
                    mx = fmaxf(mx, mx2); mn = fminf(mn, mn2);
                    float res = fmaxf(geluf(mx), geluf(mn));
                    if ((lo & 3) == 0)
                        houtile[(nt * 4 + (lo >> 2)) * 68 + dt * 16 + quad * 4 + r] = res;
                }
            }
        }
        __syncthreads();
        float* dst = h_main + (size_t)bc * 16384 + tile * 4096;
        for (int i = t * 4; i < 4096; i += 1024) {
            float4 v = *(const float4*)&ubuf[(i >> 6) * 68 + (i & 63)];
            *(float4*)&dst[i] = v;
        }
        __syncthreads();
    }
}

// =============================== K2: FFT + spec norm =========================
__global__ __launch_bounds__(512) void k_fft(const float* __restrict__ x, float* __restrict__ Xn)
{
    __shared__ float re[4096];
    __shared__ float im[4096];
    __shared__ float red[8];
    int bc = blockIdx.x, t = threadIdx.x;
    const float* xr = x + (size_t)bc * 4096;
    for (int i = t; i < 4096; i += 512) {
        int r = __brev((unsigned)i) >> 20;
        re[r] = xr[i];
        im[r] = 0.f;
    }
    __syncthreads();
    for (int s = 1; s <= 12; s++) {
        int half = 1 << (s - 1);
        float ang = -6.283185307179586f / (float)(1 << s);
        for (int m = t; m < 2048; m += 512) {
            int j = m & (half - 1);
            int pos = ((m >> (s - 1)) << s) | j;
            float sn, cs;
            __sincosf(ang * (float)j, &sn, &cs);
            float ur = re[pos], ui = im[pos];
            float vr = re[pos + half], vi = im[pos + half];
            float tr = vr * cs - vi * sn;
            float ti = vr * sn + vi * cs;
            re[pos] = ur + tr; im[pos] = ui + ti;
            re[pos + half] = ur - tr; im[pos + half] = ui - ti;
        }
        __syncthreads();
    }
    float mag[5];
    float ss = 0.f;
    int cnt = 0;
    for (int f = t; f <= 2048; f += 512) {
        float m2 = re[f] * re[f] + im[f] * im[f];
        mag[cnt++] = sqrtf(m2);
        ss += m2;
    }
    for (int off = 32; off; off >>= 1) ss += __shfl_xor(ss, off, 64);
    if ((t & 63) == 0) red[t >> 6] = ss;
    __syncthreads();
    float tot = 0.f;
#pragma unroll
    for (int i = 0; i < 8; i++) tot += red[i];
    float inv = 1.0f / (sqrtf(tot) + 1e-8f);
    cnt = 0;
    for (int f = t; f <= 2048; f += 512) Xn[(size_t)bc * 2049 + f] = mag[cnt++] * inv;
}

// =============================== K3: h_avg -> hn =============================
__global__ __launch_bounds__(64) void k_havg(const float* __restrict__ hm, float* __restrict__ hnf)
{
    int bc = blockIdx.x, d = threadIdx.x;
    const float* base = hm + (size_t)bc * 16384;
    float s = 0.f;
    for (int tp = 0; tp < 256; tp++) s += base[tp * 64 + d];
    float avg = s * (1.0f / 256.0f);
    float tot = avg;
    for (int off = 32; off; off >>= 1) tot += __shfl_xor(tot, off, 64);
    float hc = avg - tot * (1.0f / 64.0f);
    float sq = hc * hc;
    for (int off = 32; off; off >>= 1) sq += __shfl_xor(sq, off, 64);
    hnf[bc * 64 + d] = hc / (sqrtf(sq) + 1e-8f);
}

// =============================== K4: adjacency ===============================
__global__ __launch_bounds__(256) void k_adj(
    const float* __restrict__ Xn, const float* __restrict__ hnf,
    const float* __restrict__ prior, const float* __restrict__ logw,
    float* __restrict__ adjw, void* __restrict__ out, const int* __restrict__ flag)
{
    __shared__ float xt[16][257];
    __shared__ float hh[16 * 64];
    int b = blockIdx.x, t = threadIdx.x;
    int c = t >> 4, e = t & 15;
    for (int i = t; i < 1024; i += 256) hh[i] = hnf[b * 1024 + i];
    __syncthreads();
    float fc = 0.f;
    for (int d = 0; d < 64; d++) fc += hh[c * 64 + d] * hh[e * 64 + d];
    float sc = 0.f;
    const float* Xb = Xn + (size_t)b * 16 * 2049;
    for (int f0 = 0; f0 < 2048; f0 += 256) {
        __syncthreads();
        for (int i = t; i < 16 * 256; i += 256) {
            int rr = i >> 8, ff = i & 255;
            xt[rr][ff] = Xb[rr * 2049 + f0 + ff];
        }
        __syncthreads();
        for (int ff = 0; ff < 256; ff++) sc += xt[c][ff] * xt[e][ff];
    }
    sc += Xb[c * 2049 + 2048] * Xb[e * 2049 + 2048];
    float l0 = logw[0], l1 = logw[1], l2 = logw[2];
    float mx = fmaxf(l0, fmaxf(l1, l2));
    float e0 = __expf(l0 - mx), e1 = __expf(l1 - mx), e2 = __expf(l2 - mx);
    float isum = 1.0f / (e0 + e1 + e2);
    float pr = prior[c * 16 + e] + prior[e * 16 + c];
    float v = (e0 * fc + e1 * sc + e2 * pr) * isum;
    adjw[b * 256 + t] = v;
    if (*flag) ((bf16*)out)[4096 + b * 256 + t] = f2b(v);
    else       ((float*)out)[4096 + b * 256 + t] = v;
}

// =============================== K5: GAT stack (MFMA) ========================
__device__ __forceinline__ void ln_wave(const float (*ht)[68], ushort_t (*out)[72],
                                        const float* __restrict__ g, const float* __restrict__ bp,
                                        int quad, int lo)
{
    float v[16];
    const float4* row = (const float4*)(&ht[lo][quad * 16]);
#pragma unroll
    for (int i = 0; i < 4; i++) {
        float4 a = row[i];
        v[4 * i] = a.x; v[4 * i + 1] = a.y; v[4 * i + 2] = a.z; v[4 * i + 3] = a.w;
    }
    float s = 0.f;
#pragma unroll
    for (int i = 0; i < 16; i++) s += v[i];
    s += __shfl_xor(s, 16); s += __shfl_xor(s, 32);
    float mean = s * (1.0f / 64.0f);
    float q = 0.f;
#pragma unroll
    for (int i = 0; i < 16; i++) { float d = v[i] - mean; q += d * d; }
    q += __shfl_xor(q, 16); q += __shfl_xor(q, 32);
    float rstd = rsqrtf(q * (1.0f / 64.0f) + 1e-5f);
    const float4* gp = (const float4*)(g + quad * 16);
    const float4* bb4 = (const float4*)(bp + quad * 16);
    unsigned* orow = (unsigned*)(&out[lo][quad * 16]);
#pragma unroll
    for (int i = 0; i < 4; i++) {
        float4 gg = gp[i], bb = bb4[i];
        float o0 = (v[4 * i] - mean) * rstd * gg.x + bb.x;
        float o1 = (v[4 * i + 1] - mean) * rstd * gg.y + bb.y;
        float o2 = (v[4 * i + 2] - mean) * rstd * gg.z + bb.z;
        float o3 = (v[4 * i + 3] - mean) * rstd * gg.w + bb.w;
        orow[2 * i] = pack2bf(o0, o1);
        orow[2 * i + 1] = pack2bf(o2, o3);
    }
}

__global__ __launch_bounds__(256) void k_gat(
    const float* __restrict__ hm, const float* __restrict__ adjw,
    const ushort_t* __restrict__ wpk,
    const float* __restrict__ qb_, const float* __restrict__ ob_,
    const float* __restrict__ f1b_, const float* __restrict__ f2b_,
    const float* __restrict__ n1g_, const float* __restrict__ n1b_,
    const float* __restrict__ n2g_, const float* __restrict__ n2b_,
    const float* __restrict__ gng, const float* __restrict__ gnb,
    ushort_t* __restrict__ hmb)
{
    __shared__ float htw_all[4][16][68];
    __shared__ ushort_t hnw_all[4][16][72];
    __shared__ ushort_t qkb_all[4][16][200];
    __shared__ ushort_t pb_all[4][16][72];
    __shared__ ushort_t vt_all[4][64][24];
    int t = threadIdx.x;
    int w = t >> 6, l = t & 63;
    int quad = l >> 4, lo = l & 15;
    int n = blockIdx.x * 4 + w;
    int b = n >> 8, tp = n & 255;
    float (*htw)[68] = htw_all[w];
    ushort_t (*hnw)[72] = hnw_all[w];
    ushort_t (*qkb)[200] = qkb_all[w];
    ushort_t (*pb)[72] = pb_all[w];
    ushort_t (*vt)[24] = vt_all[w];
    const float* src = hm + (size_t)b * 16 * 16384 + (size_t)tp * 64;
#pragma unroll
    for (int c = 0; c < 16; c++) htw[c][l] = src[(size_t)c * 16384 + l];
    float adjr[4];
#pragma unroll
    for (int r = 0; r < 4; r++) adjr[r] = adjw[b * 256 + (quad * 4 + r) * 16 + lo];

    for (int layer = 0; layer < 2; layer++) {
        const ushort_t* wq  = wpk + layer * 12288;
        const ushort_t* wo  = wpk + 24576 + layer * 4096;
        const ushort_t* wf1 = wpk + 32768 + layer * 8192;
        const ushort_t* wf2 = wpk + 49152 + layer * 8192;
        const float* qb = qb_ + layer * 192;
        const float* ob = ob_ + layer * 64;
        const float* f1b = f1b_ + layer * 128;
        const float* f2b = f2b_ + layer * 64;

        ln_wave(htw, hnw, n1g_ + layer * 64, n1b_ + layer * 64, quad, lo);

        short8 a0 = *(const short8*)&hnw[lo][quad * 8];
        short8 a1 = *(const short8*)&hnw[lo][32 + quad * 8];
#pragma unroll
        for (int nt = 0; nt < 12; nt++) {
            const ushort_t* wr = wq + (nt * 16 + lo) * 64 + quad * 8;
            short8 b0 = *(const short8*)wr;
            short8 b1 = *(const short8*)(wr + 32);
            f32x4 acc = {0.f, 0.f, 0.f, 0.f};
            acc = __builtin_amdgcn_mfma_f32_16x16x32_bf16(a0, b0, acc, 0, 0, 0);
            acc = __builtin_amdgcn_mfma_f32_16x16x32_bf16(a1, b1, acc, 0, 0, 0);
            float bias = qb[nt * 16 + lo];
            if (nt < 8) {
#pragma unroll
                for (int r = 0; r < 4; r++) qkb[quad * 4 + r][nt * 16 + lo] = f2bu(acc[r] + bias);
            } else {
#pragma unroll
                for (int r = 0; r < 4; r++) vt[(nt - 8) * 16 + lo][quad * 4 + r] = f2bu(acc[r] + bias);
            }
        }

        short8 zf = {0, 0, 0, 0, 0, 0, 0, 0};
#pragma unroll
        for (int h = 0; h < 4; h++) {
            short8 qf = zf, kf = zf;
            if (quad < 2) {
                qf = *(const short8*)&qkb[lo][h * 16 + quad * 8];
                kf = *(const short8*)&qkb[lo][64 + h * 16 + quad * 8];
            }
            f32x4 s4 = {0.f, 0.f, 0.f, 0.f};
            s4 = __builtin_amdgcn_mfma_f32_16x16x32_bf16(qf, kf, s4, 0, 0, 0);
#pragma unroll
            for (int r = 0; r < 4; r++) {
                float sv = s4[r] * 0.25f + adjr[r];
                float mx = sv;
                mx = fmaxf(mx, __shfl_xor(mx, 1));
                mx = fmaxf(mx, __shfl_xor(mx, 2));
                mx = fmaxf(mx, __shfl_xor(mx, 4));
                mx = fmaxf(mx, __shfl_xor(mx, 8));
                float e = __expf(sv - mx);
                float sm = e;
                sm += __shfl_xor(sm, 1);
                sm += __shfl_xor(sm, 2);
                sm += __shfl_xor(sm, 4);
                sm += __shfl_xor(sm, 8);
                pb[quad * 4 + r][h * 16 + lo] = f2bu(e / sm);
            }
        }
#pragma unroll
        for (int h = 0; h < 4; h++) {
            short8 pf = zf, vf = zf;
            if (quad < 2) {
                pf = *(const short8*)&pb[lo][h * 16 + quad * 8];
                vf = *(const short8*)&vt[h * 16 + lo][quad * 8];
            }
            f32x4 oc = {0.f, 0.f, 0.f, 0.f};
            oc = __builtin_amdgcn_mfma_f32_16x16x32_bf16(pf, vf, oc, 0, 0, 0);
#pragma unroll
            for (int r = 0; r < 4; r++) qkb[quad * 4 + r][h * 16 + lo] = f2bu(oc[r]);
        }
        short8 pa0 = *(const short8*)&qkb[lo][quad * 8];
        short8 pa1 = *(const short8*)&qkb[lo][32 + quad * 8];
#pragma unroll
        for (int nt = 0; nt < 4; nt++) {
            const ushort_t* wr = wo + (nt * 16 + lo) * 64 + quad * 8;
            short8 b0 = *(const short8*)wr;
            short8 b1 = *(const short8*)(wr + 32);
            f32x4 acc = {0.f, 0.f, 0.f, 0.f};
            acc = __builtin_amdgcn_mfma_f32_16x16x32_bf16(pa0, b0, acc, 0, 0, 0);
            acc = __builtin_amdgcn_mfma_f32_16x16x32_bf16(pa1, b1, acc, 0, 0, 0);
            float bias = ob[nt * 16 + lo];
#pragma unroll
            for (int r = 0; r < 4; r++) htw[quad * 4 + r][nt * 16 + lo] += acc[r] + bias;
        }
        ln_wave(htw, hnw, n2g_ + layer * 64, n2b_ + layer * 64, quad, lo);
        short8 fa0 = *(const short8*)&hnw[lo][quad * 8];
        short8 fa1 = *(const short8*)&hnw[lo][32 + quad * 8];
#pragma unroll
        for (int nt = 0; nt < 8; nt++) {
            const ushort_t* wr = wf1 + (nt * 16 + lo) * 64 + quad * 8;
            short8 b0 = *(const short8*)wr;
            short8 b1 = *(const short8*)(wr + 32);
            f32x4 acc = {0.f, 0.f, 0.f, 0.f};
            acc = __builtin_amdgcn_mfma_f32_16x16x32_bf16(fa0, b0, acc, 0, 0, 0);
            acc = __builtin_amdgcn_mfma_f32_16x16x32_bf16(fa1, b1, acc, 0, 0, 0);
            float bias = f1b[nt * 16 + lo];
#pragma unroll
            for (int r = 0; r < 4; r++) qkb[quad * 4 + r][nt * 16 + lo] = f2bu(geluf(acc[r] + bias));
        }
        short8 ga[4];
#pragma unroll
        for (int kb = 0; kb < 4; kb++) ga[kb] = *(const short8*)&qkb[lo][kb * 32 + quad * 8];
#pragma unroll
        for (int nt = 0; nt < 4; nt++) {
            const ushort_t* wr = wf2 + (nt * 16 + lo) * 128 + quad * 8;
            f32x4 acc = {0.f, 0.f, 0.f, 0.f};
#pragma unroll
            for (int kb = 0; kb < 4; kb++) {
                short8 bb = *(const short8*)(wr + kb * 32);
                acc = __builtin_amdgcn_mfma_f32_16x16x32_bf16(ga[kb], bb, acc, 0, 0, 0);
            }
            float bias = f2b[nt * 16 + lo];
#pragma unroll
            for (int r = 0; r < 4; r++) htw[quad * 4 + r][nt * 16 + lo] += acc[r] + bias;
        }
    }
    // ---- final LN -> bf16 hmb ----
    {
        float v[16];
        const float4* row = (const float4*)(&htw[lo][quad * 16]);
#pragma unroll
        for (int i = 0; i < 4; i++) {
            float4 a = row[i];
            v[4 * i] = a.x; v[4 * i + 1] = a.y; v[4 * i + 2] = a.z; v[4 * i + 3] = a.w;
        }
        float s = 0.f;
#pragma unroll
        for (int i = 0; i < 16; i++) s += v[i];
        s += __shfl_xor(s, 16); s += __shfl_xor(s, 32);
        float mean = s * (1.0f / 64.0f);
        float q = 0.f;
#pragma unroll
        for (int i = 0; i < 16; i++) { float d = v[i] - mean; q += d * d; }
        q += __shfl_xor(q, 16); q += __shfl_xor(q, 32);
        float rstd = rsqrtf(q * (1.0f / 64.0f) + 1e-5f);
        const float4* gp = (const float4*)(gng + quad * 16);
        const float4* bb4 = (const float4*)(gnb + quad * 16);
        unsigned u[8];
#pragma unroll
        for (int i = 0; i < 4; i++) {
            float4 gg = gp[i], bb = bb4[i];
            float o0 = (v[4 * i] - mean) * rstd * gg.x + bb.x;
            float o1 = (v[4 * i + 1] - mean) * rstd * gg.y + bb.y;
            float o2 = (v[4 * i + 2] - mean) * rstd * gg.z + bb.z;
            float o3 = (v[4 * i + 3] - mean) * rstd * gg.w + bb.w;
            u[2 * i] = pack2bf(o0, o1);
            u[2 * i + 1] = pack2bf(o2, o3);
        }
        ushort_t* dst = hmb + (size_t)(b * 16 + lo) * 16384 + (size_t)tp * 64 + quad * 16;
        ((uint4*)dst)[0] = make_uint4(u[0], u[1], u[2], u[3]);
        ((uint4*)dst)[1] = make_uint4(u[4], u[5], u[6], u[7]);
    }
}

// =============================== K6: GRU (MFMA, pipelined) ===================
// Raw s_barrier with lgkmcnt-only drain: global x prefetch stays in flight
// across the per-step barrier (vmcnt(0) drain was the round-6 bottleneck).
// x-side gate MFMAs accumulate one step ahead into separate accumulators;
// h-side MFMAs (2-chain) seed from them -> short critical path.
__global__ __launch_bounds__(256) void k_gru(
    const ushort_t* __restrict__ hmb, const ushort_t* __restrict__ wgru,
    const float* __restrict__ bih_, const float* __restrict__ bhh_,
    float* __restrict__ h_out)
{
    __shared__ ushort_t hbuf[2][16][72];
    int t = threadIdx.x;
    int w = t >> 6, l = t & 63;
    int ln = l & 15, qd = l >> 4;
    int dir = blockIdx.x >> 5;
    int cseq0 = (blockIdx.x & 31) * 16;
    const ushort_t* wih = wgru + dir * 12288;
    const ushort_t* whh = wgru + 24576 + dir * 12288;
    const ushort_t* pr0 = wih + ((w)*16 + ln) * 64 + qd * 8;
    const ushort_t* pz0 = wih + ((4 + w)*16 + ln) * 64 + qd * 8;
    const ushort_t* pn0 = wih + ((8 + w)*16 + ln) * 64 + qd * 8;
    const ushort_t* hr0 = whh + ((w)*16 + ln) * 64 + qd * 8;
    const ushort_t* hz0 = whh + ((4 + w)*16 + ln) * 64 + qd * 8;
    const ushort_t* hn0 = whh + ((8 + w)*16 + ln) * 64 + qd * 8;
    short8 wi_r0 = *(const short8*)pr0, wi_r1 = *(const short8*)(pr0 + 32);
    short8 wi_z0 = *(const short8*)pz0, wi_z1 = *(const short8*)(pz0 + 32);
    short8 wi_n0 = *(const short8*)pn0, wi_n1 = *(const short8*)(pn0 + 32);
    short8 wh_r0 = *(const short8*)hr0, wh_r1 = *(const short8*)(hr0 + 32);
    short8 wh_z0 = *(const short8*)hz0, wh_z1 = *(const short8*)(hz0 + 32);
    short8 wh_n0 = *(const short8*)hn0, wh_n1 = *(const short8*)(hn0 + 32);
    int d = w * 16 + ln;
    float bs_r = bih_[dir * 192 + d] + bhh_[dir * 192 + d];
    float bs_z = bih_[dir * 192 + 64 + d] + bhh_[dir * 192 + 64 + d];
    float bi_n = bih_[dir * 192 + 128 + d];
    float bh_n = bhh_[dir * 192 + 128 + d];
    const ushort_t* xrow = hmb + (size_t)(cseq0 + ln) * 16384 + qd * 8;
    for (int i = t; i < 2 * 16 * 72; i += 256) ((ushort_t*)hbuf)[i] = 0;
    float h_old[4] = {0.f, 0.f, 0.f, 0.f};

    // logical t -> physical step s = dir ? 255-t : t
    int s0 = dir ? 255 : 0;
    int s1 = dir ? 254 : 1;
    int s2 = dir ? 253 : 2;
    short8 xc0 = *(const short8*)(xrow + s0 * 64);
    short8 xc1 = *(const short8*)(xrow + s0 * 64 + 32);
    short8 xA0 = *(const short8*)(xrow + s1 * 64);      // x(t+1)
    short8 xA1 = *(const short8*)(xrow + s1 * 64 + 32);
    short8 xB0 = *(const short8*)(xrow + s2 * 64);      // x(t+2)
    short8 xB1 = *(const short8*)(xrow + s2 * 64 + 32);
    // x-side accums for t=0
    f32x4 axr = {0.f, 0.f, 0.f, 0.f}, axz = {0.f, 0.f, 0.f, 0.f}, axn = {0.f, 0.f, 0.f, 0.f};
    axr = __builtin_amdgcn_mfma_f32_16x16x32_bf16(xc0, wi_r0, axr, 0, 0, 0);
    axr = __builtin_amdgcn_mfma_f32_16x16x32_bf16(xc1, wi_r1, axr, 0, 0, 0);
    axz = __builtin_amdgcn_mfma_f32_16x16x32_bf16(xc0, wi_z0, axz, 0, 0, 0);
    axz = __builtin_amdgcn_mfma_f32_16x16x32_bf16(xc1, wi_z1, axz, 0, 0, 0);
    axn = __builtin_amdgcn_mfma_f32_16x16x32_bf16(xc0, wi_n0, axn, 0, 0, 0);
    axn = __builtin_amdgcn_mfma_f32_16x16x32_bf16(xc1, wi_n1, axn, 0, 0, 0);
    __syncthreads();
#pragma unroll 2
    for (int step = 0; step < 256; step++) {
        int cur = step & 1, nxt = cur ^ 1;
        // ---- off-critical: build x-accums for t+1 from xA ----
        f32x4 nxr = {0.f, 0.f, 0.f, 0.f}, nxz = {0.f, 0.f, 0.f, 0.f}, nxn = {0.f, 0.f, 0.f, 0.f};
        nxr = __builtin_amdgcn_mfma_f32_16x16x32_bf16(xA0, wi_r0, nxr, 0, 0, 0);
        nxr = __builtin_amdgcn_mfma_f32_16x16x32_bf16(xA1, wi_r1, nxr, 0, 0, 0);
        nxz = __builtin_amdgcn_mfma_f32_16x16x32_bf16(xA0, wi_z0, nxz, 0, 0, 0);
        nxz = __builtin_amdgcn_mfma_f32_16x16x32_bf16(xA1, wi_z1, nxz, 0, 0, 0);
        nxn = __builtin_amdgcn_mfma_f32_16x16x32_bf16(xA0, wi_n0, nxn, 0, 0, 0);
        nxn = __builtin_amdgcn_mfma_f32_16x16x32_bf16(xA1, wi_n1, nxn, 0, 0, 0);
        // rotate prefetch: xA <- xB, issue load for t+3
        xA0 = xB0; xA1 = xB1;
        int tl = step + 3 > 255 ? 255 : step + 3;
        int sf = dir ? 255 - tl : tl;
        xB0 = *(const short8*)(xrow + sf * 64);
        xB1 = *(const short8*)(xrow + sf * 64 + 32);
        // ---- critical path: h-side ----
        short8 ah0 = *(const short8*)&hbuf[cur][ln][qd * 8];
        short8 ah1 = *(const short8*)&hbuf[cur][ln][32 + qd * 8];
        f32x4 ar = axr, az = axz;
        f32x4 anh = {0.f, 0.f, 0.f, 0.f};
        ar = __builtin_amdgcn_mfma_f32_16x16x32_bf16(ah0, wh_r0, ar, 0, 0, 0);
        ar = __builtin_amdgcn_mfma_f32_16x16x32_bf16(ah1, wh_r1, ar, 0, 0, 0);
        az = __builtin_amdgcn_mfma_f32_16x16x32_bf16(ah0, wh_z0, az, 0, 0, 0);
        az = __builtin_amdgcn_mfma_f32_16x16x32_bf16(ah1, wh_z1, az, 0, 0, 0);
        anh = __builtin_amdgcn_mfma_f32_16x16x32_bf16(ah0, wh_n0, anh, 0, 0, 0);
        anh = __builtin_amdgcn_mfma_f32_16x16x32_bf16(ah1, wh_n1, anh, 0, 0, 0);
#pragma unroll
        for (int r = 0; r < 4; r++) {
            float gr = sigmoidf_(ar[r] + bs_r);
            float gz = sigmoidf_(az[r] + bs_z);
            float nin = (axn[r] + bi_n) + gr * (anh[r] + bh_n);
            nin = fminf(fmaxf(nin, -15.f), 15.f);
            float e = __expf(-2.f * nin);
            float gn = (1.f - e) / (1.f + e);
            float hn = gn + gz * (h_old[r] - gn);
            h_old[r] = hn;
            hbuf[nxt][qd * 4 + r][d] = f2bu(hn);
        }
        // lgkm-only drain + barrier: vmcnt loads stay in flight
        asm volatile("s_waitcnt lgkmcnt(0)\n\ts_barrier" ::: "memory");
        axr = nxr; axz = nxz; axn = nxn;
    }
#pragma unroll
    for (int r = 0; r < 4; r++)
        h_out[(size_t)(cseq0 + qd * 4 + r) * 128 + dir * 64 + d] = h_old[r];
}

// =============================== K7: readout =================================
__global__ __launch_bounds__(128) void k_readout(
    const float* __restrict__ h_out, const float* __restrict__ gw, const float* __restrict__ gb,
    void* __restrict__ out, const int* __restrict__ flag)
{
    __shared__ float gate_s[16];
    __shared__ float gws[128];
    int b = blockIdx.x, t = threadIdx.x;
    gws[t] = gw[t];
    __syncthreads();
    int isb = *flag;
    if (t < 16) {
        const float* hr = h_out + (size_t)(b * 16 + t) * 128;
        float acc = gb[0];
        for (int k = 0; k < 128; k++) acc += hr[k] * gws[k];
        float g = sigmoidf_(acc);
        gate_s[t] = g;
        if (isb) ((bf16*)out)[12288 + b * 16 + t] = f2b(g);
        else     ((float*)out)[12288 + b * 16 + t] = g;
    }
    __syncthreads();
    float den = 1e-8f;
#pragma unroll
    for (int c = 0; c < 16; c++) den += gate_s[c];
    float num = 0.f;
#pragma unroll
    for (int c = 0; c < 16; c++) num += h_out[(size_t)(b * 16 + c) * 128 + t] * gate_s[c];
    float v = num / den;
    if (isb) ((bf16*)out)[b * 128 + t] = f2b(v);
    else     ((float*)out)[b * 128 + t] = v;
}

// =============================== launch ======================================
extern "C" void kernel_launch(void* const* d_in, const int* in_sizes, int n_in,
                              void* d_out, int out_size, void* d_ws, size_t ws_size,
                              hipStream_t stream)
{
    int* flag = (int*)d_ws;
    float* cvt = (float*)((char*)d_ws + 256);

    InPtrs P;
    InOffs O;
    int cum = 0;
    for (int i = 0; i < 35; i++) {
        P.p[i] = d_in[i];
        O.off[i] = cum;
        O.sz[i] = in_sizes[i];
        cum += (in_sizes[i] + 7) & ~7;
    }
    int total = cum;

    const float* x     = cvt + O.off[0];
    const float* c1w   = cvt + O.off[1];
    const float* c1b   = cvt + O.off[2];
    const float* bn1g  = cvt + O.off[3];
    const float* bn1b  = cvt + O.off[4];
    const float* bn1m  = cvt + O.off[5];
    const float* bn1v  = cvt + O.off[6];
    const float* c2w   = cvt + O.off[7];
    const float* c2b   = cvt + O.off[8];
    const float* bn2g  = cvt + O.off[9];
    const float* bn2b  = cvt + O.off[10];
    const float* bn2m  = cvt + O.off[11];
    const float* bn2v  = cvt + O.off[12];
    const float* prior = cvt + O.off[13];
    const float* logw  = cvt + O.off[14];
    const float* n1g   = cvt + O.off[15];
    const float* n1b   = cvt + O.off[16];
    const float* qkvw  = cvt + O.off[17];
    const float* qkvb  = cvt + O.off[18];
    const float* outw  = cvt + O.off[19];
    const float* outb  = cvt + O.off[20];
    const float* n2g   = cvt + O.off[21];
    const float* n2b   = cvt + O.off[22];
    const float* f1w   = cvt + O.off[23];
    const float* f1b   = cvt + O.off[24];
    const float* f2w   = cvt + O.off[25];
    const float* f2b_  = cvt + O.off[26];
    const float* gng   = cvt + O.off[27];
    const float* gnb   = cvt + O.off[28];
    const float* gwih  = cvt + O.off[29];
    const float* gwhh  = cvt + O.off[30];
    const float* gbih  = cvt + O.off[31];
    const float* gbhh  = cvt + O.off[32];
    const float* gatew = cvt + O.off[33];
    const float* gateb = cvt + O.off[34];

    float* fbase = cvt + ((total + 63) & ~63);
    float* hm   = fbase;                 // 8388608 floats (CNN out)
    float* Xn   = hm + 8388608;          // 1049088
    float* hnf  = Xn + 1049088;          // 32768
    float* adjw = hnf + 32768;           // 8192
    float* hout = adjw + 8192;           // 65536
    unsigned* wpk = (unsigned*)(hout + 65536);     // 62464 uints (bf16 weights)
    ushort_t* hmb = (ushort_t*)(wpk + 62464);      // 8388608 bf16 (GAT out)

    k_detect<<<1, 256, 0, stream>>>((const unsigned*)d_in[0], flag);
    k_convert<<<(total + 255) / 256, 256, 0, stream>>>(P, O, total, flag, cvt);
    k_pack<<<244, 256, 0, stream>>>(qkvw, outw, f1w, f2w, gwih, gwhh, c2w, wpk);
    k_cnn<<<512, 256, 0, stream>>>(x, c1w, c1b, bn1g, bn1b, bn1m, bn1v,
                                   c2b, bn2g, bn2b, bn2m, bn2v,
                                   (const ushort_t*)(wpk + 57344), hm);
    k_fft<<<512, 512, 0, stream>>>(x, Xn);
    k_havg<<<512, 64, 0, stream>>>(hm, hnf);
    k_adj<<<32, 256, 0, stream>>>(Xn, hnf, prior, logw, adjw, d_out, flag);
    k_gat<<<2048, 256, 0, stream>>>(hm, adjw, (const ushort_t*)wpk,
                                    qkvb, outb, f1b, f2b_, n1g, n1b, n2g, n2b, gng, gnb, hmb);
    k_gru<<<64, 256, 0, stream>>>(hmb, (const ushort_t*)(wpk + 32768), gbih, gbhh, hout);
    k_readout<<<32, 128, 0, stream>>>(hout, gatew, gateb, d_out, flag);
}

// Round 8
// 652.360 us; speedup vs baseline: 6.5568x; 1.0268x over previous
//
#include <hip/hip_runtime.h>
#include <hip/hip_bf16.h>
#include <math.h>

typedef __hip_bfloat16 bf16;
typedef unsigned short ushort_t;
typedef __attribute__((ext_vector_type(8))) short short8;
typedef __attribute__((ext_vector_type(4))) float f32x4;

__device__ __forceinline__ float b2f(bf16 v) { return __bfloat162float(v); }
__device__ __forceinline__ bf16 f2b(float v) { return __float2bfloat16(v); }
__device__ __forceinline__ float sigmoidf_(float x) { return 1.0f / (1.0f + __expf(-x)); }

// fast exact-gelu: erf via Abramowitz-Stegun 7.1.26 (|err| <= 1.5e-7)
__device__ __forceinline__ float geluf(float x) {
    float z = x * 0.70710678118654752f;
    float az = fabsf(z);
    float t = 1.0f / (1.0f + 0.3275911f * az);
    float poly = ((((1.061405429f * t - 1.453152027f) * t + 1.421413741f) * t
                   - 0.284496736f) * t + 0.254829592f) * t;
    float erfa = 1.0f - poly * __expf(-z * z);
    float er = (z < 0.f) ? -erfa : erfa;
    return 0.5f * x * (1.0f + er);
}

__device__ __forceinline__ unsigned pack2bf(float a, float b) {
    unsigned ua = __float_as_uint(a); ua = (ua + 0x7FFFu + ((ua >> 16) & 1u)) >> 16;
    unsigned ub = __float_as_uint(b); ub = (ub + 0x7FFFu + ((ub >> 16) & 1u)) >> 16;
    return ua | (ub << 16);
}
__device__ __forceinline__ ushort_t f2bu(float v) {
    unsigned u = __float_as_uint(v);
    u = (u + 0x7FFFu + ((u >> 16) & 1u)) >> 16;
    return (ushort_t)u;
}

// ========================== K0a: dtype detector ==============================
__global__ __launch_bounds__(256) void k_detect(const unsigned* __restrict__ x, int* __restrict__ flag)
{
    __shared__ int cnt;
    if (threadIdx.x == 0) cnt = 0;
    __syncthreads();
    unsigned u = x[threadIdx.x] & 0xFFFFu;
    float f = __uint_as_float(u << 16);
    float a = fabsf(f);
    int sane = (f == 0.0f) || (a > 1e-8f && a < 1e4f);
    atomicAdd(&cnt, sane);
    __syncthreads();
    if (threadIdx.x == 0) *flag = (cnt >= 160) ? 1 : 0;
}

// ========================== K0b: canonicalize to fp32 ========================
struct InPtrs { const void* p[35]; };
struct InOffs { int off[35]; int sz[35]; };

__global__ __launch_bounds__(256) void k_convert(InPtrs P, InOffs O, int total,
                                                 const int* __restrict__ flag,
                                                 float* __restrict__ cvt)
{
    int idx = blockIdx.x * 256 + threadIdx.x;
    if (idx >= total) return;
    int isb = *flag;
    float v = 0.f;
#pragma unroll 1
    for (int s = 0; s < 35; s++) {
        int rel = idx - O.off[s];
        if (rel >= 0 && rel < O.sz[s]) {
            v = isb ? b2f(((const bf16*)P.p[s])[rel]) : ((const float*)P.p[s])[rel];
            break;
        }
    }
    cvt[idx] = v;
}

// ========================== K0c: pack weights to bf16 ========================
// uint regions: qw 12288 | ow 4096 | f1w 8192 | f2w 8192 | gwih 12288 | gwhh 12288
//             | conv2 wt [tap][d][ic] 5120
__global__ __launch_bounds__(256) void k_pack(const float* __restrict__ qw, const float* __restrict__ ow,
                                              const float* __restrict__ f1w, const float* __restrict__ f2w,
                                              const float* __restrict__ gwih, const float* __restrict__ gwhh,
                                              const float* __restrict__ c2w,
                                              unsigned* __restrict__ dst)
{
    int i = blockIdx.x * 256 + threadIdx.x;
    if (i >= 62464) return;
    if (i >= 57344) {
        int j0 = (i - 57344) * 2;
        int tap = j0 >> 11, rem = j0 & 2047;
        int d = rem >> 5, ic = rem & 31;
        dst[i] = pack2bf(c2w[d * 160 + ic * 5 + tap], c2w[d * 160 + (ic + 1) * 5 + tap]);
        return;
    }
    const float* s; int rel;
    if (i < 12288)      { s = qw;   rel = i; }
    else if (i < 16384) { s = ow;   rel = i - 12288; }
    else if (i < 24576) { s = f1w;  rel = i - 16384; }
    else if (i < 32768) { s = f2w;  rel = i - 24576; }
    else if (i < 45056) { s = gwih; rel = i - 32768; }
    else                { s = gwhh; rel = i - 45056; }
    dst[i] = pack2bf(s[2 * rel], s[2 * rel + 1]);
}

// ====================== K1: fused front (CNN+havg | FFT) =====================
// blocks 0..511: CNN (conv1 VALU + conv2 tap-GEMM MFMA) + h_avg/hn epilogue.
// blocks 512..1023: 4096-pt radix-2 FFT + spectral norm.
// Co-grid: both are latency-bound and independent -> co-residency overlaps.
__global__ __launch_bounds__(256) void k_front(
    const float* __restrict__ x,
    const float* __restrict__ c1w, const float* __restrict__ c1b,
    const float* __restrict__ bn1g, const float* __restrict__ bn1b, const float* __restrict__ bn1m, const float* __restrict__ bn1v,
    const float* __restrict__ c2b,
    const float* __restrict__ bn2g, const float* __restrict__ bn2b, const float* __restrict__ bn2m, const float* __restrict__ bn2v,
    const ushort_t* __restrict__ w2pk,
    float* __restrict__ h_main, float* __restrict__ Xn, float* __restrict__ hnf)
{
    __shared__ float smem[9984];
    int t = threadIdx.x;
    if (blockIdx.x >= 512) {
        // ---------------- FFT path ----------------
        float* re = smem;
        float* im = smem + 4096;
        float* red = smem + 8192;
        int bc = blockIdx.x - 512;
        const float* xr = x + (size_t)bc * 4096;
        for (int i = t; i < 4096; i += 256) {
            int r = __brev((unsigned)i) >> 20;
            re[r] = xr[i];
            im[r] = 0.f;
        }
        __syncthreads();
        for (int s = 1; s <= 12; s++) {
            int half = 1 << (s - 1);
            float ang = -6.283185307179586f / (float)(1 << s);
            for (int m = t; m < 2048; m += 256) {
                int j = m & (half - 1);
                int pos = ((m >> (s - 1)) << s) | j;
                float sn, cs;
                __sincosf(ang * (float)j, &sn, &cs);
                float ur = re[pos], ui = im[pos];
                float vr = re[pos + half], vi = im[pos + half];
                float tr = vr * cs - vi * sn;
                float ti = vr * sn + vi * cs;
                re[pos] = ur + tr; im[pos] = ui + ti;
                re[pos + half] = ur - tr; im[pos + half] = ui - ti;
            }
            __syncthreads();
        }
        float mag[9];
        float ss = 0.f;
        int cnt = 0;
        for (int f = t; f <= 2048; f += 256) {
            float m2 = re[f] * re[f] + im[f] * im[f];
            mag[cnt++] = sqrtf(m2);
            ss += m2;
        }
        for (int off = 32; off; off >>= 1) ss += __shfl_xor(ss, off, 64);
        if ((t & 63) == 0) red[t >> 6] = ss;
        __syncthreads();
        float tot = red[0] + red[1] + red[2] + red[3];
        float inv = 1.0f / (sqrtf(tot) + 1e-8f);
        cnt = 0;
        for (int f = t; f <= 2048; f += 256) Xn[(size_t)bc * 2049 + f] = mag[cnt++] * inv;
        return;
    }
    // ---------------- CNN path ----------------
    float* ubuf = smem;                           // 4352 floats
    ushort_t* h1t = (ushort_t*)(smem + 4352);     // 10400 ushorts (260 rows x 40)
    float* A2s = smem + 9552;
    float* B2s = smem + 9616;
    float* hsum = smem + 9680;                    // 256
    int bc = blockIdx.x;
    int l = t & 63, w = t >> 6;
    int lo = l & 15, quad = l >> 4;

    if (t < 64) {
        float s = bn2g[t] * rsqrtf(bn2v[t] + 1e-5f);
        A2s[t] = s; B2s[t] = (c2b[t] - bn2m[t]) * s + bn2b[t];
    }
    int icp = t & 15;
    float w1r[2][7], A1r[2], B1r[2];
#pragma unroll
    for (int s = 0; s < 2; s++) {
        int ic = icp * 2 + s;
#pragma unroll
        for (int k = 0; k < 7; k++) w1r[s][k] = c1w[ic * 7 + k];
        float sc = bn1g[ic] * rsqrtf(bn1v[ic] + 1e-5f);
        A1r[s] = sc; B1r[s] = (c1b[ic] - bn1m[ic]) * sc + bn1b[ic];
    }
    short8 Afr[4][5];
#pragma unroll
    for (int dt = 0; dt < 4; dt++)
#pragma unroll
        for (int tap = 0; tap < 5; tap++)
            Afr[dt][tap] = *(const short8*)(w2pk + ((tap * 64 + dt * 16 + lo) * 32 + quad * 8));

    const float* xrow = x + (size_t)bc * 4096;
    float rs = 0.f;
    int dd = t & 63, pg = t >> 6;
    for (int tile = 0; tile < 4; tile++) {
        int X0 = 1024 * tile - 11;
        for (int i = t; i < 1056; i += 256) {
            int g = X0 + i;
            ubuf[i] = (g >= 0 && g < 4096) ? xrow[g] : 0.0f;
        }
        __syncthreads();
        for (int pos = (t >> 4); pos < 260; pos += 16) {
            const float4* xw = (const float4*)&ubuf[4 * pos];
            float4 fa = xw[0], fb = xw[1], fc = xw[2];
            float xv[12] = {fa.x, fa.y, fa.z, fa.w, fb.x, fb.y, fb.z, fb.w,
                            fc.x, fc.y, fc.z, fc.w};
            int t1pg = tile * 256 + pos - 2;
            bool ok = (t1pg >= 0 && t1pg < 1024);
            float res[2];
#pragma unroll
            for (int s = 0; s < 2; s++) {
                float a0 = 0.f, a1 = 0.f, a2 = 0.f, a3 = 0.f;
#pragma unroll
                for (int k = 0; k < 7; k++) {
                    float wv = w1r[s][k];
                    a0 += xv[k] * wv;     a1 += xv[k + 1] * wv;
                    a2 += xv[k + 2] * wv; a3 += xv[k + 3] * wv;
                }
                float A = A1r[s], B = B1r[s];
                a0 = a0 * A + B; a1 = a1 * A + B; a2 = a2 * A + B; a3 = a3 * A + B;
                float mx = fmaxf(fmaxf(a0, a1), fmaxf(a2, a3));
                float mn = fminf(fminf(a0, a1), fminf(a2, a3));
                res[s] = ok ? fmaxf(geluf(mx), geluf(mn)) : 0.0f;
            }
            ((unsigned*)h1t)[pos * 20 + icp] = pack2bf(res[0], res[1]);
        }
        __syncthreads();
        float* houtile = ubuf;
#pragma unroll
        for (int ni = 0; ni < 4; ni++) {
            int nt = w * 4 + ni;
            short8 bfr[5];
#pragma unroll
            for (int tap = 0; tap < 5; tap++)
                bfr[tap] = *(const short8*)&h1t[(nt * 16 + lo + tap) * 40 + quad * 8];
#pragma unroll
            for (int dt = 0; dt < 4; dt++) {
                f32x4 acc = {0.f, 0.f, 0.f, 0.f};
#pragma unroll
                for (int tap = 0; tap < 5; tap++)
                    acc = __builtin_amdgcn_mfma_f32_16x16x32_bf16(Afr[dt][tap], bfr[tap], acc, 0, 0, 0);
                const float4 a2 = *(const float4*)&A2s[dt * 16 + quad * 4];
                const float4 b2 = *(const float4*)&B2s[dt * 16 + quad * 4];
                float a2a[4] = {a2.x, a2.y, a2.z, a2.w};
                float b2a[4] = {b2.x, b2.y, b2.z, b2.w};
#pragma unroll
                for (int r = 0; r < 4; r++) {
                    float v = acc[r] * a2a[r] + b2a[r];
                    float o1 = __shfl_xor(v, 1);
                    float mx = fmaxf(v, o1), mn = fminf(v, o1);
                    float mx2 = __shfl_xor(mx, 2), mn2 = __shfl_xor(mn, 2);
                    mx = fmaxf(mx, mx2); mn = fminf(mn, mn2);
                    float res = fmaxf(geluf(mx), geluf(mn));
                    if ((lo & 3) == 0)
                        houtile[(nt * 4 + (lo >> 2)) * 68 + dt * 16 + quad * 4 + r] = res;
                }
            }
        }
        __syncthreads();
        // accumulate for h_avg (read-only on ubuf, concurrent with flush)
#pragma unroll
        for (int i = 0; i < 16; i++) rs += ubuf[(pg * 16 + i) * 68 + dd];
        float* dst = h_main + (size_t)bc * 16384 + tile * 4096;
        for (int i = t * 4; i < 4096; i += 1024) {
            float4 v = *(const float4*)&ubuf[(i >> 6) * 68 + (i & 63)];
            *(float4*)&dst[i] = v;
        }
        __syncthreads();
    }
    // ---- havg epilogue: mean over tp, center over d, normalize ----
    hsum[t] = rs;
    __syncthreads();
    if (t < 64) {
        float avg = (hsum[t] + hsum[64 + t] + hsum[128 + t] + hsum[192 + t]) * (1.0f / 256.0f);
        float tot = avg;
        for (int off = 32; off; off >>= 1) tot += __shfl_xor(tot, off, 64);
        float hc = avg - tot * (1.0f / 64.0f);
        float sq = hc * hc;
        for (int off = 32; off; off >>= 1) sq += __shfl_xor(sq, off, 64);
        hnf[bc * 64 + t] = hc / (sqrtf(sq) + 1e-8f);
    }
}

// =============================== K4: adjacency ===============================
__global__ __launch_bounds__(256) void k_adj(
    const float* __restrict__ Xn, const float* __restrict__ hnf,
    const float* __restrict__ prior, const float* __restrict__ logw,
    float* __restrict__ adjw, void* __restrict__ out, const int* __restrict__ flag)
{
    __shared__ float xt[16][257];
    __shared__ float hh[16 * 64];
    int b = blockIdx.x, t = threadIdx.x;
    int c = t >> 4, e = t & 15;
    for (int i = t; i < 1024; i += 256) hh[i] = hnf[b * 1024 + i];
    __syncthreads();
    float fc = 0.f;
    for (int d = 0; d < 64; d++) fc += hh[c * 64 + d] * hh[e * 64 + d];
    float sc = 0.f;
    const float* Xb = Xn + (size_t)b * 16 * 2049;
    for (int f0 = 0; f0 < 2048; f0 += 256) {
        __syncthreads();
        for (int i = t; i < 16 * 256; i += 256) {
            int rr = i >> 8, ff = i & 255;
            xt[rr][ff] = Xb[rr * 2049 + f0 + ff];
        }
        __syncthreads();
        for (int ff = 0; ff < 256; ff++) sc += xt[c][ff] * xt[e][ff];
    }
    sc += Xb[c * 2049 + 2048] * Xb[e * 2049 + 2048];
    float l0 = logw[0], l1 = logw[1], l2 = logw[2];
    float mx = fmaxf(l0, fmaxf(l1, l2));
    float e0 = __expf(l0 - mx), e1 = __expf(l1 - mx), e2 = __expf(l2 - mx);
    float isum = 1.0f / (e0 + e1 + e2);
    float pr = prior[c * 16 + e] + prior[e * 16 + c];
    float v = (e0 * fc + e1 * sc + e2 * pr) * isum;
    adjw[b * 256 + t] = v;
    if (*flag) ((bf16*)out)[4096 + b * 256 + t] = f2b(v);
    else       ((float*)out)[4096 + b * 256 + t] = v;
}

// =============================== K5: GAT stack (MFMA) ========================
__device__ __forceinline__ void ln_wave(const float (*ht)[68], ushort_t (*out)[72],
                                        const float* __restrict__ g, const float* __restrict__ bp,
                                        int quad, int lo)
{
    float v[16];
    const float4* row = (const float4*)(&ht[lo][quad * 16]);
#pragma unroll
    for (int i = 0; i < 4; i++) {
        float4 a = row[i];
        v[4 * i] = a.x; v[4 * i + 1] = a.y; v[4 * i + 2] = a.z; v[4 * i + 3] = a.w;
    }
    float s = 0.f;
#pragma unroll
    for (int i = 0; i < 16; i++) s += v[i];
    s += __shfl_xor(s, 16); s += __shfl_xor(s, 32);
    float mean = s * (1.0f / 64.0f);
    float q = 0.f;
#pragma unroll
    for (int i = 0; i < 16; i++) { float d = v[i] - mean; q += d * d; }
    q += __shfl_xor(q, 16); q += __shfl_xor(q, 32);
    float rstd = rsqrtf(q * (1.0f / 64.0f) + 1e-5f);
    const float4* gp = (const float4*)(g + quad * 16);
    const float4* bb4 = (const float4*)(bp + quad * 16);
    unsigned* orow = (unsigned*)(&out[lo][quad * 16]);
#pragma unroll
    for (int i = 0; i < 4; i++) {
        float4 gg = gp[i], bb = bb4[i];
        float o0 = (v[4 * i] - mean) * rstd * gg.x + bb.x;
        float o1 = (v[4 * i + 1] - mean) * rstd * gg.y + bb.y;
        float o2 = (v[4 * i + 2] - mean) * rstd * gg.z + bb.z;
        float o3 = (v[4 * i + 3] - mean) * rstd * gg.w + bb.w;
        orow[2 * i] = pack2bf(o0, o1);
        orow[2 * i + 1] = pack2bf(o2, o3);
    }
}

__global__ __launch_bounds__(256) void k_gat(
    const float* __restrict__ hm, const float* __restrict__ adjw,
    const ushort_t* __restrict__ wpk,
    const float* __restrict__ qb_, const float* __restrict__ ob_,
    const float* __restrict__ f1b_, const float* __restrict__ f2b_,
    const float* __restrict__ n1g_, const float* __restrict__ n1b_,
    const float* __restrict__ n2g_, const float* __restrict__ n2b_,
    const float* __restrict__ gng, const float* __restrict__ gnb,
    ushort_t* __restrict__ hmb)
{
    __shared__ float htw_all[4][16][68];
    __shared__ ushort_t hnw_all[4][16][72];
    __shared__ ushort_t qkb_all[4][16][200];
    __shared__ ushort_t pb_all[4][16][72];
    __shared__ ushort_t vt_all[4][64][24];
    int t = threadIdx.x;
    int w = t >> 6, l = t & 63;
    int quad = l >> 4, lo = l & 15;
    int n = blockIdx.x * 4 + w;
    int b = n >> 8, tp = n & 255;
    float (*htw)[68] = htw_all[w];
    ushort_t (*hnw)[72] = hnw_all[w];
    ushort_t (*qkb)[200] = qkb_all[w];
    ushort_t (*pb)[72] = pb_all[w];
    ushort_t (*vt)[24] = vt_all[w];
    const float* src = hm + (size_t)b * 16 * 16384 + (size_t)tp * 64;
#pragma unroll
    for (int c = 0; c < 16; c++) htw[c][l] = src[(size_t)c * 16384 + l];
    float adjr[4];
#pragma unroll
    for (int r = 0; r < 4; r++) adjr[r] = adjw[b * 256 + (quad * 4 + r) * 16 + lo];

    for (int layer = 0; layer < 2; layer++) {
        const ushort_t* wq  = wpk + layer * 12288;
        const ushort_t* wo  = wpk + 24576 + layer * 4096;
        const ushort_t* wf1 = wpk + 32768 + layer * 8192;
        const ushort_t* wf2 = wpk + 49152 + layer * 8192;
        const float* qb = qb_ + layer * 192;
        const float* ob = ob_ + layer * 64;
        const float* f1b = f1b_ + layer * 128;
        const float* f2b = f2b_ + layer * 64;

        ln_wave(htw, hnw, n1g_ + layer * 64, n1b_ + layer * 64, quad, lo);

        short8 a0 = *(const short8*)&hnw[lo][quad * 8];
        short8 a1 = *(const short8*)&hnw[lo][32 + quad * 8];
#pragma unroll
        for (int nt = 0; nt < 12; nt++) {
            const ushort_t* wr = wq + (nt * 16 + lo) * 64 + quad * 8;
            short8 b0 = *(const short8*)wr;
            short8 b1 = *(const short8*)(wr + 32);
            f32x4 acc = {0.f, 0.f, 0.f, 0.f};
            acc = __builtin_amdgcn_mfma_f32_16x16x32_bf16(a0, b0, acc, 0, 0, 0);
            acc = __builtin_amdgcn_mfma_f32_16x16x32_bf16(a1, b1, acc, 0, 0, 0);
            float bias = qb[nt * 16 + lo];
            if (nt < 8) {
#pragma unroll
                for (int r = 0; r < 4; r++) qkb[quad * 4 + r][nt * 16 + lo] = f2bu(acc[r] + bias);
            } else {
#pragma unroll
                for (int r = 0; r < 4; r++) vt[(nt - 8) * 16 + lo][quad * 4 + r] = f2bu(acc[r] + bias);
            }
        }

        short8 zf = {0, 0, 0, 0, 0, 0, 0, 0};
#pragma unroll
        for (int h = 0; h < 4; h++) {
            short8 qf = zf, kf = zf;
            if (quad < 2) {
                qf = *(const short8*)&qkb[lo][h * 16 + quad * 8];
                kf = *(const short8*)&qkb[lo][64 + h * 16 + quad * 8];
            }
            f32x4 s4 = {0.f, 0.f, 0.f, 0.f};
            s4 = __builtin_amdgcn_mfma_f32_16x16x32_bf16(qf, kf, s4, 0, 0, 0);
#pragma unroll
            for (int r = 0; r < 4; r++) {
                float sv = s4[r] * 0.25f + adjr[r];
                float mx = sv;
                mx = fmaxf(mx, __shfl_xor(mx, 1));
                mx = fmaxf(mx, __shfl_xor(mx, 2));
                mx = fmaxf(mx, __shfl_xor(mx, 4));
                mx = fmaxf(mx, __shfl_xor(mx, 8));
                float e = __expf(sv - mx);
                float sm = e;
                sm += __shfl_xor(sm, 1);
                sm += __shfl_xor(sm, 2);
                sm += __shfl_xor(sm, 4);
                sm += __shfl_xor(sm, 8);
                pb[quad * 4 + r][h * 16 + lo] = f2bu(e / sm);
            }
        }
#pragma unroll
        for (int h = 0; h < 4; h++) {
            short8 pf = zf, vf = zf;
            if (quad < 2) {
                pf = *(const short8*)&pb[lo][h * 16 + quad * 8];
                vf = *(const short8*)&vt[h * 16 + lo][quad * 8];
            }
            f32x4 oc = {0.f, 0.f, 0.f, 0.f};
            oc = __builtin_amdgcn_mfma_f32_16x16x32_bf16(pf, vf, oc, 0, 0, 0);
#pragma unroll
            for (int r = 0; r < 4; r++) qkb[quad * 4 + r][h * 16 + lo] = f2bu(oc[r]);
        }
        short8 pa0 = *(const short8*)&qkb[lo][quad * 8];
        short8 pa1 = *(const short8*)&qkb[lo][32 + quad * 8];
#pragma unroll
        for (int nt = 0; nt < 4; nt++) {
            const ushort_t* wr = wo + (nt * 16 + lo) * 64 + quad * 8;
            short8 b0 = *(const short8*)wr;
            short8 b1 = *(const short8*)(wr + 32);
            f32x4 acc = {0.f, 0.f, 0.f, 0.f};
            acc = __builtin_amdgcn_mfma_f32_16x16x32_bf16(pa0, b0, acc, 0, 0, 0);
            acc = __builtin_amdgcn_mfma_f32_16x16x32_bf16(pa1, b1, acc, 0, 0, 0);
            float bias = ob[nt * 16 + lo];
#pragma unroll
            for (int r = 0; r < 4; r++) htw[quad * 4 + r][nt * 16 + lo] += acc[r] + bias;
        }
        ln_wave(htw, hnw, n2g_ + layer * 64, n2b_ + layer * 64, quad, lo);
        short8 fa0 = *(const short8*)&hnw[lo][quad * 8];
        short8 fa1 = *(const short8*)&hnw[lo][32 + quad * 8];
#pragma unroll
        for (int nt = 0; nt < 8; nt++) {
            const ushort_t* wr = wf1 + (nt * 16 + lo) * 64 + quad * 8;
            short8 b0 = *(const short8*)wr;
            short8 b1 = *(const short8*)(wr + 32);
            f32x4 acc = {0.f, 0.f, 0.f, 0.f};
            acc = __builtin_amdgcn_mfma_f32_16x16x32_bf16(fa0, b0, acc, 0, 0, 0);
            acc = __builtin_amdgcn_mfma_f32_16x16x32_bf16(fa1, b1, acc, 0, 0, 0);
            float bias = f1b[nt * 16 + lo];
#pragma unroll
            for (int r = 0; r < 4; r++) qkb[quad * 4 + r][nt * 16 + lo] = f2bu(geluf(acc[r] + bias));
        }
        short8 ga[4];
#pragma unroll
        for (int kb = 0; kb < 4; kb++) ga[kb] = *(const short8*)&qkb[lo][kb * 32 + quad * 8];
#pragma unroll
        for (int nt = 0; nt < 4; nt++) {
            const ushort_t* wr = wf2 + (nt * 16 + lo) * 128 + quad * 8;
            f32x4 acc = {0.f, 0.f, 0.f, 0.f};
#pragma unroll
            for (int kb = 0; kb < 4; kb++) {
                short8 bb = *(const short8*)(wr + kb * 32);
                acc = __builtin_amdgcn_mfma_f32_16x16x32_bf16(ga[kb], bb, acc, 0, 0, 0);
            }
            float bias = f2b[nt * 16 + lo];
#pragma unroll
            for (int r = 0; r < 4; r++) htw[quad * 4 + r][nt * 16 + lo] += acc[r] + bias;
        }
    }
    // ---- final LN -> bf16 hmb ----
    {
        float v[16];
        const float4* row = (const float4*)(&htw[lo][quad * 16]);
#pragma unroll
        for (int i = 0; i < 4; i++) {
            float4 a = row[i];
            v[4 * i] = a.x; v[4 * i + 1] = a.y; v[4 * i + 2] = a.z; v[4 * i + 3] = a.w;
        }
        float s = 0.f;
#pragma unroll
        for (int i = 0; i < 16; i++) s += v[i];
        s += __shfl_xor(s, 16); s += __shfl_xor(s, 32);
        float mean = s * (1.0f / 64.0f);
        float q = 0.f;
#pragma unroll
        for (int i = 0; i < 16; i++) { float d = v[i] - mean; q += d * d; }
        q += __shfl_xor(q, 16); q += __shfl_xor(q, 32);
        float rstd = rsqrtf(q * (1.0f / 64.0f) + 1e-5f);
        const float4* gp = (const float4*)(gng + quad * 16);
        const float4* bb4 = (const float4*)(gnb + quad * 16);
        unsigned u[8];
#pragma unroll
        for (int i = 0; i < 4; i++) {
            float4 gg = gp[i], bb = bb4[i];
            float o0 = (v[4 * i] - mean) * rstd * gg.x + bb.x;
            float o1 = (v[4 * i + 1] - mean) * rstd * gg.y + bb.y;
            float o2 = (v[4 * i + 2] - mean) * rstd * gg.z + bb.z;
            float o3 = (v[4 * i + 3] - mean) * rstd * gg.w + bb.w;
            u[2 * i] = pack2bf(o0, o1);
            u[2 * i + 1] = pack2bf(o2, o3);
        }
        ushort_t* dst = hmb + (size_t)(b * 16 + lo) * 16384 + (size_t)tp * 64 + quad * 16;
        ((uint4*)dst)[0] = make_uint4(u[0], u[1], u[2], u[3]);
        ((uint4*)dst)[1] = make_uint4(u[4], u[5], u[6], u[7]);
    }
}

// =============================== K6: GRU (MFMA, W-as-A) ======================
// Operand swap: A=weights (m=d_out), B=h/x (n=seq). C/D = [d_out rows][seq cols]
// so each lane's 4 outputs are 4 consecutive d for one seq -> single
// ds_write_b64 per step (was 4x ds_write_b16) and float4 final store.
__global__ __launch_bounds__(256) void k_gru(
    const ushort_t* __restrict__ hmb, const ushort_t* __restrict__ wgru,
    const float* __restrict__ bih_, const float* __restrict__ bhh_,
    float* __restrict__ h_out)
{
    __shared__ ushort_t hbuf[2][16][72];
    int t = threadIdx.x;
    int w = t >> 6, l = t & 63;
    int lo = l & 15, qd = l >> 4;
    int dir = blockIdx.x >> 5;
    int cseq0 = (blockIdx.x & 31) * 16;
    const ushort_t* wih = wgru + dir * 12288;
    const ushort_t* whh = wgru + 24576 + dir * 12288;
    // A-frag: A[m=lo=d_out][k=qd*8+j] = W[gate*64 + w*16 + lo][qd*8+j]
    const ushort_t* pr0 = wih + ((w) * 16 + lo) * 64 + qd * 8;
    const ushort_t* pz0 = wih + ((4 + w) * 16 + lo) * 64 + qd * 8;
    const ushort_t* pn0 = wih + ((8 + w) * 16 + lo) * 64 + qd * 8;
    const ushort_t* hr0 = whh + ((w) * 16 + lo) * 64 + qd * 8;
    const ushort_t* hz0 = whh + ((4 + w) * 16 + lo) * 64 + qd * 8;
    const ushort_t* hn0 = whh + ((8 + w) * 16 + lo) * 64 + qd * 8;
    short8 wi_r0 = *(const short8*)pr0, wi_r1 = *(const short8*)(pr0 + 32);
    short8 wi_z0 = *(const short8*)pz0, wi_z1 = *(const short8*)(pz0 + 32);
    short8 wi_n0 = *(const short8*)pn0, wi_n1 = *(const short8*)(pn0 + 32);
    short8 wh_r0 = *(const short8*)hr0, wh_r1 = *(const short8*)(hr0 + 32);
    short8 wh_z0 = *(const short8*)hz0, wh_z1 = *(const short8*)(hz0 + 32);
    short8 wh_n0 = *(const short8*)hn0, wh_n1 = *(const short8*)(hn0 + 32);
    int d_base = w * 16 + qd * 4;
    float bsr[4], bsz[4], bin[4], bhn[4];
#pragma unroll
    for (int r = 0; r < 4; r++) {
        bsr[r] = bih_[dir * 192 + d_base + r] + bhh_[dir * 192 + d_base + r];
        bsz[r] = bih_[dir * 192 + 64 + d_base + r] + bhh_[dir * 192 + 64 + d_base + r];
        bin[r] = bih_[dir * 192 + 128 + d_base + r];
        bhn[r] = bhh_[dir * 192 + 128 + d_base + r];
    }
    const ushort_t* xrow = hmb + (size_t)(cseq0 + lo) * 16384 + qd * 8;
    for (int i = t; i < 2 * 16 * 72; i += 256) ((ushort_t*)hbuf)[i] = 0;
    float h_old[4] = {0.f, 0.f, 0.f, 0.f};

    int s0 = dir ? 255 : 0;
    int s1 = dir ? 254 : 1;
    int s2 = dir ? 253 : 2;
    short8 xc0 = *(const short8*)(xrow + s0 * 64);
    short8 xc1 = *(const short8*)(xrow + s0 * 64 + 32);
    short8 xA0 = *(const short8*)(xrow + s1 * 64);
    short8 xA1 = *(const short8*)(xrow + s1 * 64 + 32);
    short8 xB0 = *(const short8*)(xrow + s2 * 64);
    short8 xB1 = *(const short8*)(xrow + s2 * 64 + 32);
    f32x4 axr = {0.f, 0.f, 0.f, 0.f}, axz = {0.f, 0.f, 0.f, 0.f}, axn = {0.f, 0.f, 0.f, 0.f};
    axr = __builtin_amdgcn_mfma_f32_16x16x32_bf16(wi_r0, xc0, axr, 0, 0, 0);
    axr = __builtin_amdgcn_mfma_f32_16x16x32_bf16(wi_r1, xc1, axr, 0, 0, 0);
    axz = __builtin_amdgcn_mfma_f32_16x16x32_bf16(wi_z0, xc0, axz, 0, 0, 0);
    axz = __builtin_amdgcn_mfma_f32_16x16x32_bf16(wi_z1, xc1, axz, 0, 0, 0);
    axn = __builtin_amdgcn_mfma_f32_16x16x32_bf16(wi_n0, xc0, axn, 0, 0, 0);
    axn = __builtin_amdgcn_mfma_f32_16x16x32_bf16(wi_n1, xc1, axn, 0, 0, 0);
    __syncthreads();
#pragma unroll 2
    for (int step = 0; step < 256; step++) {
        int cur = step & 1, nxt = cur ^ 1;
        f32x4 nxr = {0.f, 0.f, 0.f, 0.f}, nxz = {0.f, 0.f, 0.f, 0.f}, nxn = {0.f, 0.f, 0.f, 0.f};
        nxr = __builtin_amdgcn_mfma_f32_16x16x32_bf16(wi_r0, xA0, nxr, 0, 0, 0);
        nxr = __builtin_amdgcn_mfma_f32_16x16x32_bf16(wi_r1, xA1, nxr, 0, 0, 0);
        nxz = __builtin_amdgcn_mfma_f32_16x16x32_bf16(wi_z0, xA0, nxz, 0, 0, 0);
        nxz = __builtin_amdgcn_mfma_f32_16x16x32_bf16(wi_z1, xA1, nxz, 0, 0, 0);
        nxn = __builtin_amdgcn_mfma_f32_16x16x32_bf16(wi_n0, xA0, nxn, 0, 0, 0);
        nxn = __builtin_amdgcn_mfma_f32_16x16x32_bf16(wi_n1, xA1, nxn, 0, 0, 0);
        xA0 = xB0; xA1 = xB1;
        int tl = step + 3 > 255 ? 255 : step + 3;
        int sf = dir ? 255 - tl : tl;
        xB0 = *(const short8*)(xrow + sf * 64);
        xB1 = *(const short8*)(xrow + sf * 64 + 32);
        // B-frag: B[k=qd*8+j][n=lo] = h[seq=lo][d=qd*8+j]
        short8 bh0 = *(const short8*)&hbuf[cur][lo][qd * 8];
        short8 bh1 = *(const short8*)&hbuf[cur][lo][32 + qd * 8];
        f32x4 ar = axr, az = axz;
        f32x4 anh = {0.f, 0.f, 0.f, 0.f};
        ar = __builtin_amdgcn_mfma_f32_16x16x32_bf16(wh_r0, bh0, ar, 0, 0, 0);
        ar = __builtin_amdgcn_mfma_f32_16x16x32_bf16(wh_r1, bh1, ar, 0, 0, 0);
        az = __builtin_amdgcn_mfma_f32_16x16x32_bf16(wh_z0, bh0, az, 0, 0, 0);
        az = __builtin_amdgcn_mfma_f32_16x16x32_bf16(wh_z1, bh1, az, 0, 0, 0);
        anh = __builtin_amdgcn_mfma_f32_16x16x32_bf16(wh_n0, bh0, anh, 0, 0, 0);
        anh = __builtin_amdgcn_mfma_f32_16x16x32_bf16(wh_n1, bh1, anh, 0, 0, 0);
        float hv[4];
#pragma unroll
        for (int r = 0; r < 4; r++) {
            float gr = sigmoidf_(ar[r] + bsr[r]);
            float gz = sigmoidf_(az[r] + bsz[r]);
            float nin = (axn[r] + bin[r]) + gr * (anh[r] + bhn[r]);
            nin = fminf(fmaxf(nin, -15.f), 15.f);
            float e = __expf(-2.f * nin);
            float gn = (1.f - e) / (1.f + e);
            float hn = gn + gz * (h_old[r] - gn);
            h_old[r] = hn;
            hv[r] = hn;
        }
        *(uint2*)&hbuf[nxt][lo][d_base] = make_uint2(pack2bf(hv[0], hv[1]), pack2bf(hv[2], hv[3]));
        asm volatile("s_waitcnt lgkmcnt(0)\n\ts_barrier" ::: "memory");
        axr = nxr; axz = nxz; axn = nxn;
    }
    *(float4*)&h_out[(size_t)(cseq0 + lo) * 128 + dir * 64 + d_base] =
        make_float4(h_old[0], h_old[1], h_old[2], h_old[3]);
}

// =============================== K7: readout =================================
__global__ __launch_bounds__(128) void k_readout(
    const float* __restrict__ h_out, const float* __restrict__ gw, const float* __restrict__ gb,
    void* __restrict__ out, const int* __restrict__ flag)
{
    __shared__ float gate_s[16];
    __shared__ float gws[128];
    int b = blockIdx.x, t = threadIdx.x;
    gws[t] = gw[t];
    __syncthreads();
    int isb = *flag;
    if (t < 16) {
        const float* hr = h_out + (size_t)(b * 16 + t) * 128;
        float acc = gb[0];
        for (int k = 0; k < 128; k++) acc += hr[k] * gws[k];
        float g = sigmoidf_(acc);
        gate_s[t] = g;
        if (isb) ((bf16*)out)[12288 + b * 16 + t] = f2b(g);
        else     ((float*)out)[12288 + b * 16 + t] = g;
    }
    __syncthreads();
    float den = 1e-8f;
#pragma unroll
    for (int c = 0; c < 16; c++) den += gate_s[c];
    float num = 0.f;
#pragma unroll
    for (int c = 0; c < 16; c++) num += h_out[(size_t)(b * 16 + c) * 128 + t] * gate_s[c];
    float v = num / den;
    if (isb) ((bf16*)out)[b * 128 + t] = f2b(v);
    else     ((float*)out)[b * 128 + t] = v;
}

// =============================== launch ======================================
extern "C" void kernel_launch(void* const* d_in, const int* in_sizes, int n_in,
                              void* d_out, int out_size, void* d_ws, size_t ws_size,
                              hipStream_t stream)
{
    int* flag = (int*)d_ws;
    float* cvt = (float*)((char*)d_ws + 256);

    InPtrs P;
    InOffs O;
    int cum = 0;
    for (int i = 0; i < 35; i++) {
        P.p[i] = d_in[i];
        O.off[i] = cum;
        O.sz[i] = in_sizes[i];
        cum += (in_sizes[i] + 7) & ~7;
    }
    int total = cum;

    const float* x     = cvt + O.off[0];
    const float* c1w   = cvt + O.off[1];
    const float* c1b   = cvt + O.off[2];
    const float* bn1g  = cvt + O.off[3];
    const float* bn1b  = cvt + O.off[4];
    const float* bn1m  = cvt + O.off[5];
    const float* bn1v  = cvt + O.off[6];
    const float* c2w   = cvt + O.off[7];
    const float* c2b   = cvt + O.off[8];
    const float* bn2g  = cvt + O.off[9];
    const float* bn2b  = cvt + O.off[10];
    const float* bn2m  = cvt + O.off[11];
    const float* bn2v  = cvt + O.off[12];
    const float* prior = cvt + O.off[13];
    const float* logw  = cvt + O.off[14];
    const float* n1g   = cvt + O.off[15];
    const float* n1b   = cvt + O.off[16];
    const float* qkvw  = cvt + O.off[17];
    const float* qkvb  = cvt + O.off[18];
    const float* outw  = cvt + O.off[19];
    const float* outb  = cvt + O.off[20];
    const float* n2g   = cvt + O.off[21];
    const float* n2b   = cvt + O.off[22];
    const float* f1w   = cvt + O.off[23];
    const float* f1b   = cvt + O.off[24];
    const float* f2w   = cvt + O.off[25];
    const float* f2b_  = cvt + O.off[26];
    const float* gng   = cvt + O.off[27];
    const float* gnb   = cvt + O.off[28];
    const float* gwih  = cvt + O.off[29];
    const float* gwhh  = cvt + O.off[30];
    const float* gbih  = cvt + O.off[31];
    const float* gbhh  = cvt + O.off[32];
    const float* gatew = cvt + O.off[33];
    const float* gateb = cvt + O.off[34];

    float* fbase = cvt + ((total + 63) & ~63);
    float* hm   = fbase;                 // 8388608 floats (CNN out)
    float* Xn   = hm + 8388608;          // 1049088
    float* hnf  = Xn + 1049088;          // 32768
    float* adjw = hnf + 32768;           // 8192
    float* hout = adjw + 8192;           // 65536
    unsigned* wpk = (unsigned*)(hout + 65536);     // 62464 uints (bf16 weights)
    ushort_t* hmb = (ushort_t*)(wpk + 62464);      // 8388608 bf16 (GAT out)

    k_detect<<<1, 256, 0, stream>>>((const unsigned*)d_in[0], flag);
    k_convert<<<(total + 255) / 256, 256, 0, stream>>>(P, O, total, flag, cvt);
    k_pack<<<244, 256, 0, stream>>>(qkvw, outw, f1w, f2w, gwih, gwhh, c2w, wpk);
    k_front<<<1024, 256, 0, stream>>>(x, c1w, c1b, bn1g, bn1b, bn1m, bn1v,
                                      c2b, bn2g, bn2b, bn2m, bn2v,
                                      (const ushort_t*)(wpk + 57344), hm, Xn, hnf);
    k_adj<<<32, 256, 0, stream>>>(Xn, hnf, prior, logw, adjw, d_out, flag);
    k_gat<<<2048, 256, 0, stream>>>(hm, adjw, (const ushort_t*)wpk,
                                    qkvb, outb, f1b, f2b_, n1g, n1b, n2g, n2b, gng, gnb, hmb);
    k_gru<<<64, 256, 0, stream>>>(hmb, (const ushort_t*)(wpk + 32768), gbih, gbhh, hout);
    k_readout<<<32, 128, 0, stream>>>(hout, gatew, gateb, d_out, flag);
}

// Round 9
// 603.115 us; speedup vs baseline: 7.0922x; 1.0817x over previous
//
#include <hip/hip_runtime.h>
#include <hip/hip_bf16.h>
#include <math.h>

typedef __hip_bfloat16 bf16;
typedef unsigned short ushort_t;
typedef __attribute__((ext_vector_type(8))) short short8;
typedef __attribute__((ext_vector_type(4))) float f32x4;

__device__ __forceinline__ float b2f(bf16 v) { return __bfloat162float(v); }
__device__ __forceinline__ bf16 f2b(float v) { return __float2bfloat16(v); }
__device__ __forceinline__ float sigmoidf_(float x) { return 1.0f / (1.0f + __expf(-x)); }

// fast exact-gelu: erf via Abramowitz-Stegun 7.1.26 (|err| <= 1.5e-7)
__device__ __forceinline__ float geluf(float x) {
    float z = x * 0.70710678118654752f;
    float az = fabsf(z);
    float t = 1.0f / (1.0f + 0.3275911f * az);
    float poly = ((((1.061405429f * t - 1.453152027f) * t + 1.421413741f) * t
                   - 0.284496736f) * t + 0.254829592f) * t;
    float erfa = 1.0f - poly * __expf(-z * z);
    float er = (z < 0.f) ? -erfa : erfa;
    return 0.5f * x * (1.0f + er);
}

__device__ __forceinline__ unsigned pack2bf(float a, float b) {
    unsigned ua = __float_as_uint(a); ua = (ua + 0x7FFFu + ((ua >> 16) & 1u)) >> 16;
    unsigned ub = __float_as_uint(b); ub = (ub + 0x7FFFu + ((ub >> 16) & 1u)) >> 16;
    return ua | (ub << 16);
}
__device__ __forceinline__ ushort_t f2bu(float v) {
    unsigned u = __float_as_uint(v);
    u = (u + 0x7FFFu + ((u >> 16) & 1u)) >> 16;
    return (ushort_t)u;
}

// ========================== K0a: dtype detector ==============================
__global__ __launch_bounds__(256) void k_detect(const unsigned* __restrict__ x, int* __restrict__ flag)
{
    __shared__ int cnt;
    if (threadIdx.x == 0) cnt = 0;
    __syncthreads();
    unsigned u = x[threadIdx.x] & 0xFFFFu;
    float f = __uint_as_float(u << 16);
    float a = fabsf(f);
    int sane = (f == 0.0f) || (a > 1e-8f && a < 1e4f);
    atomicAdd(&cnt, sane);
    __syncthreads();
    if (threadIdx.x == 0) *flag = (cnt >= 160) ? 1 : 0;
}

// ========================== K0b: canonicalize to fp32 ========================
struct InPtrs { const void* p[35]; };
struct InOffs { int off[35]; int sz[35]; };

__global__ __launch_bounds__(256) void k_convert(InPtrs P, InOffs O, int total,
                                                 const int* __restrict__ flag,
                                                 float* __restrict__ cvt)
{
    int idx = blockIdx.x * 256 + threadIdx.x;
    if (idx >= total) return;
    int isb = *flag;
    float v = 0.f;
#pragma unroll 1
    for (int s = 0; s < 35; s++) {
        int rel = idx - O.off[s];
        if (rel >= 0 && rel < O.sz[s]) {
            v = isb ? b2f(((const bf16*)P.p[s])[rel]) : ((const float*)P.p[s])[rel];
            break;
        }
    }
    cvt[idx] = v;
}

// ========================== K0c: pack weights to bf16 ========================
// uint regions: qw 12288 | ow 4096 | f1w 8192 | f2w 8192 | gwih 12288 | gwhh 12288
//             | conv2 wt [tap][d][ic] 5120
__global__ __launch_bounds__(256) void k_pack(const float* __restrict__ qw, const float* __restrict__ ow,
                                              const float* __restrict__ f1w, const float* __restrict__ f2w,
                                              const float* __restrict__ gwih, const float* __restrict__ gwhh,
                                              const float* __restrict__ c2w,
                                              unsigned* __restrict__ dst)
{
    int i = blockIdx.x * 256 + threadIdx.x;
    if (i >= 62464) return;
    if (i >= 57344) {
        int j0 = (i - 57344) * 2;
        int tap = j0 >> 11, rem = j0 & 2047;
        int d = rem >> 5, ic = rem & 31;
        dst[i] = pack2bf(c2w[d * 160 + ic * 5 + tap], c2w[d * 160 + (ic + 1) * 5 + tap]);
        return;
    }
    const float* s; int rel;
    if (i < 12288)      { s = qw;   rel = i; }
    else if (i < 16384) { s = ow;   rel = i - 12288; }
    else if (i < 24576) { s = f1w;  rel = i - 16384; }
    else if (i < 32768) { s = f2w;  rel = i - 24576; }
    else if (i < 45056) { s = gwih; rel = i - 32768; }
    else                { s = gwhh; rel = i - 45056; }
    dst[i] = pack2bf(s[2 * rel], s[2 * rel + 1]);
}

// ====================== K1: fused front (CNN+havg | pair-FFT) ================
// blocks 0..511: CNN (conv1 VALU + conv2 tap-GEMM MFMA) + h_avg/hn epilogue.
// blocks 512..767: TWO real rows per complex 4096-pt FFT (z = a + i b),
//   spectra separated via A=(Z[k]+Z*[N-k])/2, B=-i(Z[k]-Z*[N-k])/2.
//   Normalized magnitudes written as bf16, row stride 2080 (65 K-blocks of 32).
__global__ __launch_bounds__(256) void k_front(
    const float* __restrict__ x,
    const float* __restrict__ c1w, const float* __restrict__ c1b,
    const float* __restrict__ bn1g, const float* __restrict__ bn1b, const float* __restrict__ bn1m, const float* __restrict__ bn1v,
    const float* __restrict__ c2b,
    const float* __restrict__ bn2g, const float* __restrict__ bn2b, const float* __restrict__ bn2m, const float* __restrict__ bn2v,
    const ushort_t* __restrict__ w2pk,
    float* __restrict__ h_main, ushort_t* __restrict__ Xnb, float* __restrict__ hnf)
{
    __shared__ float smem[9984];
    int t = threadIdx.x;
    if (blockIdx.x >= 512) {
        // ---------------- pair-FFT path ----------------
        float* re = smem;
        float* im = smem + 4096;
        float* red = smem + 8192;
        int bc2 = blockIdx.x - 512;            // 0..255
        int b = bc2 >> 3, cp = bc2 & 7;
        const float* xa = x + ((size_t)b * 16 + 2 * cp) * 4096;
        const float* xb = xa + 4096;
        for (int i = t; i < 4096; i += 256) {
            int r = __brev((unsigned)i) >> 20;
            re[r] = xa[i];
            im[r] = xb[i];
        }
        __syncthreads();
        for (int s = 1; s <= 12; s++) {
            int half = 1 << (s - 1);
            float ang = -6.283185307179586f / (float)(1 << s);
            for (int m = t; m < 2048; m += 256) {
                int j = m & (half - 1);
                int pos = ((m >> (s - 1)) << s) | j;
                float sn, cs;
                __sincosf(ang * (float)j, &sn, &cs);
                float ur = re[pos], ui = im[pos];
                float vr = re[pos + half], vi = im[pos + half];
                float tr = vr * cs - vi * sn;
                float ti = vr * sn + vi * cs;
                re[pos] = ur + tr; im[pos] = ui + ti;
                re[pos + half] = ur - tr; im[pos + half] = ui - ti;
            }
            __syncthreads();
        }
        float maga[9], magb[9];
        float ssa = 0.f, ssb = 0.f;
#pragma unroll
        for (int it = 0; it < 9; it++) {
            int k = t + it * 256;
            float ma = 0.f, mb = 0.f;
            if (k <= 2048) {
                int kn = (4096 - k) & 4095;
                float Rk = re[k], Ik = im[k], Rn = re[kn], In = im[kn];
                float ra = 0.5f * (Rk + Rn), ia = 0.5f * (Ik - In);
                float rb = 0.5f * (Ik + In), ib = 0.5f * (Rn - Rk);
                ma = sqrtf(ra * ra + ia * ia);
                mb = sqrtf(rb * rb + ib * ib);
                ssa += ma * ma; ssb += mb * mb;
            }
            maga[it] = ma; magb[it] = mb;
        }
        for (int off = 32; off; off >>= 1) { ssa += __shfl_xor(ssa, off, 64); ssb += __shfl_xor(ssb, off, 64); }
        int w = t >> 6;
        if ((t & 63) == 0) { red[w] = ssa; red[4 + w] = ssb; }
        __syncthreads();
        float inva = 1.0f / (sqrtf(red[0] + red[1] + red[2] + red[3]) + 1e-8f);
        float invb = 1.0f / (sqrtf(red[4] + red[5] + red[6] + red[7]) + 1e-8f);
        ushort_t* rowa = Xnb + ((size_t)b * 16 + 2 * cp) * 2080;
        ushort_t* rowb = rowa + 2080;
#pragma unroll
        for (int it = 0; it < 9; it++) {
            int k = t + it * 256;
            if (k <= 2048) {
                rowa[k] = f2bu(maga[it] * inva);
                rowb[k] = f2bu(magb[it] * invb);
            }
        }
        for (int f = 2049 + t; f < 2080; f += 256) { rowa[f] = 0; rowb[f] = 0; }
        return;
    }
    // ---------------- CNN path ----------------
    float* ubuf = smem;                           // 4352 floats
    ushort_t* h1t = (ushort_t*)(smem + 4352);     // 10400 ushorts (260 rows x 40)
    float* A2s = smem + 9552;
    float* B2s = smem + 9616;
    float* hsum = smem + 9680;                    // 256
    int bc = blockIdx.x;
    int l = t & 63, w = t >> 6;
    int lo = l & 15, quad = l >> 4;

    if (t < 64) {
        float s = bn2g[t] * rsqrtf(bn2v[t] + 1e-5f);
        A2s[t] = s; B2s[t] = (c2b[t] - bn2m[t]) * s + bn2b[t];
    }
    int icp = t & 15;
    float w1r[2][7], A1r[2], B1r[2];
#pragma unroll
    for (int s = 0; s < 2; s++) {
        int ic = icp * 2 + s;
#pragma unroll
        for (int k = 0; k < 7; k++) w1r[s][k] = c1w[ic * 7 + k];
        float sc = bn1g[ic] * rsqrtf(bn1v[ic] + 1e-5f);
        A1r[s] = sc; B1r[s] = (c1b[ic] - bn1m[ic]) * sc + bn1b[ic];
    }
    short8 Afr[4][5];
#pragma unroll
    for (int dt = 0; dt < 4; dt++)
#pragma unroll
        for (int tap = 0; tap < 5; tap++)
            Afr[dt][tap] = *(const short8*)(w2pk + ((tap * 64 + dt * 16 + lo) * 32 + quad * 8));

    const float* xrow = x + (size_t)bc * 4096;
    float rs = 0.f;
    int dd = t & 63, pg = t >> 6;
    for (int tile = 0; tile < 4; tile++) {
        int X0 = 1024 * tile - 11;
        for (int i = t; i < 1056; i += 256) {
            int g = X0 + i;
            ubuf[i] = (g >= 0 && g < 4096) ? xrow[g] : 0.0f;
        }
        __syncthreads();
        for (int pos = (t >> 4); pos < 260; pos += 16) {
            const float4* xw = (const float4*)&ubuf[4 * pos];
            float4 fa = xw[0], fb = xw[1], fc = xw[2];
            float xv[12] = {fa.x, fa.y, fa.z, fa.w, fb.x, fb.y, fb.z, fb.w,
                            fc.x, fc.y, fc.z, fc.w};
            int t1pg = tile * 256 + pos - 2;
            bool ok = (t1pg >= 0 && t1pg < 1024);
            float res[2];
#pragma unroll
            for (int s = 0; s < 2; s++) {
                float a0 = 0.f, a1 = 0.f, a2 = 0.f, a3 = 0.f;
#pragma unroll
                for (int k = 0; k < 7; k++) {
                    float wv = w1r[s][k];
                    a0 += xv[k] * wv;     a1 += xv[k + 1] * wv;
                    a2 += xv[k + 2] * wv; a3 += xv[k + 3] * wv;
                }
                float A = A1r[s], B = B1r[s];
                a0 = a0 * A + B; a1 = a1 * A + B; a2 = a2 * A + B; a3 = a3 * A + B;
                float mx = fmaxf(fmaxf(a0, a1), fmaxf(a2, a3));
                float mn = fminf(fminf(a0, a1), fminf(a2, a3));
                res[s] = ok ? fmaxf(geluf(mx), geluf(mn)) : 0.0f;
            }
            ((unsigned*)h1t)[pos * 20 + icp] = pack2bf(res[0], res[1]);
        }
        __syncthreads();
        float* houtile = ubuf;
#pragma unroll
        for (int ni = 0; ni < 4; ni++) {
            int nt = w * 4 + ni;
            short8 bfr[5];
#pragma unroll
            for (int tap = 0; tap < 5; tap++)
                bfr[tap] = *(const short8*)&h1t[(nt * 16 + lo + tap) * 40 + quad * 8];
#pragma unroll
            for (int dt = 0; dt < 4; dt++) {
                f32x4 acc = {0.f, 0.f, 0.f, 0.f};
#pragma unroll
                for (int tap = 0; tap < 5; tap++)
                    acc = __builtin_amdgcn_mfma_f32_16x16x32_bf16(Afr[dt][tap], bfr[tap], acc, 0, 0, 0);
                const float4 a2 = *(const float4*)&A2s[dt * 16 + quad * 4];
                const float4 b2 = *(const float4*)&B2s[dt * 16 + quad * 4];
                float a2a[4] = {a2.x, a2.y, a2.z, a2.w};
                float b2a[4] = {b2.x, b2.y, b2.z, b2.w};
#pragma unroll
                for (int r = 0; r < 4; r++) {
                    float v = acc[r] * a2a[r] + b2a[r];
                    float o1 = __shfl_xor(v, 1);
                    float mx = fmaxf(v, o1), mn = fminf(v, o1);
                    float mx2 = __shfl_xor(mx, 2), mn2 = __shfl_xor(mn, 2);
                    mx = fmaxf(mx, mx2); mn = fminf(mn, mn2);
                    float res = fmaxf(geluf(mx), geluf(mn));
                    if ((lo & 3) == 0)
                        houtile[(nt * 4 + (lo >> 2)) * 68 + dt * 16 + quad * 4 + r] = res;
                }
            }
        }
        __syncthreads();
#pragma unroll
        for (int i = 0; i < 16; i++) rs += ubuf[(pg * 16 + i) * 68 + dd];
        float* dst = h_main + (size_t)bc * 16384 + tile * 4096;
        for (int i = t * 4; i < 4096; i += 1024) {
            float4 v = *(const float4*)&ubuf[(i >> 6) * 68 + (i & 63)];
            *(float4*)&dst[i] = v;
        }
        __syncthreads();
    }
    hsum[t] = rs;
    __syncthreads();
    if (t < 64) {
        float avg = (hsum[t] + hsum[64 + t] + hsum[128 + t] + hsum[192 + t]) * (1.0f / 256.0f);
        float tot = avg;
        for (int off = 32; off; off >>= 1) tot += __shfl_xor(tot, off, 64);
        float hc = avg - tot * (1.0f / 64.0f);
        float sq = hc * hc;
        for (int off = 32; off; off >>= 1) sq += __shfl_xor(sq, off, 64);
        hnf[bc * 64 + t] = hc / (sqrtf(sq) + 1e-8f);
    }
}

// =============================== K4: adjacency (MFMA) ========================
// spec_coh = Xn @ Xn^T via 65 K-blocks of mfma 16x16x32 (A-frag == B-frag,
// one 16B load per lane per K-block). 4 waves split K; LDS-reduce partials.
__global__ __launch_bounds__(256) void k_adj(
    const ushort_t* __restrict__ Xnb, const float* __restrict__ hnf,
    const float* __restrict__ prior, const float* __restrict__ logw,
    float* __restrict__ adjw, void* __restrict__ out, const int* __restrict__ flag)
{
    __shared__ float tile[4][16][17];
    __shared__ float hh[1024];
    int b = blockIdx.x, t = threadIdx.x;
    int w = t >> 6, l = t & 63;
    int lo = l & 15, quad = l >> 4;
    for (int i = t; i < 1024; i += 256) hh[i] = hnf[b * 1024 + i];
    const ushort_t* base = Xnb + (size_t)b * 16 * 2080 + lo * 2080 + quad * 8;
    f32x4 acc = {0.f, 0.f, 0.f, 0.f};
    for (int kb = w; kb < 65; kb += 4) {
        short8 f = *(const short8*)(base + kb * 32);
        acc = __builtin_amdgcn_mfma_f32_16x16x32_bf16(f, f, acc, 0, 0, 0);
    }
#pragma unroll
    for (int r = 0; r < 4; r++) tile[w][quad * 4 + r][lo] = acc[r];
    __syncthreads();
    int c = t >> 4, e = t & 15;
    float sc = tile[0][c][e] + tile[1][c][e] + tile[2][c][e] + tile[3][c][e];
    float fc = 0.f;
#pragma unroll
    for (int d = 0; d < 64; d++) fc += hh[c * 64 + d] * hh[e * 64 + d];
    float l0 = logw[0], l1 = logw[1], l2 = logw[2];
    float mx = fmaxf(l0, fmaxf(l1, l2));
    float e0 = __expf(l0 - mx), e1 = __expf(l1 - mx), e2 = __expf(l2 - mx);
    float isum = 1.0f / (e0 + e1 + e2);
    float pr = prior[c * 16 + e] + prior[e * 16 + c];
    float v = (e0 * fc + e1 * sc + e2 * pr) * isum;
    adjw[b * 256 + t] = v;
    if (*flag) ((bf16*)out)[4096 + b * 256 + t] = f2b(v);
    else       ((float*)out)[4096 + b * 256 + t] = v;
}

// =============================== K5: GAT stack (MFMA) ========================
__device__ __forceinline__ void ln_wave(const float (*ht)[68], ushort_t (*out)[72],
                                        const float* __restrict__ g, const float* __restrict__ bp,
                                        int quad, int lo)
{
    float v[16];
    const float4* row = (const float4*)(&ht[lo][quad * 16]);
#pragma unroll
    for (int i = 0; i < 4; i++) {
        float4 a = row[i];
        v[4 * i] = a.x; v[4 * i + 1] = a.y; v[4 * i + 2] = a.z; v[4 * i + 3] = a.w;
    }
    float s = 0.f;
#pragma unroll
    for (int i = 0; i < 16; i++) s += v[i];
    s += __shfl_xor(s, 16); s += __shfl_xor(s, 32);
    float mean = s * (1.0f / 64.0f);
    float q = 0.f;
#pragma unroll
    for (int i = 0; i < 16; i++) { float d = v[i] - mean; q += d * d; }
    q += __shfl_xor(q, 16); q += __shfl_xor(q, 32);
    float rstd = rsqrtf(q * (1.0f / 64.0f) + 1e-5f);
    const float4* gp = (const float4*)(g + quad * 16);
    const float4* bb4 = (const float4*)(bp + quad * 16);
    unsigned* orow = (unsigned*)(&out[lo][quad * 16]);
#pragma unroll
    for (int i = 0; i < 4; i++) {
        float4 gg = gp[i], bb = bb4[i];
        float o0 = (v[4 * i] - mean) * rstd * gg.x + bb.x;
        float o1 = (v[4 * i + 1] - mean) * rstd * gg.y + bb.y;
        float o2 = (v[4 * i + 2] - mean) * rstd * gg.z + bb.z;
        float o3 = (v[4 * i + 3] - mean) * rstd * gg.w + bb.w;
        orow[2 * i] = pack2bf(o0, o1);
        orow[2 * i + 1] = pack2bf(o2, o3);
    }
}

__global__ __launch_bounds__(256) void k_gat(
    const float* __restrict__ hm, const float* __restrict__ adjw,
    const ushort_t* __restrict__ wpk,
    const float* __restrict__ qb_, const float* __restrict__ ob_,
    const float* __restrict__ f1b_, const float* __restrict__ f2b_,
    const float* __restrict__ n1g_, const float* __restrict__ n1b_,
    const float* __restrict__ n2g_, const float* __restrict__ n2b_,
    const float* __restrict__ gng, const float* __restrict__ gnb,
    ushort_t* __restrict__ hmb)
{
    __shared__ float htw_all[4][16][68];
    __shared__ ushort_t hnw_all[4][16][72];
    __shared__ ushort_t qkb_all[4][16][200];
    __shared__ ushort_t pb_all[4][16][72];
    __shared__ ushort_t vt_all[4][64][24];
    int t = threadIdx.x;
    int w = t >> 6, l = t & 63;
    int quad = l >> 4, lo = l & 15;
    int n = blockIdx.x * 4 + w;
    int b = n >> 8, tp = n & 255;
    float (*htw)[68] = htw_all[w];
    ushort_t (*hnw)[72] = hnw_all[w];
    ushort_t (*qkb)[200] = qkb_all[w];
    ushort_t (*pb)[72] = pb_all[w];
    ushort_t (*vt)[24] = vt_all[w];
    const float* src = hm + (size_t)b * 16 * 16384 + (size_t)tp * 64;
#pragma unroll
    for (int c = 0; c < 16; c++) htw[c][l] = src[(size_t)c * 16384 + l];
    float adjr[4];
#pragma unroll
    for (int r = 0; r < 4; r++) adjr[r] = adjw[b * 256 + (quad * 4 + r) * 16 + lo];

    for (int layer = 0; layer < 2; layer++) {
        const ushort_t* wq  = wpk + layer * 12288;
        const ushort_t* wo  = wpk + 24576 + layer * 4096;
        const ushort_t* wf1 = wpk + 32768 + layer * 8192;
        const ushort_t* wf2 = wpk + 49152 + layer * 8192;
        const float* qb = qb_ + layer * 192;
        const float* ob = ob_ + layer * 64;
        const float* f1b = f1b_ + layer * 128;
        const float* f2b = f2b_ + layer * 64;

        ln_wave(htw, hnw, n1g_ + layer * 64, n1b_ + layer * 64, quad, lo);

        short8 a0 = *(const short8*)&hnw[lo][quad * 8];
        short8 a1 = *(const short8*)&hnw[lo][32 + quad * 8];
#pragma unroll
        for (int nt = 0; nt < 12; nt++) {
            const ushort_t* wr = wq + (nt * 16 + lo) * 64 + quad * 8;
            short8 b0 = *(const short8*)wr;
            short8 b1 = *(const short8*)(wr + 32);
            f32x4 acc = {0.f, 0.f, 0.f, 0.f};
            acc = __builtin_amdgcn_mfma_f32_16x16x32_bf16(a0, b0, acc, 0, 0, 0);
            acc = __builtin_amdgcn_mfma_f32_16x16x32_bf16(a1, b1, acc, 0, 0, 0);
            float bias = qb[nt * 16 + lo];
            if (nt < 8) {
#pragma unroll
                for (int r = 0; r < 4; r++) qkb[quad * 4 + r][nt * 16 + lo] = f2bu(acc[r] + bias);
            } else {
#pragma unroll
                for (int r = 0; r < 4; r++) vt[(nt - 8) * 16 + lo][quad * 4 + r] = f2bu(acc[r] + bias);
            }
        }

        short8 zf = {0, 0, 0, 0, 0, 0, 0, 0};
#pragma unroll
        for (int h = 0; h < 4; h++) {
            short8 qf = zf, kf = zf;
            if (quad < 2) {
                qf = *(const short8*)&qkb[lo][h * 16 + quad * 8];
                kf = *(const short8*)&qkb[lo][64 + h * 16 + quad * 8];
            }
            f32x4 s4 = {0.f, 0.f, 0.f, 0.f};
            s4 = __builtin_amdgcn_mfma_f32_16x16x32_bf16(qf, kf, s4, 0, 0, 0);
#pragma unroll
            for (int r = 0; r < 4; r++) {
                float sv = s4[r] * 0.25f + adjr[r];
                float mx = sv;
                mx = fmaxf(mx, __shfl_xor(mx, 1));
                mx = fmaxf(mx, __shfl_xor(mx, 2));
                mx = fmaxf(mx, __shfl_xor(mx, 4));
                mx = fmaxf(mx, __shfl_xor(mx, 8));
                float e = __expf(sv - mx);
                float sm = e;
                sm += __shfl_xor(sm, 1);
                sm += __shfl_xor(sm, 2);
                sm += __shfl_xor(sm, 4);
                sm += __shfl_xor(sm, 8);
                pb[quad * 4 + r][h * 16 + lo] = f2bu(e / sm);
            }
        }
#pragma unroll
        for (int h = 0; h < 4; h++) {
            short8 pf = zf, vf = zf;
            if (quad < 2) {
                pf = *(const short8*)&pb[lo][h * 16 + quad * 8];
                vf = *(const short8*)&vt[h * 16 + lo][quad * 8];
            }
            f32x4 oc = {0.f, 0.f, 0.f, 0.f};
            oc = __builtin_amdgcn_mfma_f32_16x16x32_bf16(pf, vf, oc, 0, 0, 0);
#pragma unroll
            for (int r = 0; r < 4; r++) qkb[quad * 4 + r][h * 16 + lo] = f2bu(oc[r]);
        }
        short8 pa0 = *(const short8*)&qkb[lo][quad * 8];
        short8 pa1 = *(const short8*)&qkb[lo][32 + quad * 8];
#pragma unroll
        for (int nt = 0; nt < 4; nt++) {
            const ushort_t* wr = wo + (nt * 16 + lo) * 64 + quad * 8;
            short8 b0 = *(const short8*)wr;
            short8 b1 = *(const short8*)(wr + 32);
            f32x4 acc = {0.f, 0.f, 0.f, 0.f};
            acc = __builtin_amdgcn_mfma_f32_16x16x32_bf16(pa0, b0, acc, 0, 0, 0);
            acc = __builtin_amdgcn_mfma_f32_16x16x32_bf16(pa1, b1, acc, 0, 0, 0);
            float bias = ob[nt * 16 + lo];
#pragma unroll
            for (int r = 0; r < 4; r++) htw[quad * 4 + r][nt * 16 + lo] += acc[r] + bias;
        }
        ln_wave(htw, hnw, n2g_ + layer * 64, n2b_ + layer * 64, quad, lo);
        short8 fa0 = *(const short8*)&hnw[lo][quad * 8];
        short8 fa1 = *(const short8*)&hnw[lo][32 + quad * 8];
#pragma unroll
        for (int nt = 0; nt < 8; nt++) {
            const ushort_t* wr = wf1 + (nt * 16 + lo) * 64 + quad * 8;
            short8 b0 = *(const short8*)wr;
            short8 b1 = *(const short8*)(wr + 32);
            f32x4 acc = {0.f, 0.f, 0.f, 0.f};
            acc = __builtin_amdgcn_mfma_f32_16x16x32_bf16(fa0, b0, acc, 0, 0, 0);
            acc = __builtin_amdgcn_mfma_f32_16x16x32_bf16(fa1, b1, acc, 0, 0, 0);
            float bias = f1b[nt * 16 + lo];
#pragma unroll
            for (int r = 0; r < 4; r++) qkb[quad * 4 + r][nt * 16 + lo] = f2bu(geluf(acc[r] + bias));
        }
        short8 ga[4];
#pragma unroll
        for (int kb = 0; kb < 4; kb++) ga[kb] = *(const short8*)&qkb[lo][kb * 32 + quad * 8];
#pragma unroll
        for (int nt = 0; nt < 4; nt++) {
            const ushort_t* wr = wf2 + (nt * 16 + lo) * 128 + quad * 8;
            f32x4 acc = {0.f, 0.f, 0.f, 0.f};
#pragma unroll
            for (int kb = 0; kb < 4; kb++) {
                short8 bb = *(const short8*)(wr + kb * 32);
                acc = __builtin_amdgcn_mfma_f32_16x16x32_bf16(ga[kb], bb, acc, 0, 0, 0);
            }
            float bias = f2b[nt * 16 + lo];
#pragma unroll
            for (int r = 0; r < 4; r++) htw[quad * 4 + r][nt * 16 + lo] += acc[r] + bias;
        }
    }
    // ---- final LN -> bf16 hmb ----
    {
        float v[16];
        const float4* row = (const float4*)(&htw[lo][quad * 16]);
#pragma unroll
        for (int i = 0; i < 4; i++) {
            float4 a = row[i];
            v[4 * i] = a.x; v[4 * i + 1] = a.y; v[4 * i + 2] = a.z; v[4 * i + 3] = a.w;
        }
        float s = 0.f;
#pragma unroll
        for (int i = 0; i < 16; i++) s += v[i];
        s += __shfl_xor(s, 16); s += __shfl_xor(s, 32);
        float mean = s * (1.0f / 64.0f);
        float q = 0.f;
#pragma unroll
        for (int i = 0; i < 16; i++) { float d = v[i] - mean; q += d * d; }
        q += __shfl_xor(q, 16); q += __shfl_xor(q, 32);
        float rstd = rsqrtf(q * (1.0f / 64.0f) + 1e-5f);
        const float4* gp = (const float4*)(gng + quad * 16);
        const float4* bb4 = (const float4*)(gnb + quad * 16);
        unsigned u[8];
#pragma unroll
        for (int i = 0; i < 4; i++) {
            float4 gg = gp[i], bb = bb4[i];
            float o0 = (v[4 * i] - mean) * rstd * gg.x + bb.x;
            float o1 = (v[4 * i + 1] - mean) * rstd * gg.y + bb.y;
            float o2 = (v[4 * i + 2] - mean) * rstd * gg.z + bb.z;
            float o3 = (v[4 * i + 3] - mean) * rstd * gg.w + bb.w;
            u[2 * i] = pack2bf(o0, o1);
            u[2 * i + 1] = pack2bf(o2, o3);
        }
        ushort_t* dst = hmb + (size_t)(b * 16 + lo) * 16384 + (size_t)tp * 64 + quad * 16;
        ((uint4*)dst)[0] = make_uint4(u[0], u[1], u[2], u[3]);
        ((uint4*)dst)[1] = make_uint4(u[4], u[5], u[6], u[7]);
    }
}

// =============================== K6: GRU (MFMA, W-as-A) ======================
__global__ __launch_bounds__(256) void k_gru(
    const ushort_t* __restrict__ hmb, const ushort_t* __restrict__ wgru,
    const float* __restrict__ bih_, const float* __restrict__ bhh_,
    float* __restrict__ h_out)
{
    __shared__ ushort_t hbuf[2][16][72];
    int t = threadIdx.x;
    int w = t >> 6, l = t & 63;
    int lo = l & 15, qd = l >> 4;
    int dir = blockIdx.x >> 5;
    int cseq0 = (blockIdx.x & 31) * 16;
    const ushort_t* wih = wgru + dir * 12288;
    const ushort_t* whh = wgru + 24576 + dir * 12288;
    const ushort_t* pr0 = wih + ((w) * 16 + lo) * 64 + qd * 8;
    const ushort_t* pz0 = wih + ((4 + w) * 16 + lo) * 64 + qd * 8;
    const ushort_t* pn0 = wih + ((8 + w) * 16 + lo) * 64 + qd * 8;
    const ushort_t* hr0 = whh + ((w) * 16 + lo) * 64 + qd * 8;
    const ushort_t* hz0 = whh + ((4 + w) * 16 + lo) * 64 + qd * 8;
    const ushort_t* hn0 = whh + ((8 + w) * 16 + lo) * 64 + qd * 8;
    short8 wi_r0 = *(const short8*)pr0, wi_r1 = *(const short8*)(pr0 + 32);
    short8 wi_z0 = *(const short8*)pz0, wi_z1 = *(const short8*)(pz0 + 32);
    short8 wi_n0 = *(const short8*)pn0, wi_n1 = *(const short8*)(pn0 + 32);
    short8 wh_r0 = *(const short8*)hr0, wh_r1 = *(const short8*)(hr0 + 32);
    short8 wh_z0 = *(const short8*)hz0, wh_z1 = *(const short8*)(hz0 + 32);
    short8 wh_n0 = *(const short8*)hn0, wh_n1 = *(const short8*)(hn0 + 32);
    int d_base = w * 16 + qd * 4;
    float bsr[4], bsz[4], bin[4], bhn[4];
#pragma unroll
    for (int r = 0; r < 4; r++) {
        bsr[r] = bih_[dir * 192 + d_base + r] + bhh_[dir * 192 + d_base + r];
        bsz[r] = bih_[dir * 192 + 64 + d_base + r] + bhh_[dir * 192 + 64 + d_base + r];
        bin[r] = bih_[dir * 192 + 128 + d_base + r];
        bhn[r] = bhh_[dir * 192 + 128 + d_base + r];
    }
    const ushort_t* xrow = hmb + (size_t)(cseq0 + lo) * 16384 + qd * 8;
    for (int i = t; i < 2 * 16 * 72; i += 256) ((ushort_t*)hbuf)[i] = 0;
    float h_old[4] = {0.f, 0.f, 0.f, 0.f};

    int s0 = dir ? 255 : 0;
    int s1 = dir ? 254 : 1;
    int s2 = dir ? 253 : 2;
    short8 xc0 = *(const short8*)(xrow + s0 * 64);
    short8 xc1 = *(const short8*)(xrow + s0 * 64 + 32);
    short8 xA0 = *(const short8*)(xrow + s1 * 64);
    short8 xA1 = *(const short8*)(xrow + s1 * 64 + 32);
    short8 xB0 = *(const short8*)(xrow + s2 * 64);
    short8 xB1 = *(const short8*)(xrow + s2 * 64 + 32);
    f32x4 axr = {0.f, 0.f, 0.f, 0.f}, axz = {0.f, 0.f, 0.f, 0.f}, axn = {0.f, 0.f, 0.f, 0.f};
    axr = __builtin_amdgcn_mfma_f32_16x16x32_bf16(wi_r0, xc0, axr, 0, 0, 0);
    axr = __builtin_amdgcn_mfma_f32_16x16x32_bf16(wi_r1, xc1, axr, 0, 0, 0);
    axz = __builtin_amdgcn_mfma_f32_16x16x32_bf16(wi_z0, xc0, axz, 0, 0, 0);
    axz = __builtin_amdgcn_mfma_f32_16x16x32_bf16(wi_z1, xc1, axz, 0, 0, 0);
    axn = __builtin_amdgcn_mfma_f32_16x16x32_bf16(wi_n0, xc0, axn, 0, 0, 0);
    axn = __builtin_amdgcn_mfma_f32_16x16x32_bf16(wi_n1, xc1, axn, 0, 0, 0);
    __syncthreads();
#pragma unroll 2
    for (int step = 0; step < 256; step++) {
        int cur = step & 1, nxt = cur ^ 1;
        f32x4 nxr = {0.f, 0.f, 0.f, 0.f}, nxz = {0.f, 0.f, 0.f, 0.f}, nxn = {0.f, 0.f, 0.f, 0.f};
        nxr = __builtin_amdgcn_mfma_f32_16x16x32_bf16(wi_r0, xA0, nxr, 0, 0, 0);
        nxr = __builtin_amdgcn_mfma_f32_16x16x32_bf16(wi_r1, xA1, nxr, 0, 0, 0);
        nxz = __builtin_amdgcn_mfma_f32_16x16x32_bf16(wi_z0, xA0, nxz, 0, 0, 0);
        nxz = __builtin_amdgcn_mfma_f32_16x16x32_bf16(wi_z1, xA1, nxz, 0, 0, 0);
        nxn = __builtin_amdgcn_mfma_f32_16x16x32_bf16(wi_n0, xA0, nxn, 0, 0, 0);
        nxn = __builtin_amdgcn_mfma_f32_16x16x32_bf16(wi_n1, xA1, nxn, 0, 0, 0);
        xA0 = xB0; xA1 = xB1;
        int tl = step + 3 > 255 ? 255 : step + 3;
        int sf = dir ? 255 - tl : tl;
        xB0 = *(const short8*)(xrow + sf * 64);
        xB1 = *(const short8*)(xrow + sf * 64 + 32);
        short8 bh0 = *(const short8*)&hbuf[cur][lo][qd * 8];
        short8 bh1 = *(const short8*)&hbuf[cur][lo][32 + qd * 8];
        f32x4 ar = axr, az = axz;
        f32x4 anh = {0.f, 0.f, 0.f, 0.f};
        ar = __builtin_amdgcn_mfma_f32_16x16x32_bf16(wh_r0, bh0, ar, 0, 0, 0);
        ar = __builtin_amdgcn_mfma_f32_16x16x32_bf16(wh_r1, bh1, ar, 0, 0, 0);
        az = __builtin_amdgcn_mfma_f32_16x16x32_bf16(wh_z0, bh0, az, 0, 0, 0);
        az = __builtin_amdgcn_mfma_f32_16x16x32_bf16(wh_z1, bh1, az, 0, 0, 0);
        anh = __builtin_amdgcn_mfma_f32_16x16x32_bf16(wh_n0, bh0, anh, 0, 0, 0);
        anh = __builtin_amdgcn_mfma_f32_16x16x32_bf16(wh_n1, bh1, anh, 0, 0, 0);
        float hv[4];
#pragma unroll
        for (int r = 0; r < 4; r++) {
            float gr = sigmoidf_(ar[r] + bsr[r]);
            float gz = sigmoidf_(az[r] + bsz[r]);
            float nin = (axn[r] + bin[r]) + gr * (anh[r] + bhn[r]);
            nin = fminf(fmaxf(nin, -15.f), 15.f);
            float e = __expf(-2.f * nin);
            float gn = (1.f - e) / (1.f + e);
            float hn = gn + gz * (h_old[r] - gn);
            h_old[r] = hn;
            hv[r] = hn;
        }
        *(uint2*)&hbuf[nxt][lo][d_base] = make_uint2(pack2bf(hv[0], hv[1]), pack2bf(hv[2], hv[3]));
        asm volatile("s_waitcnt lgkmcnt(0)\n\ts_barrier" ::: "memory");
        axr = nxr; axz = nxz; axn = nxn;
    }
    *(float4*)&h_out[(size_t)(cseq0 + lo) * 128 + dir * 64 + d_base] =
        make_float4(h_old[0], h_old[1], h_old[2], h_old[3]);
}

// =============================== K7: readout =================================
__global__ __launch_bounds__(128) void k_readout(
    const float* __restrict__ h_out, const float* __restrict__ gw, const float* __restrict__ gb,
    void* __restrict__ out, const int* __restrict__ flag)
{
    __shared__ float gate_s[16];
    __shared__ float gws[128];
    int b = blockIdx.x, t = threadIdx.x;
    gws[t] = gw[t];
    __syncthreads();
    int isb = *flag;
    if (t < 16) {
        const float* hr = h_out + (size_t)(b * 16 + t) * 128;
        float acc = gb[0];
        for (int k = 0; k < 128; k++) acc += hr[k] * gws[k];
        float g = sigmoidf_(acc);
        gate_s[t] = g;
        if (isb) ((bf16*)out)[12288 + b * 16 + t] = f2b(g);
        else     ((float*)out)[12288 + b * 16 + t] = g;
    }
    __syncthreads();
    float den = 1e-8f;
#pragma unroll
    for (int c = 0; c < 16; c++) den += gate_s[c];
    float num = 0.f;
#pragma unroll
    for (int c = 0; c < 16; c++) num += h_out[(size_t)(b * 16 + c) * 128 + t] * gate_s[c];
    float v = num / den;
    if (isb) ((bf16*)out)[b * 128 + t] = f2b(v);
    else     ((float*)out)[b * 128 + t] = v;
}

// =============================== launch ======================================
extern "C" void kernel_launch(void* const* d_in, const int* in_sizes, int n_in,
                              void* d_out, int out_size, void* d_ws, size_t ws_size,
                              hipStream_t stream)
{
    int* flag = (int*)d_ws;
    float* cvt = (float*)((char*)d_ws + 256);

    InPtrs P;
    InOffs O;
    int cum = 0;
    for (int i = 0; i < 35; i++) {
        P.p[i] = d_in[i];
        O.off[i] = cum;
        O.sz[i] = in_sizes[i];
        cum += (in_sizes[i] + 7) & ~7;
    }
    int total = cum;

    const float* x     = cvt + O.off[0];
    const float* c1w   = cvt + O.off[1];
    const float* c1b   = cvt + O.off[2];
    const float* bn1g  = cvt + O.off[3];
    const float* bn1b  = cvt + O.off[4];
    const float* bn1m  = cvt + O.off[5];
    const float* bn1v  = cvt + O.off[6];
    const float* c2w   = cvt + O.off[7];
    const float* c2b   = cvt + O.off[8];
    const float* bn2g  = cvt + O.off[9];
    const float* bn2b  = cvt + O.off[10];
    const float* bn2m  = cvt + O.off[11];
    const float* bn2v  = cvt + O.off[12];
    const float* prior = cvt + O.off[13];
    const float* logw  = cvt + O.off[14];
    const float* n1g   = cvt + O.off[15];
    const float* n1b   = cvt + O.off[16];
    const float* qkvw  = cvt + O.off[17];
    const float* qkvb  = cvt + O.off[18];
    const float* outw  = cvt + O.off[19];
    const float* outb  = cvt + O.off[20];
    const float* n2g   = cvt + O.off[21];
    const float* n2b   = cvt + O.off[22];
    const float* f1w   = cvt + O.off[23];
    const float* f1b   = cvt + O.off[24];
    const float* f2w   = cvt + O.off[25];
    const float* f2b_  = cvt + O.off[26];
    const float* gng   = cvt + O.off[27];
    const float* gnb   = cvt + O.off[28];
    const float* gwih  = cvt + O.off[29];
    const float* gwhh  = cvt + O.off[30];
    const float* gbih  = cvt + O.off[31];
    const float* gbhh  = cvt + O.off[32];
    const float* gatew = cvt + O.off[33];
    const float* gateb = cvt + O.off[34];

    float* fbase = cvt + ((total + 63) & ~63);
    float* hm    = fbase;                              // 8388608 floats (CNN out)
    ushort_t* Xnb = (ushort_t*)(hm + 8388608);         // 512*2080 bf16 spectrum
    float* hnf   = fbase + 8921088;                    // 32768
    float* adjw  = hnf + 32768;                        // 8192
    float* hout  = adjw + 8192;                        // 65536
    unsigned* wpk = (unsigned*)(hout + 65536);         // 62464 uints (bf16 weights)
    ushort_t* hmb = (ushort_t*)(wpk + 62464);          // 8388608 bf16 (GAT out)

    k_detect<<<1, 256, 0, stream>>>((const unsigned*)d_in[0], flag);
    k_convert<<<(total + 255) / 256, 256, 0, stream>>>(P, O, total, flag, cvt);
    k_pack<<<244, 256, 0, stream>>>(qkvw, outw, f1w, f2w, gwih, gwhh, c2w, wpk);
    k_front<<<768, 256, 0, stream>>>(x, c1w, c1b, bn1g, bn1b, bn1m, bn1v,
                                     c2b, bn2g, bn2b, bn2m, bn2v,
                                     (const ushort_t*)(wpk + 57344), hm, Xnb, hnf);
    k_adj<<<32, 256, 0, stream>>>(Xnb, hnf, prior, logw, adjw, d_out, flag);
    k_gat<<<2048, 256, 0, stream>>>(hm, adjw, (const ushort_t*)wpk,
                                    qkvb, outb, f1b, f2b_, n1g, n1b, n2g, n2b, gng, gnb, hmb);
    k_gru<<<64, 256, 0, stream>>>(hmb, (const ushort_t*)(wpk + 32768), gbih, gbhh, hout);
    k_readout<<<32, 128, 0, stream>>>(hout, gatew, gateb, d_out, flag);
}